// Round 1
// baseline (11540.016 us; speedup 1.0000x reference)
//
#include <hip/hip_runtime.h>
#include <hip/hip_bf16.h>
#include <math.h>

constexpr int kV = 32000;
constexpr int kD = 512;
constexpr int kC = 2;
constexpr int kS = 2048;
constexpr int kL = 4;
constexpr int kM = 64;
constexpr int kB = 16;
constexpr int kH = 2048;
constexpr int kBS = kB * kS; // 32768

// ---------------------------------------------------------------------------
// Embedding: h[b,s,:] = embed[x[b,s],:] + pos[s,:]
// ---------------------------------------------------------------------------
__global__ __launch_bounds__(256) void embed_kernel(const int* __restrict__ x,
    const float* __restrict__ emb, const float* __restrict__ pos,
    float* __restrict__ h) {
  int tid = blockIdx.x * 256 + threadIdx.x;   // over kBS * (kD/4)
  int row = tid >> 7;                          // kD/4 = 128 float4 per row
  int d4  = tid & 127;
  int tok = x[row];
  int s   = row & (kS - 1);
  float4 e = ((const float4*)emb)[(size_t)tok * 128 + d4];
  float4 p = ((const float4*)pos)[(size_t)s * 128 + d4];
  float4 o;
  o.x = e.x + p.x; o.y = e.y + p.y; o.z = e.z + p.z; o.w = e.w + p.w;
  ((float4*)h)[(size_t)row * 128 + d4] = o;
}

// ---------------------------------------------------------------------------
// Generic fp32 GEMM: C = act(A(MxK) @ W(KxN) + bias) [+ res]
// 64x64 tile, BK=16, 256 threads, 4x4 micro-tile.
// ACT: 0=none, 1=elu(x)+1, 2=gelu(exact)
// ---------------------------------------------------------------------------
template <int ACT, bool HAS_BIAS, bool HAS_RES>
__global__ __launch_bounds__(256) void gemm_kernel(
    const float* __restrict__ A, const float* __restrict__ W,
    const float* __restrict__ bias, const float* __restrict__ res,
    float* __restrict__ C, int K, int N) {
  __shared__ float As[16][68];  // [k][row], padded
  __shared__ float Bs[16][64];  // [k][col]
  const int tid = threadIdx.x;
  const int tx = tid & 15, ty = tid >> 4;
  const int row0 = blockIdx.y * 64, col0 = blockIdx.x * 64;

  float acc[4][4] = {};

  for (int k0 = 0; k0 < K; k0 += 16) {
    {  // A tile 64 rows x 16 k, transposed into As[k][row]
      int e = tid * 4;
      int r = e >> 4;
      int kc = e & 15;
      const float4 a4 = *(const float4*)&A[(size_t)(row0 + r) * K + k0 + kc];
      As[kc + 0][r] = a4.x; As[kc + 1][r] = a4.y;
      As[kc + 2][r] = a4.z; As[kc + 3][r] = a4.w;
    }
    {  // W tile 16 k x 64 cols
      int e = tid * 4;
      int kr = e >> 6;
      int nc = e & 63;
      *(float4*)&Bs[kr][nc] = *(const float4*)&W[(size_t)(k0 + kr) * N + col0 + nc];
    }
    __syncthreads();
#pragma unroll
    for (int kk = 0; kk < 16; ++kk) {
      float a[4];
#pragma unroll
      for (int i = 0; i < 4; ++i) a[i] = As[kk][ty * 4 + i];
      float4 b4 = *(const float4*)&Bs[kk][tx * 4];
      float b[4] = {b4.x, b4.y, b4.z, b4.w};
#pragma unroll
      for (int i = 0; i < 4; ++i)
#pragma unroll
        for (int j = 0; j < 4; ++j) acc[i][j] += a[i] * b[j];
    }
    __syncthreads();
  }

#pragma unroll
  for (int i = 0; i < 4; ++i) {
    int r = row0 + ty * 4 + i;
    size_t base = (size_t)r * N + col0 + tx * 4;
    float vals[4];
#pragma unroll
    for (int j = 0; j < 4; ++j) {
      float v = acc[i][j];
      if (HAS_BIAS) v += bias[col0 + tx * 4 + j];
      if (ACT == 1) v = (v > 0.f) ? (v + 1.f) : expf(v);   // elu(x)+1
      if (ACT == 2) v = 0.5f * v * (1.0f + erff(v * 0.70710678118654752f));
      if (HAS_RES) v += res[base + j];
      vals[j] = v;
    }
    *(float4*)&C[base] = make_float4(vals[0], vals[1], vals[2], vals[3]);
  }
}

// ---------------------------------------------------------------------------
// kv[b,m,d] = sum_s pk[b,s,m] * v[b,s,d]   (per-batch pk^T @ v)
// grid: (kD/64, kB); 256 threads, 4x4 micro-tile over (m,d)
// ---------------------------------------------------------------------------
__global__ __launch_bounds__(256) void kv_kernel(const float* __restrict__ pk,
    const float* __restrict__ v, float* __restrict__ kvout) {
  __shared__ float pkS[16][64];  // [s][m]
  __shared__ float vS[16][64];   // [s][d]
  const int b = blockIdx.y, d0 = blockIdx.x * 64;
  const float* pkb = pk + (size_t)b * kS * kM;
  const float* vb  = v  + (size_t)b * kS * kD;
  const int tid = threadIdx.x;
  const int tx = tid & 15, ty = tid >> 4;
  float acc[4][4] = {};

  for (int s0 = 0; s0 < kS; s0 += 16) {
    {
      int e = tid * 4;
      int sr = e >> 6, mc = e & 63;
      *(float4*)&pkS[sr][mc] = *(const float4*)&pkb[(size_t)(s0 + sr) * kM + mc];
    }
    {
      int e = tid * 4;
      int sr = e >> 6, dc = e & 63;
      *(float4*)&vS[sr][dc] = *(const float4*)&vb[(size_t)(s0 + sr) * kD + d0 + dc];
    }
    __syncthreads();
#pragma unroll
    for (int sr = 0; sr < 16; ++sr) {
      float a[4];
#pragma unroll
      for (int i = 0; i < 4; ++i) a[i] = pkS[sr][ty * 4 + i];
      float4 b4 = *(const float4*)&vS[sr][tx * 4];
      float bb[4] = {b4.x, b4.y, b4.z, b4.w};
#pragma unroll
      for (int i = 0; i < 4; ++i)
#pragma unroll
        for (int j = 0; j < 4; ++j) acc[i][j] += a[i] * bb[j];
    }
    __syncthreads();
  }

#pragma unroll
  for (int i = 0; i < 4; ++i) {
    int m = ty * 4 + i;
    *(float4*)&kvout[((size_t)b * kM + m) * kD + d0 + tx * 4] =
        make_float4(acc[i][0], acc[i][1], acc[i][2], acc[i][3]);
  }
}

// ---------------------------------------------------------------------------
// pksum[b,m] = sum_s pk[b,s,m]
// ---------------------------------------------------------------------------
__global__ __launch_bounds__(256) void pksum_kernel(const float* __restrict__ pk,
                                                    float* __restrict__ pksum) {
  __shared__ float part[4][64];
  int b = blockIdx.x;
  int lane = threadIdx.x & 63, w = threadIdx.x >> 6;
  float s = 0.f;
  for (int sI = w * (kS / 4); sI < (w + 1) * (kS / 4); ++sI)
    s += pk[((size_t)b * kS + sI) * kM + lane];
  part[w][lane] = s;
  __syncthreads();
  if (w == 0)
    pksum[b * kM + lane] = part[0][lane] + part[1][lane] + part[2][lane] + part[3][lane];
}

// ---------------------------------------------------------------------------
// z[b,s] = dot(pq[b,s,:], pksum[b,:]) + 1e-6    (one wave per row)
// ---------------------------------------------------------------------------
__global__ __launch_bounds__(256) void z_kernel(const float* __restrict__ pq,
    const float* __restrict__ pksum, float* __restrict__ z) {
  int row = blockIdx.x * 4 + (threadIdx.x >> 6);
  int lane = threadIdx.x & 63;
  int b = row >> 11;  // / kS
  float v = pq[(size_t)row * kM + lane] * pksum[b * kM + lane];
#pragma unroll
  for (int off = 32; off; off >>= 1) v += __shfl_down(v, off);
  if (lane == 0) z[row] = v + 1e-6f;
}

// ---------------------------------------------------------------------------
// att[b,s,d] = (sum_m pq[b,s,m]*kv[b,m,d]) / z[b,s]
// grid: (kD/64, kS/64, kB)
// ---------------------------------------------------------------------------
__global__ __launch_bounds__(256) void att_kernel(const float* __restrict__ pq,
    const float* __restrict__ kvm, const float* __restrict__ z,
    float* __restrict__ out) {
  __shared__ float pqS[64][68];  // [s][m]
  __shared__ float kvS[64][68];  // [m][d]
  const int d0 = blockIdx.x * 64, s0 = blockIdx.y * 64, b = blockIdx.z;
  const int tid = threadIdx.x;
  const int tx = tid & 15, ty = tid >> 4;

  for (int i = 0; i < 4; ++i) {
    int f = tid + i * 256;
    int r = f >> 4, c = (f & 15) * 4;
    *(float4*)&pqS[r][c] = *(const float4*)&pq[((size_t)(b * kS + s0 + r)) * kM + c];
    *(float4*)&kvS[r][c] = *(const float4*)&kvm[((size_t)b * kM + r) * kD + d0 + c];
  }
  __syncthreads();

  float acc[4][4] = {};
#pragma unroll
  for (int m = 0; m < kM; ++m) {
    float a[4];
#pragma unroll
    for (int i = 0; i < 4; ++i) a[i] = pqS[ty * 4 + i][m];
    float4 b4 = *(const float4*)&kvS[m][tx * 4];
    float bb[4] = {b4.x, b4.y, b4.z, b4.w};
#pragma unroll
    for (int i = 0; i < 4; ++i)
#pragma unroll
      for (int j = 0; j < 4; ++j) acc[i][j] += a[i] * bb[j];
  }

#pragma unroll
  for (int i = 0; i < 4; ++i) {
    int srow = s0 + ty * 4 + i;
    float zi = 1.0f / z[b * kS + srow];
    *(float4*)&out[((size_t)(b * kS + srow)) * kD + d0 + tx * 4] =
        make_float4(acc[i][0] * zi, acc[i][1] * zi, acc[i][2] * zi, acc[i][3] * zi);
  }
}

// ---------------------------------------------------------------------------
// LayerNorm over last dim (D=512); one block (256 thr) per row
// ---------------------------------------------------------------------------
__global__ __launch_bounds__(256) void ln_kernel(const float* __restrict__ in,
    const float* __restrict__ g, const float* __restrict__ b,
    float* __restrict__ out) {
  __shared__ float ws1[4], ws2[4];
  int row = blockIdx.x, tid = threadIdx.x;
  float2 v = ((const float2*)(in + (size_t)row * kD))[tid];
  float s = v.x + v.y;
#pragma unroll
  for (int off = 32; off; off >>= 1) s += __shfl_down(s, off);
  if ((tid & 63) == 0) ws1[tid >> 6] = s;
  __syncthreads();
  float mean = (ws1[0] + ws1[1] + ws1[2] + ws1[3]) * (1.0f / kD);
  float dx = v.x - mean, dy = v.y - mean;
  float s2 = dx * dx + dy * dy;
#pragma unroll
  for (int off = 32; off; off >>= 1) s2 += __shfl_down(s2, off);
  if ((tid & 63) == 0) ws2[tid >> 6] = s2;
  __syncthreads();
  float var = (ws2[0] + ws2[1] + ws2[2] + ws2[3]) * (1.0f / kD);
  float rstd = rsqrtf(var + 1e-5f);
  float2 gg = ((const float2*)g)[tid];
  float2 bb = ((const float2*)b)[tid];
  float2 o;
  o.x = dx * rstd * gg.x + bb.x;
  o.y = dy * rstd * gg.y + bb.y;
  ((float2*)(out + (size_t)row * kD))[tid] = o;
}

// ---------------------------------------------------------------------------
// Classifier: out[b,:] = relu(h[b,0,:] @ Wc1 + bc1) @ Wc2 + bc2
// one block per b; 256 threads = 256 hidden units
// ---------------------------------------------------------------------------
__global__ __launch_bounds__(256) void cls_kernel(const float* __restrict__ h,
    const float* __restrict__ Wc1, const float* __restrict__ bc1,
    const float* __restrict__ Wc2, const float* __restrict__ bc2,
    float* __restrict__ out) {
  __shared__ float r0[4], r1[4];
  int b = blockIdx.x;
  int j = threadIdx.x;
  const float* p = h + (size_t)b * kS * kD;  // row s=0
  float acc = bc1[j];
  for (int i = 0; i < kD; ++i) acc += p[i] * Wc1[i * (kD / 2) + j];
  acc = fmaxf(acc, 0.f);
  float p0 = acc * Wc2[j * kC + 0];
  float p1 = acc * Wc2[j * kC + 1];
#pragma unroll
  for (int off = 32; off; off >>= 1) {
    p0 += __shfl_down(p0, off);
    p1 += __shfl_down(p1, off);
  }
  if ((j & 63) == 0) { r0[j >> 6] = p0; r1[j >> 6] = p1; }
  __syncthreads();
  if (j == 0) {
    out[b * kC + 0] = r0[0] + r0[1] + r0[2] + r0[3] + bc2[0];
    out[b * kC + 1] = r1[0] + r1[1] + r1[2] + r1[3] + bc2[1];
  }
}

// ---------------------------------------------------------------------------
extern "C" void kernel_launch(void* const* d_in, const int* in_sizes, int n_in,
                              void* d_out, int out_size, void* d_ws, size_t ws_size,
                              hipStream_t stream) {
  const int*   x    = (const int*)  d_in[0];
  const float* emb  = (const float*)d_in[1];
  const float* pos  = (const float*)d_in[2];
  const float* Wq   = (const float*)d_in[3];
  const float* bq   = (const float*)d_in[4];
  const float* Wk   = (const float*)d_in[5];
  const float* bk   = (const float*)d_in[6];
  const float* Wv   = (const float*)d_in[7];
  const float* bv   = (const float*)d_in[8];
  const float* P    = (const float*)d_in[9];
  const float* Wo   = (const float*)d_in[10];
  const float* bo   = (const float*)d_in[11];
  const float* ln_g = (const float*)d_in[12];
  const float* ln_b = (const float*)d_in[13];
  const float* W1   = (const float*)d_in[14];
  const float* b1   = (const float*)d_in[15];
  const float* W2   = (const float*)d_in[16];
  const float* b2   = (const float*)d_in[17];
  const float* Wc1  = (const float*)d_in[18];
  const float* bc1  = (const float*)d_in[19];
  const float* Wc2  = (const float*)d_in[20];
  const float* bc2  = (const float*)d_in[21];
  float* out = (float*)d_out;

  // Workspace layout (floats): ~210 MB total
  float* h   = (float*)d_ws;                   // kBS*kD
  float* t0  = h   + (size_t)kBS * kD;         // kBS*kD (q/k/v, att2, F-chunk)
  float* t1  = t0  + (size_t)kBS * kD;         // kBS*kD (att, hn)
  float* pq  = t1  + (size_t)kBS * kD;         // kBS*kM
  float* pk  = pq  + (size_t)kBS * kM;         // kBS*kM
  float* kvb = pk  + (size_t)kBS * kM;         // kB*kM*kD
  float* pks = kvb + (size_t)kB * kM * kD;     // kB*kM
  float* zb  = pks + (size_t)kB * kM;          // kBS

  embed_kernel<<<kBS * (kD / 4) / 256, 256, 0, stream>>>(x, emb, pos, h);

  const dim3 g512(kD / 64, kBS / 64);

  for (int l = 0; l < kL; ++l) {
    const float* Wql = Wq + (size_t)l * kD * kD;
    const float* Wkl = Wk + (size_t)l * kD * kD;
    const float* Wvl = Wv + (size_t)l * kD * kD;
    const float* Pl  = P  + (size_t)l * kD * kM;
    const float* Wol = Wo + (size_t)l * kD * kD;
    const float* W1l = W1 + (size_t)l * kD * kH;
    const float* W2l = W2 + (size_t)l * kH * kD;

    // q -> t0 ; pq = elu(q@P)+1
    gemm_kernel<0, true, false><<<g512, 256, 0, stream>>>(h, Wql, bq + l * kD, nullptr, t0, kD, kD);
    gemm_kernel<1, false, false><<<dim3(1, kBS / 64), 256, 0, stream>>>(t0, Pl, nullptr, nullptr, pq, kD, kM);
    // k -> t0 ; pk
    gemm_kernel<0, true, false><<<g512, 256, 0, stream>>>(h, Wkl, bk + l * kD, nullptr, t0, kD, kD);
    gemm_kernel<1, false, false><<<dim3(1, kBS / 64), 256, 0, stream>>>(t0, Pl, nullptr, nullptr, pk, kD, kM);
    // v -> t0
    gemm_kernel<0, true, false><<<g512, 256, 0, stream>>>(h, Wvl, bv + l * kD, nullptr, t0, kD, kD);
    // kv, pksum, z
    kv_kernel<<<dim3(kD / 64, kB), 256, 0, stream>>>(pk, t0, kvb);
    pksum_kernel<<<kB, 256, 0, stream>>>(pk, pks);
    z_kernel<<<kBS / 4, 256, 0, stream>>>(pq, pks, zb);
    // att -> t1
    att_kernel<<<dim3(kD / 64, kS / 64, kB), 256, 0, stream>>>(pq, kvb, zb, t1);
    // att @ Wo + bo -> t0
    gemm_kernel<0, true, false><<<g512, 256, 0, stream>>>(t1, Wol, bo + l * kD, nullptr, t0, kD, kD);
    // LN -> t1
    ln_kernel<<<kBS, 256, 0, stream>>>(t0, ln_g + l * kD, ln_b + l * kD, t1);
    // FFN in 4 row-chunks of 8192: F = gelu(hn@W1+b1) -> t0 ; h += F@W2+b2
    for (int c = 0; c < 4; ++c) {
      size_t ro = (size_t)c * 8192;
      gemm_kernel<2, true, false><<<dim3(kH / 64, 8192 / 64), 256, 0, stream>>>(
          t1 + ro * kD, W1l, b1 + l * kH, nullptr, t0, kD, kH);
      gemm_kernel<0, true, true><<<dim3(kD / 64, 8192 / 64), 256, 0, stream>>>(
          t0, W2l, b2 + l * kD, h + ro * kD, h + ro * kD, kH, kD);
    }
  }

  cls_kernel<<<kB, 256, 0, stream>>>(h, Wc1, bc1, Wc2, bc2, out);
}

// Round 3
// 3591.205 us; speedup vs baseline: 3.2134x; 3.2134x over previous
//
#include <hip/hip_runtime.h>
#include <hip/hip_bf16.h>
#include <math.h>

constexpr int kV = 32000;
constexpr int kD = 512;
constexpr int kC = 2;
constexpr int kS = 2048;
constexpr int kL = 4;
constexpr int kM = 64;
constexpr int kB = 16;
constexpr int kH = 2048;
constexpr int kBS = kB * kS; // 32768

typedef __hip_bfloat16 bf16;
using bf16x8 = __attribute__((ext_vector_type(8))) short;  // 8 bf16 = 4 VGPRs
using f32x4  = __attribute__((ext_vector_type(4))) float;

__device__ inline unsigned short f2bf_u16(float f) {
  bf16 b = __float2bfloat16(f);
  return *reinterpret_cast<unsigned short*>(&b);
}

// ---------------------------------------------------------------------------
// Embedding: h[b,s,:] = embed[x[b,s],:] + pos[s,:]  (writes fp32 h AND bf16 hb)
// ---------------------------------------------------------------------------
__global__ __launch_bounds__(256) void embed_kernel(const int* __restrict__ x,
    const float* __restrict__ emb, const float* __restrict__ pos,
    float* __restrict__ h, bf16* __restrict__ hb) {
  int tid = blockIdx.x * 256 + threadIdx.x;   // over kBS * (kD/4)
  int row = tid >> 7;                          // kD/4 = 128 float4 per row
  int d4  = tid & 127;
  int tok = x[row];
  int s   = row & (kS - 1);
  float4 e = ((const float4*)emb)[(size_t)tok * 128 + d4];
  float4 p = ((const float4*)pos)[(size_t)s * 128 + d4];
  float4 o;
  o.x = e.x + p.x; o.y = e.y + p.y; o.z = e.z + p.z; o.w = e.w + p.w;
  ((float4*)h)[(size_t)row * 128 + d4] = o;
  ushort4 ub;
  ub.x = f2bf_u16(o.x); ub.y = f2bf_u16(o.y);
  ub.z = f2bf_u16(o.z); ub.w = f2bf_u16(o.w);
  ((ushort4*)hb)[(size_t)row * 128 + d4] = ub;
}

// ---------------------------------------------------------------------------
// Transpose + cast: Wt[n][k] = (bf16) W[k][n]
// ---------------------------------------------------------------------------
__global__ __launch_bounds__(256) void transpose_cast_kernel(
    const float* __restrict__ W, bf16* __restrict__ Wt, int K, int N) {
  __shared__ float tile[32][33];
  const int k0 = blockIdx.x * 32, n0 = blockIdx.y * 32;
  int tx = threadIdx.x & 31, ty = threadIdx.x >> 5;  // 32 x 8
#pragma unroll
  for (int i = 0; i < 32; i += 8)
    tile[ty + i][tx] = W[(size_t)(k0 + ty + i) * N + n0 + tx];
  __syncthreads();
#pragma unroll
  for (int i = 0; i < 32; i += 8)
    Wt[(size_t)(n0 + ty + i) * K + k0 + tx] = __float2bfloat16(tile[tx][ty + i]);
}

// ---------------------------------------------------------------------------
// bf16 MFMA GEMM: C = act(A(MxK,bf16) @ Wt(NxK,bf16)^T + bias) [+res]
// 128x128 tile, BK=32, 256 threads (4 waves, each a 64x64 quadrant of 4x4
// 16x16x32 MFMAs). fp32 accumulate; epilogue writes fp32 C and/or bf16 Cb.
// ACT: 0=none, 2=gelu(exact)
// ---------------------------------------------------------------------------
template <int ACT, bool HAS_RES, bool WRITE_F32, bool WRITE_BF16>
__global__ __launch_bounds__(256) void mfma_gemm(
    const bf16* __restrict__ A, const bf16* __restrict__ Wt,
    const float* __restrict__ bias, const float* __restrict__ res,
    float* __restrict__ C, bf16* __restrict__ Cb, int K, int N) {
  __shared__ short As[128 * 32];
  __shared__ short Bs[128 * 32];
  const int tid  = threadIdx.x;
  const int lane = tid & 63;
  const int wave = tid >> 6;
  const int row0 = blockIdx.y * 128;
  const int col0 = blockIdx.x * 128;
  const int wr = (wave & 1) * 64;
  const int wc = (wave >> 1) * 64;
  const int lcol = lane & 15;
  const int quad = lane >> 4;

  f32x4 acc[4][4];
#pragma unroll
  for (int i = 0; i < 4; ++i)
#pragma unroll
    for (int j = 0; j < 4; ++j) acc[i][j] = (f32x4){0.f, 0.f, 0.f, 0.f};

  const int idx0 = tid * 2;
  for (int k0 = 0; k0 < K; k0 += 32) {
#pragma unroll
    for (int p = 0; p < 2; ++p) {
      int idx = idx0 + p;
      int r = idx >> 2, kc = idx & 3;
      *(int4*)&As[idx * 8] = *(const int4*)&A[(size_t)(row0 + r) * K + k0 + kc * 8];
      *(int4*)&Bs[idx * 8] = *(const int4*)&Wt[(size_t)(col0 + r) * K + k0 + kc * 8];
    }
    __syncthreads();
    bf16x8 af[4], bfr[4];
#pragma unroll
    for (int i = 0; i < 4; ++i)
      af[i] = *(const bf16x8*)&As[(wr + i * 16 + lcol) * 32 + quad * 8];
#pragma unroll
    for (int j = 0; j < 4; ++j)
      bfr[j] = *(const bf16x8*)&Bs[(wc + j * 16 + lcol) * 32 + quad * 8];
#pragma unroll
    for (int i = 0; i < 4; ++i)
#pragma unroll
      for (int j = 0; j < 4; ++j)
        acc[i][j] = __builtin_amdgcn_mfma_f32_16x16x32_bf16(af[i], bfr[j], acc[i][j], 0, 0, 0);
    __syncthreads();
  }

#pragma unroll
  for (int i = 0; i < 4; ++i) {
#pragma unroll
    for (int r = 0; r < 4; ++r) {
      int grow = row0 + wr + i * 16 + quad * 4 + r;
#pragma unroll
      for (int j = 0; j < 4; ++j) {
        int gcol = col0 + wc + j * 16 + lcol;
        float v = acc[i][j][r] + bias[gcol];
        if (ACT == 2) v = 0.5f * v * (1.0f + erff(v * 0.70710678118654752f));
        size_t off = (size_t)grow * N + gcol;
        if (HAS_RES) v += res[off];
        if (WRITE_F32) C[off] = v;
        if (WRITE_BF16) Cb[off] = __float2bfloat16(v);
      }
    }
  }
}

// ---------------------------------------------------------------------------
// fp32 GEMM (kept for the skinny N=64 P-projections): C = elu(A@W)+1
// ---------------------------------------------------------------------------
template <int ACT>
__global__ __launch_bounds__(256) void gemm_kernel(
    const float* __restrict__ A, const float* __restrict__ W,
    float* __restrict__ C, int K, int N) {
  __shared__ float As[16][68];
  __shared__ float Bs[16][64];
  const int tid = threadIdx.x;
  const int tx = tid & 15, ty = tid >> 4;
  const int row0 = blockIdx.y * 64, col0 = blockIdx.x * 64;
  float acc[4][4] = {};
  for (int k0 = 0; k0 < K; k0 += 16) {
    {
      int e = tid * 4;
      int r = e >> 4, kc = e & 15;
      const float4 a4 = *(const float4*)&A[(size_t)(row0 + r) * K + k0 + kc];
      As[kc + 0][r] = a4.x; As[kc + 1][r] = a4.y;
      As[kc + 2][r] = a4.z; As[kc + 3][r] = a4.w;
    }
    {
      int e = tid * 4;
      int kr = e >> 6, nc = e & 63;
      *(float4*)&Bs[kr][nc] = *(const float4*)&W[(size_t)(k0 + kr) * N + col0 + nc];
    }
    __syncthreads();
#pragma unroll
    for (int kk = 0; kk < 16; ++kk) {
      float a[4];
#pragma unroll
      for (int i = 0; i < 4; ++i) a[i] = As[kk][ty * 4 + i];
      float4 b4 = *(const float4*)&Bs[kk][tx * 4];
      float b[4] = {b4.x, b4.y, b4.z, b4.w};
#pragma unroll
      for (int i = 0; i < 4; ++i)
#pragma unroll
        for (int j = 0; j < 4; ++j) acc[i][j] += a[i] * b[j];
    }
    __syncthreads();
  }
#pragma unroll
  for (int i = 0; i < 4; ++i) {
    int r = row0 + ty * 4 + i;
    size_t base = (size_t)r * N + col0 + tx * 4;
    float vals[4];
#pragma unroll
    for (int j = 0; j < 4; ++j) {
      float v = acc[i][j];
      if (ACT == 1) v = (v > 0.f) ? (v + 1.f) : expf(v);
      vals[j] = v;
    }
    *(float4*)&C[base] = make_float4(vals[0], vals[1], vals[2], vals[3]);
  }
}

// ---------------------------------------------------------------------------
// kv[b,m,d] = sum_s pk[b,s,m] * v[b,s,d]
// ---------------------------------------------------------------------------
__global__ __launch_bounds__(256) void kv_kernel(const float* __restrict__ pk,
    const float* __restrict__ v, float* __restrict__ kvout) {
  __shared__ float pkS[16][64];
  __shared__ float vS[16][64];
  const int b = blockIdx.y, d0 = blockIdx.x * 64;
  const float* pkb = pk + (size_t)b * kS * kM;
  const float* vb  = v  + (size_t)b * kS * kD;
  const int tid = threadIdx.x;
  const int tx = tid & 15, ty = tid >> 4;
  float acc[4][4] = {};
  for (int s0 = 0; s0 < kS; s0 += 16) {
    {
      int e = tid * 4;
      int sr = e >> 6, mc = e & 63;
      *(float4*)&pkS[sr][mc] = *(const float4*)&pkb[(size_t)(s0 + sr) * kM + mc];
    }
    {
      int e = tid * 4;
      int sr = e >> 6, dc = e & 63;
      *(float4*)&vS[sr][dc] = *(const float4*)&vb[(size_t)(s0 + sr) * kD + d0 + dc];
    }
    __syncthreads();
#pragma unroll
    for (int sr = 0; sr < 16; ++sr) {
      float a[4];
#pragma unroll
      for (int i = 0; i < 4; ++i) a[i] = pkS[sr][ty * 4 + i];
      float4 b4 = *(const float4*)&vS[sr][tx * 4];
      float bb[4] = {b4.x, b4.y, b4.z, b4.w};
#pragma unroll
      for (int i = 0; i < 4; ++i)
#pragma unroll
        for (int j = 0; j < 4; ++j) acc[i][j] += a[i] * bb[j];
    }
    __syncthreads();
  }
#pragma unroll
  for (int i = 0; i < 4; ++i) {
    int m = ty * 4 + i;
    *(float4*)&kvout[((size_t)b * kM + m) * kD + d0 + tx * 4] =
        make_float4(acc[i][0], acc[i][1], acc[i][2], acc[i][3]);
  }
}

// ---------------------------------------------------------------------------
__global__ __launch_bounds__(256) void pksum_kernel(const float* __restrict__ pk,
                                                    float* __restrict__ pksum) {
  __shared__ float part[4][64];
  int b = blockIdx.x;
  int lane = threadIdx.x & 63, w = threadIdx.x >> 6;
  float s = 0.f;
  for (int sI = w * (kS / 4); sI < (w + 1) * (kS / 4); ++sI)
    s += pk[((size_t)b * kS + sI) * kM + lane];
  part[w][lane] = s;
  __syncthreads();
  if (w == 0)
    pksum[b * kM + lane] = part[0][lane] + part[1][lane] + part[2][lane] + part[3][lane];
}

// ---------------------------------------------------------------------------
__global__ __launch_bounds__(256) void z_kernel(const float* __restrict__ pq,
    const float* __restrict__ pksum, float* __restrict__ z) {
  int row = blockIdx.x * 4 + (threadIdx.x >> 6);
  int lane = threadIdx.x & 63;
  int b = row >> 11;
  float v = pq[(size_t)row * kM + lane] * pksum[b * kM + lane];
#pragma unroll
  for (int off = 32; off; off >>= 1) v += __shfl_down(v, off);
  if (lane == 0) z[row] = v + 1e-6f;
}

// ---------------------------------------------------------------------------
// att[b,s,d] = (sum_m pq[b,s,m]*kv[b,m,d]) / z[b,s]  -> bf16 out
// ---------------------------------------------------------------------------
__global__ __launch_bounds__(256) void att_kernel(const float* __restrict__ pq,
    const float* __restrict__ kvm, const float* __restrict__ z,
    bf16* __restrict__ out) {
  __shared__ float pqS[64][68];
  __shared__ float kvS[64][68];
  const int d0 = blockIdx.x * 64, s0 = blockIdx.y * 64, b = blockIdx.z;
  const int tid = threadIdx.x;
  const int tx = tid & 15, ty = tid >> 4;
  for (int i = 0; i < 4; ++i) {
    int f = tid + i * 256;
    int r = f >> 4, c = (f & 15) * 4;
    *(float4*)&pqS[r][c] = *(const float4*)&pq[((size_t)(b * kS + s0 + r)) * kM + c];
    *(float4*)&kvS[r][c] = *(const float4*)&kvm[((size_t)b * kM + r) * kD + d0 + c];
  }
  __syncthreads();
  float acc[4][4] = {};
#pragma unroll
  for (int m = 0; m < kM; ++m) {
    float a[4];
#pragma unroll
    for (int i = 0; i < 4; ++i) a[i] = pqS[ty * 4 + i][m];
    float4 b4 = *(const float4*)&kvS[m][tx * 4];
    float bb[4] = {b4.x, b4.y, b4.z, b4.w};
#pragma unroll
    for (int i = 0; i < 4; ++i)
#pragma unroll
      for (int j = 0; j < 4; ++j) acc[i][j] += a[i] * bb[j];
  }
#pragma unroll
  for (int i = 0; i < 4; ++i) {
    int srow = s0 + ty * 4 + i;
    float zi = 1.0f / z[b * kS + srow];
    ushort4 u;
    u.x = f2bf_u16(acc[i][0] * zi);
    u.y = f2bf_u16(acc[i][1] * zi);
    u.z = f2bf_u16(acc[i][2] * zi);
    u.w = f2bf_u16(acc[i][3] * zi);
    *(ushort4*)&out[((size_t)(b * kS + srow)) * kD + d0 + tx * 4] = u;
  }
}

// ---------------------------------------------------------------------------
// LayerNorm over D=512; fp32 in, bf16 out
// ---------------------------------------------------------------------------
__global__ __launch_bounds__(256) void ln_kernel(const float* __restrict__ in,
    const float* __restrict__ g, const float* __restrict__ b,
    bf16* __restrict__ out) {
  __shared__ float ws1[4], ws2[4];
  int row = blockIdx.x, tid = threadIdx.x;
  float2 v = ((const float2*)(in + (size_t)row * kD))[tid];
  float s = v.x + v.y;
#pragma unroll
  for (int off = 32; off; off >>= 1) s += __shfl_down(s, off);
  if ((tid & 63) == 0) ws1[tid >> 6] = s;
  __syncthreads();
  float mean = (ws1[0] + ws1[1] + ws1[2] + ws1[3]) * (1.0f / kD);
  float dx = v.x - mean, dy = v.y - mean;
  float s2 = dx * dx + dy * dy;
#pragma unroll
  for (int off = 32; off; off >>= 1) s2 += __shfl_down(s2, off);
  if ((tid & 63) == 0) ws2[tid >> 6] = s2;
  __syncthreads();
  float var = (ws2[0] + ws2[1] + ws2[2] + ws2[3]) * (1.0f / kD);
  float rstd = rsqrtf(var + 1e-5f);
  float2 gg = ((const float2*)g)[tid];
  float2 bb = ((const float2*)b)[tid];
  ushort2 u;
  u.x = f2bf_u16(dx * rstd * gg.x + bb.x);
  u.y = f2bf_u16(dy * rstd * gg.y + bb.y);
  ((ushort2*)(out + (size_t)row * kD))[tid] = u;
}

// ---------------------------------------------------------------------------
__global__ __launch_bounds__(256) void cls_kernel(const float* __restrict__ h,
    const float* __restrict__ Wc1, const float* __restrict__ bc1,
    const float* __restrict__ Wc2, const float* __restrict__ bc2,
    float* __restrict__ out) {
  __shared__ float r0[4], r1[4];
  int b = blockIdx.x;
  int j = threadIdx.x;
  const float* p = h + (size_t)b * kS * kD;
  float acc = bc1[j];
  for (int i = 0; i < kD; ++i) acc += p[i] * Wc1[i * (kD / 2) + j];
  acc = fmaxf(acc, 0.f);
  float p0 = acc * Wc2[j * kC + 0];
  float p1 = acc * Wc2[j * kC + 1];
#pragma unroll
  for (int off = 32; off; off >>= 1) {
    p0 += __shfl_down(p0, off);
    p1 += __shfl_down(p1, off);
  }
  if ((j & 63) == 0) { r0[j >> 6] = p0; r1[j >> 6] = p1; }
  __syncthreads();
  if (j == 0) {
    out[b * kC + 0] = r0[0] + r0[1] + r0[2] + r0[3] + bc2[0];
    out[b * kC + 1] = r1[0] + r1[1] + r1[2] + r1[3] + bc2[1];
  }
}

// ---------------------------------------------------------------------------
extern "C" void kernel_launch(void* const* d_in, const int* in_sizes, int n_in,
                              void* d_out, int out_size, void* d_ws, size_t ws_size,
                              hipStream_t stream) {
  const int*   x    = (const int*)  d_in[0];
  const float* emb  = (const float*)d_in[1];
  const float* pos  = (const float*)d_in[2];
  const float* Wq   = (const float*)d_in[3];
  const float* bq   = (const float*)d_in[4];
  const float* Wk   = (const float*)d_in[5];
  const float* bk   = (const float*)d_in[6];
  const float* Wv   = (const float*)d_in[7];
  const float* bv   = (const float*)d_in[8];
  const float* P    = (const float*)d_in[9];
  const float* Wo   = (const float*)d_in[10];
  const float* bo   = (const float*)d_in[11];
  const float* ln_g = (const float*)d_in[12];
  const float* ln_b = (const float*)d_in[13];
  const float* W1   = (const float*)d_in[14];
  const float* b1   = (const float*)d_in[15];
  const float* W2   = (const float*)d_in[16];
  const float* b2   = (const float*)d_in[17];
  const float* Wc1  = (const float*)d_in[18];
  const float* bc1  = (const float*)d_in[19];
  const float* Wc2  = (const float*)d_in[20];
  const float* bc2  = (const float*)d_in[21];
  float* out = (float*)d_out;

  // Workspace layout (~216 MB total; round-1's 220 MB footprint is proven OK)
  float* h   = (float*)d_ws;                   // kBS*kD f32         64 MB
  float* t0  = h   + (size_t)kBS * kD;         // kBS*kD f32         64 MB (q/k/v, Wo out; F aliases this in FFN)
  float* pq  = t0  + (size_t)kBS * kD;         // kBS*kM              8 MB
  float* pk  = pq  + (size_t)kBS * kM;         // kBS*kM              8 MB
  float* kvb = pk  + (size_t)kBS * kM;         // kB*kM*kD            2 MB
  float* pks = kvb + (size_t)kB * kM * kD;     // kB*kM
  float* zb  = pks + (size_t)kB * kM;          // kBS
  bf16* hb   = (bf16*)(zb + kBS);              // kBS*kD bf16        32 MB
  bf16* ab   = hb + (size_t)kBS * kD;          // kBS*kD bf16        32 MB (att, then hn)
  // per-layer transposed weights (reused each layer): 6 MB
  bf16* Wqt  = ab  + (size_t)kBS * kD;         // kD*kD
  bf16* Wkt  = Wqt + (size_t)kD * kD;
  bf16* Wvt  = Wkt + (size_t)kD * kD;
  bf16* Wot  = Wvt + (size_t)kD * kD;
  bf16* W1t  = Wot + (size_t)kD * kD;          // kH*kD ([H][D])
  bf16* W2t  = W1t + (size_t)kD * kH;          // kD*kH ([D][H])
  bf16* F    = (bf16*)t0;                      // 8192*kH bf16 aliases t0 (32 MB)

  embed_kernel<<<kBS * (kD / 4) / 256, 256, 0, stream>>>(x, emb, pos, h, hb);

  const dim3 gDD(kD / 128, kBS / 128);   // (4, 256)

  for (int l = 0; l < kL; ++l) {
    const float* Pl = P + (size_t)l * kD * kM;

    // Transpose+cast this layer's weights (tiny kernels)
    transpose_cast_kernel<<<dim3(kD / 32, kD / 32), 256, 0, stream>>>(
        Wq + (size_t)l * kD * kD, Wqt, kD, kD);
    transpose_cast_kernel<<<dim3(kD / 32, kD / 32), 256, 0, stream>>>(
        Wk + (size_t)l * kD * kD, Wkt, kD, kD);
    transpose_cast_kernel<<<dim3(kD / 32, kD / 32), 256, 0, stream>>>(
        Wv + (size_t)l * kD * kD, Wvt, kD, kD);
    transpose_cast_kernel<<<dim3(kD / 32, kD / 32), 256, 0, stream>>>(
        Wo + (size_t)l * kD * kD, Wot, kD, kD);
    transpose_cast_kernel<<<dim3(kD / 32, kH / 32), 256, 0, stream>>>(
        W1 + (size_t)l * kD * kH, W1t, kD, kH);
    transpose_cast_kernel<<<dim3(kH / 32, kD / 32), 256, 0, stream>>>(
        W2 + (size_t)l * kH * kD, W2t, kH, kD);

    // q -> t0 (f32) ; pq = elu(q@P)+1
    mfma_gemm<0, false, true, false><<<gDD, 256, 0, stream>>>(
        hb, Wqt, bq + l * kD, nullptr, t0, nullptr, kD, kD);
    gemm_kernel<1><<<dim3(1, kBS / 64), 256, 0, stream>>>(t0, Pl, pq, kD, kM);
    // k -> t0 ; pk
    mfma_gemm<0, false, true, false><<<gDD, 256, 0, stream>>>(
        hb, Wkt, bk + l * kD, nullptr, t0, nullptr, kD, kD);
    gemm_kernel<1><<<dim3(1, kBS / 64), 256, 0, stream>>>(t0, Pl, pk, kD, kM);
    // v -> t0
    mfma_gemm<0, false, true, false><<<gDD, 256, 0, stream>>>(
        hb, Wvt, bv + l * kD, nullptr, t0, nullptr, kD, kD);
    // kv, pksum, z
    kv_kernel<<<dim3(kD / 64, kB), 256, 0, stream>>>(pk, t0, kvb);
    pksum_kernel<<<kB, 256, 0, stream>>>(pk, pks);
    z_kernel<<<kBS / 4, 256, 0, stream>>>(pq, pks, zb);
    // att -> ab (bf16)
    att_kernel<<<dim3(kD / 64, kS / 64, kB), 256, 0, stream>>>(pq, kvb, zb, ab);
    // att @ Wo + bo -> t0 (f32)
    mfma_gemm<0, false, true, false><<<gDD, 256, 0, stream>>>(
        ab, Wot, bo + l * kD, nullptr, t0, nullptr, kD, kD);
    // LN -> ab (bf16, reused as hn)   [t0 dead after this; F aliases it]
    ln_kernel<<<kBS, 256, 0, stream>>>(t0, ln_g + l * kD, ln_b + l * kD, ab);
    // FFN in 4 row-chunks of 8192:
    //   F = bf16(gelu(hn@W1+b1)) ; h += F@W2+b2 (writes h f32 + hb bf16)
    for (int c = 0; c < 4; ++c) {
      size_t ro = (size_t)c * 8192;
      mfma_gemm<2, false, false, true><<<dim3(kH / 128, 8192 / 128), 256, 0, stream>>>(
          ab + ro * kD, W1t, b1 + l * kH, nullptr, nullptr, F, kD, kH);
      mfma_gemm<0, true, true, true><<<dim3(kD / 128, 8192 / 128), 256, 0, stream>>>(
          F, W2t, b2 + l * kD, h + ro * kD, h + ro * kD, hb + ro * kD, kH, kD);
    }
  }

  cls_kernel<<<kB, 256, 0, stream>>>(h, Wc1, bc1, Wc2, bc2, out);
}

// Round 4
// 3192.947 us; speedup vs baseline: 3.6142x; 1.1247x over previous
//
#include <hip/hip_runtime.h>
#include <hip/hip_bf16.h>
#include <math.h>

constexpr int kV = 32000;
constexpr int kD = 512;
constexpr int kC = 2;
constexpr int kS = 2048;
constexpr int kL = 4;
constexpr int kM = 64;
constexpr int kB = 16;
constexpr int kH = 2048;
constexpr int kBS = kB * kS; // 32768

typedef __hip_bfloat16 bf16;
using bf16x8 = __attribute__((ext_vector_type(8))) short;  // 8 bf16 = 4 VGPRs
using f32x4  = __attribute__((ext_vector_type(4))) float;

#define GLOBAL_LOAD_LDS16(gp, lp)                                              \
  __builtin_amdgcn_global_load_lds(                                            \
      (const __attribute__((address_space(1))) void*)(gp),                     \
      (__attribute__((address_space(3))) void*)(lp), 16, 0, 0)

__device__ inline unsigned short f2bf_u16(float f) {
  bf16 b = __float2bfloat16(f);
  return *reinterpret_cast<unsigned short*>(&b);
}

// ---------------------------------------------------------------------------
// Embedding: h[b,s,:] = embed[x[b,s],:] + pos[s,:]  (writes fp32 h AND bf16 hb)
// ---------------------------------------------------------------------------
__global__ __launch_bounds__(256) void embed_kernel(const int* __restrict__ x,
    const float* __restrict__ emb, const float* __restrict__ pos,
    float* __restrict__ h, bf16* __restrict__ hb) {
  int tid = blockIdx.x * 256 + threadIdx.x;   // over kBS * (kD/4)
  int row = tid >> 7;                          // kD/4 = 128 float4 per row
  int d4  = tid & 127;
  int tok = x[row];
  int s   = row & (kS - 1);
  float4 e = ((const float4*)emb)[(size_t)tok * 128 + d4];
  float4 p = ((const float4*)pos)[(size_t)s * 128 + d4];
  float4 o;
  o.x = e.x + p.x; o.y = e.y + p.y; o.z = e.z + p.z; o.w = e.w + p.w;
  ((float4*)h)[(size_t)row * 128 + d4] = o;
  ushort4 ub;
  ub.x = f2bf_u16(o.x); ub.y = f2bf_u16(o.y);
  ub.z = f2bf_u16(o.z); ub.w = f2bf_u16(o.w);
  ((ushort4*)hb)[(size_t)row * 128 + d4] = ub;
}

// ---------------------------------------------------------------------------
// Transpose + cast: Wt[n][k] = (bf16) W[k][n]
// ---------------------------------------------------------------------------
__global__ __launch_bounds__(256) void transpose_cast_kernel(
    const float* __restrict__ W, bf16* __restrict__ Wt, int K, int N) {
  __shared__ float tile[32][33];
  const int k0 = blockIdx.x * 32, n0 = blockIdx.y * 32;
  int tx = threadIdx.x & 31, ty = threadIdx.x >> 5;  // 32 x 8
#pragma unroll
  for (int i = 0; i < 32; i += 8)
    tile[ty + i][tx] = W[(size_t)(k0 + ty + i) * N + n0 + tx];
  __syncthreads();
#pragma unroll
  for (int i = 0; i < 32; i += 8)
    Wt[(size_t)(n0 + ty + i) * K + k0 + tx] = __float2bfloat16(tile[tx][ty + i]);
}

// ---------------------------------------------------------------------------
// bf16 MFMA GEMM: C = act(A(MxK,bf16) @ Wt(NxK,bf16)^T + bias) [+res]
// 128x128 tile, BK=32, 256 threads (4 waves, each a 64x64 quadrant of 4x4
// 16x16x32 MFMAs). Staging via global_load_lds width=16 (m97 recipe).
// fp32 accumulate; epilogue writes fp32 C and/or bf16 Cb.
// ACT: 0=none, 2=gelu(exact)
// ---------------------------------------------------------------------------
template <int ACT, bool HAS_RES, bool WRITE_F32, bool WRITE_BF16>
__global__ __launch_bounds__(256) void mfma_gemm(
    const bf16* __restrict__ A, const bf16* __restrict__ Wt,
    const float* __restrict__ bias, const float* __restrict__ res,
    float* __restrict__ C, bf16* __restrict__ Cb, int K, int N) {
  __shared__ short As[128 * 32];
  __shared__ short Bs[128 * 32];
  const int tid  = threadIdx.x;
  const int lane = tid & 63;
  const int wave = tid >> 6;
  const int row0 = blockIdx.y * 128;
  const int col0 = blockIdx.x * 128;
  const int wr = (wave & 1) * 64;
  const int wc = (wave >> 1) * 64;
  const int lcol = lane & 15;
  const int quad = lane >> 4;

  f32x4 acc[4][4];
#pragma unroll
  for (int i = 0; i < 4; ++i)
#pragma unroll
    for (int j = 0; j < 4; ++j) acc[i][j] = (f32x4){0.f, 0.f, 0.f, 0.f};

  for (int k0 = 0; k0 < K; k0 += 32) {
    // async staging: wave w, instr p covers LDS bytes [(p*256+w*64)*16, +1024)
#pragma unroll
    for (int p = 0; p < 2; ++p) {
      int idx = p * 256 + tid;
      int r = idx >> 2, kc = idx & 3;
      GLOBAL_LOAD_LDS16(&A[(size_t)(row0 + r) * K + k0 + kc * 8], &As[idx * 8]);
      GLOBAL_LOAD_LDS16(&Wt[(size_t)(col0 + r) * K + k0 + kc * 8], &Bs[idx * 8]);
    }
    __syncthreads();
    bf16x8 af[4], bfr[4];
#pragma unroll
    for (int i = 0; i < 4; ++i)
      af[i] = *(const bf16x8*)&As[(wr + i * 16 + lcol) * 32 + quad * 8];
#pragma unroll
    for (int j = 0; j < 4; ++j)
      bfr[j] = *(const bf16x8*)&Bs[(wc + j * 16 + lcol) * 32 + quad * 8];
#pragma unroll
    for (int i = 0; i < 4; ++i)
#pragma unroll
      for (int j = 0; j < 4; ++j)
        acc[i][j] = __builtin_amdgcn_mfma_f32_16x16x32_bf16(af[i], bfr[j], acc[i][j], 0, 0, 0);
    __syncthreads();
  }

#pragma unroll
  for (int i = 0; i < 4; ++i) {
#pragma unroll
    for (int r = 0; r < 4; ++r) {
      int grow = row0 + wr + i * 16 + quad * 4 + r;
#pragma unroll
      for (int j = 0; j < 4; ++j) {
        int gcol = col0 + wc + j * 16 + lcol;
        float v = acc[i][j][r] + bias[gcol];
        if (ACT == 2) v = 0.5f * v * (1.0f + erff(v * 0.70710678118654752f));
        size_t off = (size_t)grow * N + gcol;
        if (HAS_RES) v += res[off];
        if (WRITE_F32) C[off] = v;
        if (WRITE_BF16) Cb[off] = __float2bfloat16(v);
      }
    }
  }
}

// ---------------------------------------------------------------------------
// fp32 GEMM (kept for the skinny N=64 P-projections): C = elu(A@W)+1
// ---------------------------------------------------------------------------
template <int ACT>
__global__ __launch_bounds__(256) void gemm_kernel(
    const float* __restrict__ A, const float* __restrict__ W,
    float* __restrict__ C, int K, int N) {
  __shared__ float As[16][68];
  __shared__ float Bs[16][64];
  const int tid = threadIdx.x;
  const int tx = tid & 15, ty = tid >> 4;
  const int row0 = blockIdx.y * 64, col0 = blockIdx.x * 64;
  float acc[4][4] = {};
  for (int k0 = 0; k0 < K; k0 += 16) {
    {
      int e = tid * 4;
      int r = e >> 4, kc = e & 15;
      const float4 a4 = *(const float4*)&A[(size_t)(row0 + r) * K + k0 + kc];
      As[kc + 0][r] = a4.x; As[kc + 1][r] = a4.y;
      As[kc + 2][r] = a4.z; As[kc + 3][r] = a4.w;
    }
    {
      int e = tid * 4;
      int kr = e >> 6, nc = e & 63;
      *(float4*)&Bs[kr][nc] = *(const float4*)&W[(size_t)(k0 + kr) * N + col0 + nc];
    }
    __syncthreads();
#pragma unroll
    for (int kk = 0; kk < 16; ++kk) {
      float a[4];
#pragma unroll
      for (int i = 0; i < 4; ++i) a[i] = As[kk][ty * 4 + i];
      float4 b4 = *(const float4*)&Bs[kk][tx * 4];
      float b[4] = {b4.x, b4.y, b4.z, b4.w};
#pragma unroll
      for (int i = 0; i < 4; ++i)
#pragma unroll
        for (int j = 0; j < 4; ++j) acc[i][j] += a[i] * b[j];
    }
    __syncthreads();
  }
#pragma unroll
  for (int i = 0; i < 4; ++i) {
    int r = row0 + ty * 4 + i;
    size_t base = (size_t)r * N + col0 + tx * 4;
    float vals[4];
#pragma unroll
    for (int j = 0; j < 4; ++j) {
      float v = acc[i][j];
      if (ACT == 1) v = (v > 0.f) ? (v + 1.f) : expf(v);
      vals[j] = v;
    }
    *(float4*)&C[base] = make_float4(vals[0], vals[1], vals[2], vals[3]);
  }
}

// ---------------------------------------------------------------------------
// Zero kvb (kB*kM*kD) + pks (kB*kM) — adjacent in ws. 131328 float4s.
// ---------------------------------------------------------------------------
__global__ __launch_bounds__(256) void zero_kvpks_kernel(float* __restrict__ p) {
  int tid = blockIdx.x * 256 + threadIdx.x;
  ((float4*)p)[tid] = make_float4(0.f, 0.f, 0.f, 0.f);
}

// ---------------------------------------------------------------------------
// kv[b,m,d] += sum_{s in chunk} pk[b,s,m] * v[b,s,d]
// grid: (kD/64, kB, 8 s-splits); s-chunk = 256; atomicAdd epilogue
// ---------------------------------------------------------------------------
__global__ __launch_bounds__(256) void kv_split_kernel(const float* __restrict__ pk,
    const float* __restrict__ v, float* __restrict__ kvout) {
  __shared__ float pkS[16][64];
  __shared__ float vS[16][64];
  const int b = blockIdx.y, d0 = blockIdx.x * 64;
  const int s_beg = blockIdx.z * 256;
  const float* pkb = pk + (size_t)b * kS * kM;
  const float* vb  = v  + (size_t)b * kS * kD;
  const int tid = threadIdx.x;
  const int tx = tid & 15, ty = tid >> 4;
  float acc[4][4] = {};
  for (int s0 = s_beg; s0 < s_beg + 256; s0 += 16) {
    {
      int e = tid * 4;
      int sr = e >> 6, mc = e & 63;
      *(float4*)&pkS[sr][mc] = *(const float4*)&pkb[(size_t)(s0 + sr) * kM + mc];
    }
    {
      int e = tid * 4;
      int sr = e >> 6, dc = e & 63;
      *(float4*)&vS[sr][dc] = *(const float4*)&vb[(size_t)(s0 + sr) * kD + d0 + dc];
    }
    __syncthreads();
#pragma unroll
    for (int sr = 0; sr < 16; ++sr) {
      float a[4];
#pragma unroll
      for (int i = 0; i < 4; ++i) a[i] = pkS[sr][ty * 4 + i];
      float4 b4 = *(const float4*)&vS[sr][tx * 4];
      float bb[4] = {b4.x, b4.y, b4.z, b4.w};
#pragma unroll
      for (int i = 0; i < 4; ++i)
#pragma unroll
        for (int j = 0; j < 4; ++j) acc[i][j] += a[i] * bb[j];
    }
    __syncthreads();
  }
#pragma unroll
  for (int i = 0; i < 4; ++i)
#pragma unroll
    for (int j = 0; j < 4; ++j)
      atomicAdd(&kvout[((size_t)b * kM + ty * 4 + i) * kD + d0 + tx * 4 + j],
                acc[i][j]);
}

// ---------------------------------------------------------------------------
// pksum[b,m] += sum_{s in chunk} pk[b,s,m]; grid: kB*16 splits
// ---------------------------------------------------------------------------
__global__ __launch_bounds__(256) void pksum_kernel(const float* __restrict__ pk,
                                                    float* __restrict__ pksum) {
  __shared__ float part[4][64];
  int b = blockIdx.x >> 4;
  int split = blockIdx.x & 15;
  int lane = threadIdx.x & 63, w = threadIdx.x >> 6;
  float s = 0.f;
  int base = split * 128 + w * 32;
  for (int i = 0; i < 32; ++i)
    s += pk[((size_t)b * kS + base + i) * kM + lane];
  part[w][lane] = s;
  __syncthreads();
  if (w == 0)
    atomicAdd(&pksum[b * kM + lane],
              part[0][lane] + part[1][lane] + part[2][lane] + part[3][lane]);
}

// ---------------------------------------------------------------------------
__global__ __launch_bounds__(256) void z_kernel(const float* __restrict__ pq,
    const float* __restrict__ pksum, float* __restrict__ z) {
  int row = blockIdx.x * 4 + (threadIdx.x >> 6);
  int lane = threadIdx.x & 63;
  int b = row >> 11;
  float v = pq[(size_t)row * kM + lane] * pksum[b * kM + lane];
#pragma unroll
  for (int off = 32; off; off >>= 1) v += __shfl_down(v, off);
  if (lane == 0) z[row] = v + 1e-6f;
}

// ---------------------------------------------------------------------------
// att[b,s,d] = (sum_m pq[b,s,m]*kv[b,m,d]) / z[b,s]  -> bf16 out
// ---------------------------------------------------------------------------
__global__ __launch_bounds__(256) void att_kernel(const float* __restrict__ pq,
    const float* __restrict__ kvm, const float* __restrict__ z,
    bf16* __restrict__ out) {
  __shared__ float pqS[64][68];
  __shared__ float kvS[64][68];
  const int d0 = blockIdx.x * 64, s0 = blockIdx.y * 64, b = blockIdx.z;
  const int tid = threadIdx.x;
  const int tx = tid & 15, ty = tid >> 4;
  for (int i = 0; i < 4; ++i) {
    int f = tid + i * 256;
    int r = f >> 4, c = (f & 15) * 4;
    *(float4*)&pqS[r][c] = *(const float4*)&pq[((size_t)(b * kS + s0 + r)) * kM + c];
    *(float4*)&kvS[r][c] = *(const float4*)&kvm[((size_t)b * kM + r) * kD + d0 + c];
  }
  __syncthreads();
  float acc[4][4] = {};
#pragma unroll
  for (int m = 0; m < kM; ++m) {
    float a[4];
#pragma unroll
    for (int i = 0; i < 4; ++i) a[i] = pqS[ty * 4 + i][m];
    float4 b4 = *(const float4*)&kvS[m][tx * 4];
    float bb[4] = {b4.x, b4.y, b4.z, b4.w};
#pragma unroll
    for (int i = 0; i < 4; ++i)
#pragma unroll
      for (int j = 0; j < 4; ++j) acc[i][j] += a[i] * bb[j];
  }
#pragma unroll
  for (int i = 0; i < 4; ++i) {
    int srow = s0 + ty * 4 + i;
    float zi = 1.0f / z[b * kS + srow];
    ushort4 u;
    u.x = f2bf_u16(acc[i][0] * zi);
    u.y = f2bf_u16(acc[i][1] * zi);
    u.z = f2bf_u16(acc[i][2] * zi);
    u.w = f2bf_u16(acc[i][3] * zi);
    *(ushort4*)&out[((size_t)(b * kS + srow)) * kD + d0 + tx * 4] = u;
  }
}

// ---------------------------------------------------------------------------
// LayerNorm over D=512; fp32 in, bf16 out
// ---------------------------------------------------------------------------
__global__ __launch_bounds__(256) void ln_kernel(const float* __restrict__ in,
    const float* __restrict__ g, const float* __restrict__ b,
    bf16* __restrict__ out) {
  __shared__ float ws1[4], ws2[4];
  int row = blockIdx.x, tid = threadIdx.x;
  float2 v = ((const float2*)(in + (size_t)row * kD))[tid];
  float s = v.x + v.y;
#pragma unroll
  for (int off = 32; off; off >>= 1) s += __shfl_down(s, off);
  if ((tid & 63) == 0) ws1[tid >> 6] = s;
  __syncthreads();
  float mean = (ws1[0] + ws1[1] + ws1[2] + ws1[3]) * (1.0f / kD);
  float dx = v.x - mean, dy = v.y - mean;
  float s2 = dx * dx + dy * dy;
#pragma unroll
  for (int off = 32; off; off >>= 1) s2 += __shfl_down(s2, off);
  if ((tid & 63) == 0) ws2[tid >> 6] = s2;
  __syncthreads();
  float var = (ws2[0] + ws2[1] + ws2[2] + ws2[3]) * (1.0f / kD);
  float rstd = rsqrtf(var + 1e-5f);
  float2 gg = ((const float2*)g)[tid];
  float2 bb = ((const float2*)b)[tid];
  ushort2 u;
  u.x = f2bf_u16(dx * rstd * gg.x + bb.x);
  u.y = f2bf_u16(dy * rstd * gg.y + bb.y);
  ((ushort2*)(out + (size_t)row * kD))[tid] = u;
}

// ---------------------------------------------------------------------------
__global__ __launch_bounds__(256) void cls_kernel(const float* __restrict__ h,
    const float* __restrict__ Wc1, const float* __restrict__ bc1,
    const float* __restrict__ Wc2, const float* __restrict__ bc2,
    float* __restrict__ out) {
  __shared__ float r0[4], r1[4];
  int b = blockIdx.x;
  int j = threadIdx.x;
  const float* p = h + (size_t)b * kS * kD;
  float acc = bc1[j];
  for (int i = 0; i < kD; ++i) acc += p[i] * Wc1[i * (kD / 2) + j];
  acc = fmaxf(acc, 0.f);
  float p0 = acc * Wc2[j * kC + 0];
  float p1 = acc * Wc2[j * kC + 1];
#pragma unroll
  for (int off = 32; off; off >>= 1) {
    p0 += __shfl_down(p0, off);
    p1 += __shfl_down(p1, off);
  }
  if ((j & 63) == 0) { r0[j >> 6] = p0; r1[j >> 6] = p1; }
  __syncthreads();
  if (j == 0) {
    out[b * kC + 0] = r0[0] + r0[1] + r0[2] + r0[3] + bc2[0];
    out[b * kC + 1] = r1[0] + r1[1] + r1[2] + r1[3] + bc2[1];
  }
}

// ---------------------------------------------------------------------------
extern "C" void kernel_launch(void* const* d_in, const int* in_sizes, int n_in,
                              void* d_out, int out_size, void* d_ws, size_t ws_size,
                              hipStream_t stream) {
  const int*   x    = (const int*)  d_in[0];
  const float* emb  = (const float*)d_in[1];
  const float* pos  = (const float*)d_in[2];
  const float* Wq   = (const float*)d_in[3];
  const float* bq   = (const float*)d_in[4];
  const float* Wk   = (const float*)d_in[5];
  const float* bk   = (const float*)d_in[6];
  const float* Wv   = (const float*)d_in[7];
  const float* bv   = (const float*)d_in[8];
  const float* P    = (const float*)d_in[9];
  const float* Wo   = (const float*)d_in[10];
  const float* bo   = (const float*)d_in[11];
  const float* ln_g = (const float*)d_in[12];
  const float* ln_b = (const float*)d_in[13];
  const float* W1   = (const float*)d_in[14];
  const float* b1   = (const float*)d_in[15];
  const float* W2   = (const float*)d_in[16];
  const float* b2   = (const float*)d_in[17];
  const float* Wc1  = (const float*)d_in[18];
  const float* bc1  = (const float*)d_in[19];
  const float* Wc2  = (const float*)d_in[20];
  const float* bc2  = (const float*)d_in[21];
  float* out = (float*)d_out;

  // Workspace layout (~216 MB total; proven OK)
  float* h   = (float*)d_ws;                   // kBS*kD f32         64 MB
  float* t0  = h   + (size_t)kBS * kD;         // kBS*kD f32         64 MB (q/k/v, Wo out; F aliases)
  float* pq  = t0  + (size_t)kBS * kD;         // kBS*kM              8 MB
  float* pk  = pq  + (size_t)kBS * kM;         // kBS*kM              8 MB
  float* kvb = pk  + (size_t)kBS * kM;         // kB*kM*kD            2 MB
  float* pks = kvb + (size_t)kB * kM * kD;     // kB*kM   (adjacent to kvb)
  float* zb  = pks + (size_t)kB * kM;          // kBS
  bf16* hb   = (bf16*)(zb + kBS);              // kBS*kD bf16        32 MB
  bf16* ab   = hb + (size_t)kBS * kD;          // kBS*kD bf16        32 MB (att, then hn)
  bf16* Wqt  = ab  + (size_t)kBS * kD;         // per-layer transposed weights, 6 MB
  bf16* Wkt  = Wqt + (size_t)kD * kD;
  bf16* Wvt  = Wkt + (size_t)kD * kD;
  bf16* Wot  = Wvt + (size_t)kD * kD;
  bf16* W1t  = Wot + (size_t)kD * kD;          // kH*kD ([H][D])
  bf16* W2t  = W1t + (size_t)kD * kH;          // kD*kH ([D][H])
  bf16* F    = (bf16*)t0;                      // 8192*kH bf16 aliases t0

  embed_kernel<<<kBS * (kD / 4) / 256, 256, 0, stream>>>(x, emb, pos, h, hb);

  const dim3 gDD(kD / 128, kBS / 128);   // (4, 256)

  for (int l = 0; l < kL; ++l) {
    const float* Pl = P + (size_t)l * kD * kM;

    transpose_cast_kernel<<<dim3(kD / 32, kD / 32), 256, 0, stream>>>(
        Wq + (size_t)l * kD * kD, Wqt, kD, kD);
    transpose_cast_kernel<<<dim3(kD / 32, kD / 32), 256, 0, stream>>>(
        Wk + (size_t)l * kD * kD, Wkt, kD, kD);
    transpose_cast_kernel<<<dim3(kD / 32, kD / 32), 256, 0, stream>>>(
        Wv + (size_t)l * kD * kD, Wvt, kD, kD);
    transpose_cast_kernel<<<dim3(kD / 32, kD / 32), 256, 0, stream>>>(
        Wo + (size_t)l * kD * kD, Wot, kD, kD);
    transpose_cast_kernel<<<dim3(kD / 32, kH / 32), 256, 0, stream>>>(
        W1 + (size_t)l * kD * kH, W1t, kD, kH);
    transpose_cast_kernel<<<dim3(kH / 32, kD / 32), 256, 0, stream>>>(
        W2 + (size_t)l * kH * kD, W2t, kH, kD);

    // q -> t0 (f32) ; pq = elu(q@P)+1
    mfma_gemm<0, false, true, false><<<gDD, 256, 0, stream>>>(
        hb, Wqt, bq + l * kD, nullptr, t0, nullptr, kD, kD);
    gemm_kernel<1><<<dim3(1, kBS / 64), 256, 0, stream>>>(t0, Pl, pq, kD, kM);
    // k -> t0 ; pk
    mfma_gemm<0, false, true, false><<<gDD, 256, 0, stream>>>(
        hb, Wkt, bk + l * kD, nullptr, t0, nullptr, kD, kD);
    gemm_kernel<1><<<dim3(1, kBS / 64), 256, 0, stream>>>(t0, Pl, pk, kD, kM);
    // v -> t0
    mfma_gemm<0, false, true, false><<<gDD, 256, 0, stream>>>(
        hb, Wvt, bv + l * kD, nullptr, t0, nullptr, kD, kD);
    // zero kv+pksum accumulators, then split-S kv / pksum with atomics
    zero_kvpks_kernel<<<(kB * kM * kD + kB * kM) / 1024, 256, 0, stream>>>(kvb);
    kv_split_kernel<<<dim3(kD / 64, kB, 8), 256, 0, stream>>>(pk, t0, kvb);
    pksum_kernel<<<kB * 16, 256, 0, stream>>>(pk, pks);
    z_kernel<<<kBS / 4, 256, 0, stream>>>(pq, pks, zb);
    // att -> ab (bf16)
    att_kernel<<<dim3(kD / 64, kS / 64, kB), 256, 0, stream>>>(pq, kvb, zb, ab);
    // att @ Wo + bo -> t0 (f32)
    mfma_gemm<0, false, true, false><<<gDD, 256, 0, stream>>>(
        ab, Wot, bo + l * kD, nullptr, t0, nullptr, kD, kD);
    // LN -> ab (bf16, reused as hn)   [t0 dead after this; F aliases it]
    ln_kernel<<<kBS, 256, 0, stream>>>(t0, ln_g + l * kD, ln_b + l * kD, ab);
    // FFN in 4 row-chunks of 8192
    for (int c = 0; c < 4; ++c) {
      size_t ro = (size_t)c * 8192;
      mfma_gemm<2, false, false, true><<<dim3(kH / 128, 8192 / 128), 256, 0, stream>>>(
          ab + ro * kD, W1t, b1 + l * kH, nullptr, nullptr, F, kD, kH);
      mfma_gemm<0, true, true, true><<<dim3(kD / 128, 8192 / 128), 256, 0, stream>>>(
          F, W2t, b2 + l * kD, h + ro * kD, h + ro * kD, hb + ro * kD, kH, kD);
    }
  }

  cls_kernel<<<kB, 256, 0, stream>>>(h, Wc1, bc1, Wc2, bc2, out);
}

// Round 5
// 2361.218 us; speedup vs baseline: 4.8873x; 1.3522x over previous
//
#include <hip/hip_runtime.h>
#include <hip/hip_bf16.h>
#include <math.h>

constexpr int kV = 32000;
constexpr int kD = 512;
constexpr int kC = 2;
constexpr int kS = 2048;
constexpr int kL = 4;
constexpr int kM = 64;
constexpr int kB = 16;
constexpr int kH = 2048;
constexpr int kBS = kB * kS; // 32768

typedef __hip_bfloat16 bf16;
using bf16x8 = __attribute__((ext_vector_type(8))) short;  // 8 bf16 = 4 VGPRs
using f32x4  = __attribute__((ext_vector_type(4))) float;

#define GLOBAL_LOAD_LDS16(gp, lp)                                              \
  __builtin_amdgcn_global_load_lds(                                            \
      (const __attribute__((address_space(1))) void*)(gp),                     \
      (__attribute__((address_space(3))) void*)(lp), 16, 0, 0)

__device__ inline unsigned short f2bf_u16(float f) {
  bf16 b = __float2bfloat16(f);
  return *reinterpret_cast<unsigned short*>(&b);
}

// ---------------------------------------------------------------------------
// Embedding: h[b,s,:] = embed[x[b,s],:] + pos[s,:]  (fp32 h AND bf16 hb)
// ---------------------------------------------------------------------------
__global__ __launch_bounds__(256) void embed_kernel(const int* __restrict__ x,
    const float* __restrict__ emb, const float* __restrict__ pos,
    float* __restrict__ h, bf16* __restrict__ hb) {
  int tid = blockIdx.x * 256 + threadIdx.x;
  int row = tid >> 7;
  int d4  = tid & 127;
  int tok = x[row];
  int s   = row & (kS - 1);
  float4 e = ((const float4*)emb)[(size_t)tok * 128 + d4];
  float4 p = ((const float4*)pos)[(size_t)s * 128 + d4];
  float4 o;
  o.x = e.x + p.x; o.y = e.y + p.y; o.z = e.z + p.z; o.w = e.w + p.w;
  ((float4*)h)[(size_t)row * 128 + d4] = o;
  ushort4 ub;
  ub.x = f2bf_u16(o.x); ub.y = f2bf_u16(o.y);
  ub.z = f2bf_u16(o.z); ub.w = f2bf_u16(o.w);
  ((ushort4*)hb)[(size_t)row * 128 + d4] = ub;
}

// ---------------------------------------------------------------------------
// Transpose + cast: Wt[n][k] = (bf16) W[k][n]
// ---------------------------------------------------------------------------
__global__ __launch_bounds__(256) void transpose_cast_kernel(
    const float* __restrict__ W, bf16* __restrict__ Wt, int K, int N) {
  __shared__ float tile[32][33];
  const int k0 = blockIdx.x * 32, n0 = blockIdx.y * 32;
  int tx = threadIdx.x & 31, ty = threadIdx.x >> 5;
#pragma unroll
  for (int i = 0; i < 32; i += 8)
    tile[ty + i][tx] = W[(size_t)(k0 + ty + i) * N + n0 + tx];
  __syncthreads();
#pragma unroll
  for (int i = 0; i < 32; i += 8)
    Wt[(size_t)(n0 + ty + i) * K + k0 + tx] = __float2bfloat16(tile[tx][ty + i]);
}

// ---------------------------------------------------------------------------
// Weight fold: Wt[m][kk] = bf16( sum_c W[kk][c] * P[c][m] )  (W: DxD, P: DxM)
// grid 128 x 256 threads; lane m coalesces P reads, kk broadcast per wave.
// ---------------------------------------------------------------------------
__global__ __launch_bounds__(256) void wfold_kernel(const float* __restrict__ W,
    const float* __restrict__ P, bf16* __restrict__ Wt) {
  int gid = blockIdx.x * 256 + threadIdx.x;
  int m = gid & (kM - 1);
  int kk = gid >> 6;
  float acc = 0.f;
  for (int c = 0; c < kD; ++c) acc += W[(size_t)kk * kD + c] * P[(size_t)c * kM + m];
  Wt[(size_t)m * kD + kk] = __float2bfloat16(acc);
}

// bias fold: bqp[m] = sum_c bq[c]P[c][m]; bkp[m] likewise. 1 block, 128 thr.
__global__ __launch_bounds__(128) void bfold_kernel(const float* __restrict__ bq,
    const float* __restrict__ bk, const float* __restrict__ P,
    float* __restrict__ bqp, float* __restrict__ bkp) {
  int m = threadIdx.x & (kM - 1);
  const float* src = (threadIdx.x >> 6) ? bk : bq;
  float* dst = (threadIdx.x >> 6) ? bkp : bqp;
  float acc = 0.f;
  for (int c = 0; c < kD; ++c) acc += src[c] * P[(size_t)c * kM + m];
  dst[m] = acc;
}

// ---------------------------------------------------------------------------
// bf16 MFMA GEMM: C = act(A @ Wt^T + bias) [+res]; 128x128 tile, BK=32.
// ---------------------------------------------------------------------------
template <int ACT, bool HAS_RES, bool WRITE_F32, bool WRITE_BF16>
__global__ __launch_bounds__(256) void mfma_gemm(
    const bf16* __restrict__ A, const bf16* __restrict__ Wt,
    const float* __restrict__ bias, const float* __restrict__ res,
    float* __restrict__ C, bf16* __restrict__ Cb, int K, int N) {
  __shared__ short As[128 * 32];
  __shared__ short Bs[128 * 32];
  const int tid  = threadIdx.x;
  const int lane = tid & 63;
  const int wave = tid >> 6;
  const int row0 = blockIdx.y * 128;
  const int col0 = blockIdx.x * 128;
  const int wr = (wave & 1) * 64;
  const int wc = (wave >> 1) * 64;
  const int lcol = lane & 15;
  const int quad = lane >> 4;

  f32x4 acc[4][4];
#pragma unroll
  for (int i = 0; i < 4; ++i)
#pragma unroll
    for (int j = 0; j < 4; ++j) acc[i][j] = (f32x4){0.f, 0.f, 0.f, 0.f};

  for (int k0 = 0; k0 < K; k0 += 32) {
#pragma unroll
    for (int p = 0; p < 2; ++p) {
      int idx = p * 256 + tid;
      int r = idx >> 2, kc = idx & 3;
      GLOBAL_LOAD_LDS16(&A[(size_t)(row0 + r) * K + k0 + kc * 8], &As[idx * 8]);
      GLOBAL_LOAD_LDS16(&Wt[(size_t)(col0 + r) * K + k0 + kc * 8], &Bs[idx * 8]);
    }
    __syncthreads();
    bf16x8 af[4], bfr[4];
#pragma unroll
    for (int i = 0; i < 4; ++i)
      af[i] = *(const bf16x8*)&As[(wr + i * 16 + lcol) * 32 + quad * 8];
#pragma unroll
    for (int j = 0; j < 4; ++j)
      bfr[j] = *(const bf16x8*)&Bs[(wc + j * 16 + lcol) * 32 + quad * 8];
#pragma unroll
    for (int i = 0; i < 4; ++i)
#pragma unroll
      for (int j = 0; j < 4; ++j)
        acc[i][j] = __builtin_amdgcn_mfma_f32_16x16x32_bf16(af[i], bfr[j], acc[i][j], 0, 0, 0);
    __syncthreads();
  }

#pragma unroll
  for (int i = 0; i < 4; ++i) {
#pragma unroll
    for (int r = 0; r < 4; ++r) {
      int grow = row0 + wr + i * 16 + quad * 4 + r;
#pragma unroll
      for (int j = 0; j < 4; ++j) {
        int gcol = col0 + wc + j * 16 + lcol;
        float v = acc[i][j][r] + bias[gcol];
        if (ACT == 2) v = 0.5f * v * (1.0f + erff(v * 0.70710678118654752f));
        size_t off = (size_t)grow * N + gcol;
        if (HAS_RES) v += res[off];
        if (WRITE_F32) C[off] = v;
        if (WRITE_BF16) Cb[off] = __float2bfloat16(v);
      }
    }
  }
}

// ---------------------------------------------------------------------------
// Skinny MFMA GEMM (N=64, K=512): C = elu(A @ Wt^T + bias)+1, fp32 out.
// 128 rows/block, 4 waves x 32 rows, full 64 cols per wave.
// ---------------------------------------------------------------------------
__global__ __launch_bounds__(256) void skinny_elu_gemm(
    const bf16* __restrict__ A, const bf16* __restrict__ Wt,
    const float* __restrict__ bias, float* __restrict__ C) {
  __shared__ short As[128 * 32];
  __shared__ short Bs[64 * 32];
  const int tid  = threadIdx.x;
  const int lane = tid & 63;
  const int wave = tid >> 6;
  const int row0 = blockIdx.x * 128;
  const int lcol = lane & 15;
  const int quad = lane >> 4;

  f32x4 acc[2][4];
#pragma unroll
  for (int i = 0; i < 2; ++i)
#pragma unroll
    for (int j = 0; j < 4; ++j) acc[i][j] = (f32x4){0.f, 0.f, 0.f, 0.f};

  for (int k0 = 0; k0 < kD; k0 += 32) {
#pragma unroll
    for (int p = 0; p < 2; ++p) {
      int idx = p * 256 + tid;
      int r = idx >> 2, kc = idx & 3;
      GLOBAL_LOAD_LDS16(&A[(size_t)(row0 + r) * kD + k0 + kc * 8], &As[idx * 8]);
    }
    {
      int r = tid >> 2, kc = tid & 3;
      GLOBAL_LOAD_LDS16(&Wt[(size_t)r * kD + k0 + kc * 8], &Bs[tid * 8]);
    }
    __syncthreads();
    bf16x8 af[2], bfr[4];
#pragma unroll
    for (int i = 0; i < 2; ++i)
      af[i] = *(const bf16x8*)&As[(wave * 32 + i * 16 + lcol) * 32 + quad * 8];
#pragma unroll
    for (int j = 0; j < 4; ++j)
      bfr[j] = *(const bf16x8*)&Bs[(j * 16 + lcol) * 32 + quad * 8];
#pragma unroll
    for (int i = 0; i < 2; ++i)
#pragma unroll
      for (int j = 0; j < 4; ++j)
        acc[i][j] = __builtin_amdgcn_mfma_f32_16x16x32_bf16(af[i], bfr[j], acc[i][j], 0, 0, 0);
    __syncthreads();
  }

#pragma unroll
  for (int i = 0; i < 2; ++i) {
#pragma unroll
    for (int r = 0; r < 4; ++r) {
      int grow = row0 + wave * 32 + i * 16 + quad * 4 + r;
#pragma unroll
      for (int j = 0; j < 4; ++j) {
        int gcol = j * 16 + lcol;
        float v = acc[i][j][r] + bias[gcol];
        v = (v > 0.f) ? (v + 1.f) : expf(v);
        C[(size_t)grow * kM + gcol] = v;
      }
    }
  }
}

// ---------------------------------------------------------------------------
// kv split: part[split][b][m][d] = sum_{s in 128-chunk} pk[b,s,m]*v[b,s,d]
// grid (kD/256, kB, 16); 64m x 256d tile; coalesced float4 stores, no atomics.
// ---------------------------------------------------------------------------
__global__ __launch_bounds__(256) void kv_split_kernel(const float* __restrict__ pk,
    const float* __restrict__ v, float* __restrict__ part) {
  __shared__ float pkS[16][64];
  __shared__ float vS[16][256];
  const int d0 = blockIdx.x * 256, b = blockIdx.y, split = blockIdx.z;
  const int s_beg = split * 128;
  const float* pkb = pk + (size_t)b * kS * kM;
  const float* vb  = v  + (size_t)b * kS * kD;
  const int tid = threadIdx.x;
  const int tx = tid & 15, ty = tid >> 4;
  float4 acc[4][4];
#pragma unroll
  for (int i = 0; i < 4; ++i)
#pragma unroll
    for (int j = 0; j < 4; ++j) acc[i][j] = make_float4(0.f, 0.f, 0.f, 0.f);

  for (int s0 = s_beg; s0 < s_beg + 128; s0 += 16) {
    {
      int e = tid * 4;
      int sr = e >> 6, mc = e & 63;
      *(float4*)&pkS[sr][mc] = *(const float4*)&pkb[(size_t)(s0 + sr) * kM + mc];
    }
#pragma unroll
    for (int p = 0; p < 4; ++p) {
      int idx = p * 256 + tid;
      int sr = idx >> 6, dc = (idx & 63) * 4;
      *(float4*)&vS[sr][dc] = *(const float4*)&vb[(size_t)(s0 + sr) * kD + d0 + dc];
    }
    __syncthreads();
#pragma unroll
    for (int sr = 0; sr < 16; ++sr) {
      float a[4];
#pragma unroll
      for (int i = 0; i < 4; ++i) a[i] = pkS[sr][ty * 4 + i];
      float4 bv[4];
#pragma unroll
      for (int j = 0; j < 4; ++j) bv[j] = *(const float4*)&vS[sr][tx * 16 + j * 4];
#pragma unroll
      for (int i = 0; i < 4; ++i)
#pragma unroll
        for (int j = 0; j < 4; ++j) {
          acc[i][j].x += a[i] * bv[j].x;
          acc[i][j].y += a[i] * bv[j].y;
          acc[i][j].z += a[i] * bv[j].z;
          acc[i][j].w += a[i] * bv[j].w;
        }
    }
    __syncthreads();
  }
  float* pp = part + (((size_t)split * kB + b) * kM) * kD;
#pragma unroll
  for (int i = 0; i < 4; ++i)
#pragma unroll
    for (int j = 0; j < 4; ++j)
      *(float4*)&pp[(size_t)(ty * 4 + i) * kD + d0 + tx * 16 + j * 4] = acc[i][j];
}

// kv_reduce: kvb = sum over 16 partials. 131072 float4s.
__global__ __launch_bounds__(256) void kv_reduce_kernel(const float* __restrict__ part,
                                                        float* __restrict__ kvb) {
  int gid = blockIdx.x * 256 + threadIdx.x;
  float4 s = make_float4(0.f, 0.f, 0.f, 0.f);
#pragma unroll
  for (int sp = 0; sp < 16; ++sp) {
    float4 p = ((const float4*)part)[(size_t)sp * (kB * kM * kD / 4) + gid];
    s.x += p.x; s.y += p.y; s.z += p.z; s.w += p.w;
  }
  ((float4*)kvb)[gid] = s;
}

// ---------------------------------------------------------------------------
__global__ __launch_bounds__(256) void zero_pks_kernel(float* __restrict__ p) {
  ((float4*)p)[threadIdx.x] = make_float4(0.f, 0.f, 0.f, 0.f);
}

__global__ __launch_bounds__(256) void pksum_kernel(const float* __restrict__ pk,
                                                    float* __restrict__ pksum) {
  __shared__ float part[4][64];
  int b = blockIdx.x >> 4;
  int split = blockIdx.x & 15;
  int lane = threadIdx.x & 63, w = threadIdx.x >> 6;
  float s = 0.f;
  int base = split * 128 + w * 32;
  for (int i = 0; i < 32; ++i)
    s += pk[((size_t)b * kS + base + i) * kM + lane];
  part[w][lane] = s;
  __syncthreads();
  if (w == 0)
    atomicAdd(&pksum[b * kM + lane],
              part[0][lane] + part[1][lane] + part[2][lane] + part[3][lane]);
}

// ---------------------------------------------------------------------------
__global__ __launch_bounds__(256) void z_kernel(const float* __restrict__ pq,
    const float* __restrict__ pksum, float* __restrict__ z) {
  int row = blockIdx.x * 4 + (threadIdx.x >> 6);
  int lane = threadIdx.x & 63;
  int b = row >> 11;
  float v = pq[(size_t)row * kM + lane] * pksum[b * kM + lane];
#pragma unroll
  for (int off = 32; off; off >>= 1) v += __shfl_down(v, off);
  if (lane == 0) z[row] = v + 1e-6f;
}

// ---------------------------------------------------------------------------
// att[b,s,d] = (sum_m pq[b,s,m]*kv[b,m,d]) / z[b,s]  -> bf16 out
// ---------------------------------------------------------------------------
__global__ __launch_bounds__(256) void att_kernel(const float* __restrict__ pq,
    const float* __restrict__ kvm, const float* __restrict__ z,
    bf16* __restrict__ out) {
  __shared__ float pqS[64][68];
  __shared__ float kvS[64][68];
  const int d0 = blockIdx.x * 64, s0 = blockIdx.y * 64, b = blockIdx.z;
  const int tid = threadIdx.x;
  const int tx = tid & 15, ty = tid >> 4;
  for (int i = 0; i < 4; ++i) {
    int f = tid + i * 256;
    int r = f >> 4, c = (f & 15) * 4;
    *(float4*)&pqS[r][c] = *(const float4*)&pq[((size_t)(b * kS + s0 + r)) * kM + c];
    *(float4*)&kvS[r][c] = *(const float4*)&kvm[((size_t)b * kM + r) * kD + d0 + c];
  }
  __syncthreads();
  float acc[4][4] = {};
#pragma unroll
  for (int m = 0; m < kM; ++m) {
    float a[4];
#pragma unroll
    for (int i = 0; i < 4; ++i) a[i] = pqS[ty * 4 + i][m];
    float4 b4 = *(const float4*)&kvS[m][tx * 4];
    float bb[4] = {b4.x, b4.y, b4.z, b4.w};
#pragma unroll
    for (int i = 0; i < 4; ++i)
#pragma unroll
      for (int j = 0; j < 4; ++j) acc[i][j] += a[i] * bb[j];
  }
#pragma unroll
  for (int i = 0; i < 4; ++i) {
    int srow = s0 + ty * 4 + i;
    float zi = 1.0f / z[b * kS + srow];
    ushort4 u;
    u.x = f2bf_u16(acc[i][0] * zi);
    u.y = f2bf_u16(acc[i][1] * zi);
    u.z = f2bf_u16(acc[i][2] * zi);
    u.w = f2bf_u16(acc[i][3] * zi);
    *(ushort4*)&out[((size_t)(b * kS + srow)) * kD + d0 + tx * 4] = u;
  }
}

// ---------------------------------------------------------------------------
__global__ __launch_bounds__(256) void ln_kernel(const float* __restrict__ in,
    const float* __restrict__ g, const float* __restrict__ b,
    bf16* __restrict__ out) {
  __shared__ float ws1[4], ws2[4];
  int row = blockIdx.x, tid = threadIdx.x;
  float2 v = ((const float2*)(in + (size_t)row * kD))[tid];
  float s = v.x + v.y;
#pragma unroll
  for (int off = 32; off; off >>= 1) s += __shfl_down(s, off);
  if ((tid & 63) == 0) ws1[tid >> 6] = s;
  __syncthreads();
  float mean = (ws1[0] + ws1[1] + ws1[2] + ws1[3]) * (1.0f / kD);
  float dx = v.x - mean, dy = v.y - mean;
  float s2 = dx * dx + dy * dy;
#pragma unroll
  for (int off = 32; off; off >>= 1) s2 += __shfl_down(s2, off);
  if ((tid & 63) == 0) ws2[tid >> 6] = s2;
  __syncthreads();
  float var = (ws2[0] + ws2[1] + ws2[2] + ws2[3]) * (1.0f / kD);
  float rstd = rsqrtf(var + 1e-5f);
  float2 gg = ((const float2*)g)[tid];
  float2 bb = ((const float2*)b)[tid];
  ushort2 u;
  u.x = f2bf_u16(dx * rstd * gg.x + bb.x);
  u.y = f2bf_u16(dy * rstd * gg.y + bb.y);
  ((ushort2*)(out + (size_t)row * kD))[tid] = u;
}

// ---------------------------------------------------------------------------
__global__ __launch_bounds__(256) void cls_kernel(const float* __restrict__ h,
    const float* __restrict__ Wc1, const float* __restrict__ bc1,
    const float* __restrict__ Wc2, const float* __restrict__ bc2,
    float* __restrict__ out) {
  __shared__ float r0[4], r1[4];
  int b = blockIdx.x;
  int j = threadIdx.x;
  const float* p = h + (size_t)b * kS * kD;
  float acc = bc1[j];
  for (int i = 0; i < kD; ++i) acc += p[i] * Wc1[i * (kD / 2) + j];
  acc = fmaxf(acc, 0.f);
  float p0 = acc * Wc2[j * kC + 0];
  float p1 = acc * Wc2[j * kC + 1];
#pragma unroll
  for (int off = 32; off; off >>= 1) {
    p0 += __shfl_down(p0, off);
    p1 += __shfl_down(p1, off);
  }
  if ((j & 63) == 0) { r0[j >> 6] = p0; r1[j >> 6] = p1; }
  __syncthreads();
  if (j == 0) {
    out[b * kC + 0] = r0[0] + r0[1] + r0[2] + r0[3] + bc2[0];
    out[b * kC + 1] = r1[0] + r1[1] + r1[2] + r1[3] + bc2[1];
  }
}

// ---------------------------------------------------------------------------
extern "C" void kernel_launch(void* const* d_in, const int* in_sizes, int n_in,
                              void* d_out, int out_size, void* d_ws, size_t ws_size,
                              hipStream_t stream) {
  const int*   x    = (const int*)  d_in[0];
  const float* emb  = (const float*)d_in[1];
  const float* pos  = (const float*)d_in[2];
  const float* Wq   = (const float*)d_in[3];
  const float* bq   = (const float*)d_in[4];
  const float* Wk   = (const float*)d_in[5];
  const float* bk   = (const float*)d_in[6];
  const float* Wv   = (const float*)d_in[7];
  const float* bv   = (const float*)d_in[8];
  const float* P    = (const float*)d_in[9];
  const float* Wo   = (const float*)d_in[10];
  const float* bo   = (const float*)d_in[11];
  const float* ln_g = (const float*)d_in[12];
  const float* ln_b = (const float*)d_in[13];
  const float* W1   = (const float*)d_in[14];
  const float* b1   = (const float*)d_in[15];
  const float* W2   = (const float*)d_in[16];
  const float* b2   = (const float*)d_in[17];
  const float* Wc1  = (const float*)d_in[18];
  const float* bc1  = (const float*)d_in[19];
  const float* Wc2  = (const float*)d_in[20];
  const float* bc2  = (const float*)d_in[21];
  float* out = (float*)d_out;

  // Workspace layout (~216 MB; proven OK)
  float* h   = (float*)d_ws;                   // kBS*kD f32         64 MB
  float* t0  = h   + (size_t)kBS * kD;         // kBS*kD f32         64 MB (v, Wo out; F aliases)
  float* pq  = t0  + (size_t)kBS * kD;         // kBS*kM              8 MB
  float* pk  = pq  + (size_t)kBS * kM;         // kBS*kM              8 MB
  float* kvb = pk  + (size_t)kBS * kM;         // kB*kM*kD            2 MB
  float* pks = kvb + (size_t)kB * kM * kD;     // kB*kM
  float* zb  = pks + (size_t)kB * kM;          // kBS
  float* bqp = zb  + kBS;                      // kM (folded biases)
  float* bkp = bqp + kM;                       // kM
  bf16* hb   = (bf16*)(bkp + kM);              // kBS*kD bf16        32 MB
  bf16* ab   = hb + (size_t)kBS * kD;          // kBS*kD bf16        32 MB (kv partials, att, hn)
  bf16* Wqpt = ab  + (size_t)kBS * kD;         // kM*kD folded (Wq@P)^T
  bf16* Wkpt = Wqpt + (size_t)kM * kD;         // kM*kD
  bf16* Wvt  = Wkpt + (size_t)kM * kD;         // kD*kD
  bf16* Wot  = Wvt + (size_t)kD * kD;          // kD*kD
  bf16* W1t  = Wot + (size_t)kD * kD;          // kH*kD
  bf16* W2t  = W1t + (size_t)kD * kH;          // kD*kH
  bf16* F    = (bf16*)t0;                      // 16384*kH bf16 aliases t0 (64 MB)
  float* kvpart = (float*)ab;                  // 16 splits * kB*kM*kD f32 = 32 MB (dead ab)

  embed_kernel<<<kBS * (kD / 4) / 256, 256, 0, stream>>>(x, emb, pos, h, hb);

  const dim3 gDD(kD / 128, kBS / 128);   // (4, 256)

  for (int l = 0; l < kL; ++l) {
    const float* Pl = P + (size_t)l * kD * kM;

    // Fold P into Wq/Wk (exact algebra); transpose-cast Wv/Wo/W1/W2
    wfold_kernel<<<128, 256, 0, stream>>>(Wq + (size_t)l * kD * kD, Pl, Wqpt);
    wfold_kernel<<<128, 256, 0, stream>>>(Wk + (size_t)l * kD * kD, Pl, Wkpt);
    bfold_kernel<<<1, 128, 0, stream>>>(bq + l * kD, bk + l * kD, Pl, bqp, bkp);
    transpose_cast_kernel<<<dim3(kD / 32, kD / 32), 256, 0, stream>>>(
        Wv + (size_t)l * kD * kD, Wvt, kD, kD);
    transpose_cast_kernel<<<dim3(kD / 32, kD / 32), 256, 0, stream>>>(
        Wo + (size_t)l * kD * kD, Wot, kD, kD);
    transpose_cast_kernel<<<dim3(kD / 32, kH / 32), 256, 0, stream>>>(
        W1 + (size_t)l * kD * kH, W1t, kD, kH);
    transpose_cast_kernel<<<dim3(kH / 32, kD / 32), 256, 0, stream>>>(
        W2 + (size_t)l * kH * kD, W2t, kH, kD);

    // pq = elu(h@(WqP) + bq@P)+1 ; pk likewise (skinny MFMA, N=64)
    skinny_elu_gemm<<<kBS / 128, 256, 0, stream>>>(hb, Wqpt, bqp, pq);
    skinny_elu_gemm<<<kBS / 128, 256, 0, stream>>>(hb, Wkpt, bkp, pk);
    // v -> t0 (f32)
    mfma_gemm<0, false, true, false><<<gDD, 256, 0, stream>>>(
        hb, Wvt, bv + l * kD, nullptr, t0, nullptr, kD, kD);
    // kv via split partials (no atomics) + reduce; pksum; z
    kv_split_kernel<<<dim3(kD / 256, kB, 16), 256, 0, stream>>>(pk, t0, kvpart);
    kv_reduce_kernel<<<kB * kM * kD / 1024, 256, 0, stream>>>(kvpart, kvb);
    zero_pks_kernel<<<1, 256, 0, stream>>>(pks);
    pksum_kernel<<<kB * 16, 256, 0, stream>>>(pk, pks);
    z_kernel<<<kBS / 4, 256, 0, stream>>>(pq, pks, zb);
    // att -> ab (bf16)  [kvpart dead; att fully overwrites ab]
    att_kernel<<<dim3(kD / 64, kS / 64, kB), 256, 0, stream>>>(pq, kvb, zb, ab);
    // att @ Wo + bo -> t0 (f32)
    mfma_gemm<0, false, true, false><<<gDD, 256, 0, stream>>>(
        ab, Wot, bo + l * kD, nullptr, t0, nullptr, kD, kD);
    // LN -> ab (bf16 hn)   [t0 dead after this; F aliases it]
    ln_kernel<<<kBS, 256, 0, stream>>>(t0, ln_g + l * kD, ln_b + l * kD, ab);
    // FFN in 2 row-chunks of 16384
    for (int c = 0; c < 2; ++c) {
      size_t ro = (size_t)c * 16384;
      mfma_gemm<2, false, false, true><<<dim3(kH / 128, 16384 / 128), 256, 0, stream>>>(
          ab + ro * kD, W1t, b1 + l * kH, nullptr, nullptr, F, kD, kH);
      mfma_gemm<0, true, true, true><<<dim3(kD / 128, 16384 / 128), 256, 0, stream>>>(
          F, W2t, b2 + l * kD, h + ro * kD, h + ro * kD, hb + ro * kD, kH, kD);
    }
  }

  cls_kernel<<<kB, 256, 0, stream>>>(h, Wc1, bc1, Wc2, bc2, out);
}

// Round 6
// 2252.737 us; speedup vs baseline: 5.1227x; 1.0482x over previous
//
#include <hip/hip_runtime.h>
#include <hip/hip_bf16.h>
#include <math.h>

constexpr int kV = 32000;
constexpr int kD = 512;
constexpr int kC = 2;
constexpr int kS = 2048;
constexpr int kL = 4;
constexpr int kM = 64;
constexpr int kB = 16;
constexpr int kH = 2048;
constexpr int kBS = kB * kS; // 32768

typedef __hip_bfloat16 bf16;
using bf16x8 = __attribute__((ext_vector_type(8))) short;  // 8 bf16 = 4 VGPRs
using f32x4  = __attribute__((ext_vector_type(4))) float;

#define GLOBAL_LOAD_LDS16(gp, lp)                                              \
  __builtin_amdgcn_global_load_lds(                                            \
      (const __attribute__((address_space(1))) void*)(gp),                     \
      (__attribute__((address_space(3))) void*)(lp), 16, 0, 0)

__device__ inline unsigned short f2bf_u16(float f) {
  bf16 b = __float2bfloat16(f);
  return *reinterpret_cast<unsigned short*>(&b);
}

// ---------------------------------------------------------------------------
// Embedding: h[b,s,:] = embed[x[b,s],:] + pos[s,:]  (fp32 h AND bf16 hb)
// ---------------------------------------------------------------------------
__global__ __launch_bounds__(256) void embed_kernel(const int* __restrict__ x,
    const float* __restrict__ emb, const float* __restrict__ pos,
    float* __restrict__ h, bf16* __restrict__ hb) {
  int tid = blockIdx.x * 256 + threadIdx.x;
  int row = tid >> 7;
  int d4  = tid & 127;
  int tok = x[row];
  int s   = row & (kS - 1);
  float4 e = ((const float4*)emb)[(size_t)tok * 128 + d4];
  float4 p = ((const float4*)pos)[(size_t)s * 128 + d4];
  float4 o;
  o.x = e.x + p.x; o.y = e.y + p.y; o.z = e.z + p.z; o.w = e.w + p.w;
  ((float4*)h)[(size_t)row * 128 + d4] = o;
  ushort4 ub;
  ub.x = f2bf_u16(o.x); ub.y = f2bf_u16(o.y);
  ub.z = f2bf_u16(o.z); ub.w = f2bf_u16(o.w);
  ((ushort4*)hb)[(size_t)row * 128 + d4] = ub;
}

// ---------------------------------------------------------------------------
// Transpose + cast: Wt[n][k] = (bf16) W[k][n]
// ---------------------------------------------------------------------------
__global__ __launch_bounds__(256) void transpose_cast_kernel(
    const float* __restrict__ W, bf16* __restrict__ Wt, int K, int N) {
  __shared__ float tile[32][33];
  const int k0 = blockIdx.x * 32, n0 = blockIdx.y * 32;
  int tx = threadIdx.x & 31, ty = threadIdx.x >> 5;
#pragma unroll
  for (int i = 0; i < 32; i += 8)
    tile[ty + i][tx] = W[(size_t)(k0 + ty + i) * N + n0 + tx];
  __syncthreads();
#pragma unroll
  for (int i = 0; i < 32; i += 8)
    Wt[(size_t)(n0 + ty + i) * K + k0 + tx] = __float2bfloat16(tile[tx][ty + i]);
}

// ---------------------------------------------------------------------------
// Weight fold: Wt[m][kk] = bf16( sum_c W[kk][c] * P[c][m] )
// ---------------------------------------------------------------------------
__global__ __launch_bounds__(256) void wfold_kernel(const float* __restrict__ W,
    const float* __restrict__ P, bf16* __restrict__ Wt) {
  int gid = blockIdx.x * 256 + threadIdx.x;
  int m = gid & (kM - 1);
  int kk = gid >> 6;
  float acc = 0.f;
  for (int c = 0; c < kD; ++c) acc += W[(size_t)kk * kD + c] * P[(size_t)c * kM + m];
  Wt[(size_t)m * kD + kk] = __float2bfloat16(acc);
}

__global__ __launch_bounds__(128) void bfold_kernel(const float* __restrict__ bq,
    const float* __restrict__ bk, const float* __restrict__ P,
    float* __restrict__ bqp, float* __restrict__ bkp) {
  int m = threadIdx.x & (kM - 1);
  const float* src = (threadIdx.x >> 6) ? bk : bq;
  float* dst = (threadIdx.x >> 6) ? bkp : bqp;
  float acc = 0.f;
  for (int c = 0; c < kD; ++c) acc += src[c] * P[(size_t)c * kM + m];
  dst[m] = acc;
}

// ---------------------------------------------------------------------------
// bf16 MFMA GEMM: C = act(A @ Wt^T + bias) [+res]; 128x128 tile, BK=32.
// LDS chunk-slot XOR-swizzle ((r>>1)&3) kills the 8-way ds_read conflicts;
// XCD-aware block remap co-locates same-row-tile col-blocks on one XCD.
// ---------------------------------------------------------------------------
template <int ACT, bool HAS_RES, bool WRITE_F32, bool WRITE_BF16>
__global__ __launch_bounds__(256) void mfma_gemm(
    const bf16* __restrict__ A, const bf16* __restrict__ Wt,
    const float* __restrict__ bias, const float* __restrict__ res,
    float* __restrict__ C, bf16* __restrict__ Cb, int K, int N) {
  __shared__ short As[128 * 32];
  __shared__ short Bs[128 * 32];
  const int tid  = threadIdx.x;
  const int lane = tid & 63;
  const int wave = tid >> 6;
  // XCD remap: b = stripe*(nx*8) + c*8 + r8  -> row stripe*8+r8, col c.
  // Same-row col-blocks differ by 8 in linear id => same XCD (id%8), close in time.
  const int nx = gridDim.x;
  const int b_lin = blockIdx.y * nx + blockIdx.x;
  const int stripe = b_lin / (nx * 8);
  const int rem = b_lin - stripe * (nx * 8);
  const int row0 = (stripe * 8 + (rem & 7)) * 128;
  const int col0 = (rem >> 3) * 128;
  const int wr = (wave & 1) * 64;
  const int wc = (wave >> 1) * 64;
  const int lcol = lane & 15;
  const int quad = lane >> 4;

  f32x4 acc[4][4];
#pragma unroll
  for (int i = 0; i < 4; ++i)
#pragma unroll
    for (int j = 0; j < 4; ++j) acc[i][j] = (f32x4){0.f, 0.f, 0.f, 0.f};

  for (int k0 = 0; k0 < K; k0 += 32) {
#pragma unroll
    for (int p = 0; p < 2; ++p) {
      int idx = p * 256 + tid;
      int r = idx >> 2;
      int kc = (idx & 3) ^ ((r >> 1) & 3);   // swizzled source chunk
      GLOBAL_LOAD_LDS16(&A[(size_t)(row0 + r) * K + k0 + kc * 8], &As[idx * 8]);
      GLOBAL_LOAD_LDS16(&Wt[(size_t)(col0 + r) * K + k0 + kc * 8], &Bs[idx * 8]);
    }
    __syncthreads();
    bf16x8 af[4], bfr[4];
#pragma unroll
    for (int i = 0; i < 4; ++i) {
      int rr = wr + i * 16 + lcol;
      af[i] = *(const bf16x8*)&As[(rr * 4 + (quad ^ ((rr >> 1) & 3))) * 8];
    }
#pragma unroll
    for (int j = 0; j < 4; ++j) {
      int rr = wc + j * 16 + lcol;
      bfr[j] = *(const bf16x8*)&Bs[(rr * 4 + (quad ^ ((rr >> 1) & 3))) * 8];
    }
#pragma unroll
    for (int i = 0; i < 4; ++i)
#pragma unroll
      for (int j = 0; j < 4; ++j)
        acc[i][j] = __builtin_amdgcn_mfma_f32_16x16x32_bf16(af[i], bfr[j], acc[i][j], 0, 0, 0);
    __syncthreads();
  }

#pragma unroll
  for (int i = 0; i < 4; ++i) {
#pragma unroll
    for (int r = 0; r < 4; ++r) {
      int grow = row0 + wr + i * 16 + quad * 4 + r;
#pragma unroll
      for (int j = 0; j < 4; ++j) {
        int gcol = col0 + wc + j * 16 + lcol;
        float v = acc[i][j][r] + bias[gcol];
        if (ACT == 2) v = 0.5f * v * (1.0f + erff(v * 0.70710678118654752f));
        size_t off = (size_t)grow * N + gcol;
        if (HAS_RES) v += res[off];
        if (WRITE_F32) C[off] = v;
        if (WRITE_BF16) Cb[off] = __float2bfloat16(v);
      }
    }
  }
}

// ---------------------------------------------------------------------------
// Skinny MFMA GEMM (N=64, K=512): C = elu(A @ Wt^T + bias)+1, fp32 out.
// ---------------------------------------------------------------------------
__global__ __launch_bounds__(256) void skinny_elu_gemm(
    const bf16* __restrict__ A, const bf16* __restrict__ Wt,
    const float* __restrict__ bias, float* __restrict__ C) {
  __shared__ short As[128 * 32];
  __shared__ short Bs[64 * 32];
  const int tid  = threadIdx.x;
  const int lane = tid & 63;
  const int wave = tid >> 6;
  const int row0 = blockIdx.x * 128;
  const int lcol = lane & 15;
  const int quad = lane >> 4;

  f32x4 acc[2][4];
#pragma unroll
  for (int i = 0; i < 2; ++i)
#pragma unroll
    for (int j = 0; j < 4; ++j) acc[i][j] = (f32x4){0.f, 0.f, 0.f, 0.f};

  for (int k0 = 0; k0 < kD; k0 += 32) {
#pragma unroll
    for (int p = 0; p < 2; ++p) {
      int idx = p * 256 + tid;
      int r = idx >> 2;
      int kc = (idx & 3) ^ ((r >> 1) & 3);
      GLOBAL_LOAD_LDS16(&A[(size_t)(row0 + r) * kD + k0 + kc * 8], &As[idx * 8]);
    }
    {
      int r = tid >> 2;
      int kc = (tid & 3) ^ ((r >> 1) & 3);
      GLOBAL_LOAD_LDS16(&Wt[(size_t)r * kD + k0 + kc * 8], &Bs[tid * 8]);
    }
    __syncthreads();
    bf16x8 af[2], bfr[4];
#pragma unroll
    for (int i = 0; i < 2; ++i) {
      int rr = wave * 32 + i * 16 + lcol;
      af[i] = *(const bf16x8*)&As[(rr * 4 + (quad ^ ((rr >> 1) & 3))) * 8];
    }
#pragma unroll
    for (int j = 0; j < 4; ++j) {
      int rr = j * 16 + lcol;
      bfr[j] = *(const bf16x8*)&Bs[(rr * 4 + (quad ^ ((rr >> 1) & 3))) * 8];
    }
#pragma unroll
    for (int i = 0; i < 2; ++i)
#pragma unroll
      for (int j = 0; j < 4; ++j)
        acc[i][j] = __builtin_amdgcn_mfma_f32_16x16x32_bf16(af[i], bfr[j], acc[i][j], 0, 0, 0);
    __syncthreads();
  }

#pragma unroll
  for (int i = 0; i < 2; ++i) {
#pragma unroll
    for (int r = 0; r < 4; ++r) {
      int grow = row0 + wave * 32 + i * 16 + quad * 4 + r;
#pragma unroll
      for (int j = 0; j < 4; ++j) {
        int gcol = j * 16 + lcol;
        float v = acc[i][j][r] + bias[gcol];
        v = (v > 0.f) ? (v + 1.f) : expf(v);
        C[(size_t)grow * kM + gcol] = v;
      }
    }
  }
}

// ---------------------------------------------------------------------------
// kv split: part[split][b][m][d] = sum_{s in 128-chunk} pk[b,s,m]*v[b,s,d]
// ---------------------------------------------------------------------------
__global__ __launch_bounds__(256) void kv_split_kernel(const float* __restrict__ pk,
    const float* __restrict__ v, float* __restrict__ part) {
  __shared__ float pkS[16][64];
  __shared__ float vS[16][256];
  const int d0 = blockIdx.x * 256, b = blockIdx.y, split = blockIdx.z;
  const int s_beg = split * 128;
  const float* pkb = pk + (size_t)b * kS * kM;
  const float* vb  = v  + (size_t)b * kS * kD;
  const int tid = threadIdx.x;
  const int tx = tid & 15, ty = tid >> 4;
  float4 acc[4][4];
#pragma unroll
  for (int i = 0; i < 4; ++i)
#pragma unroll
    for (int j = 0; j < 4; ++j) acc[i][j] = make_float4(0.f, 0.f, 0.f, 0.f);

  for (int s0 = s_beg; s0 < s_beg + 128; s0 += 16) {
    {
      int e = tid * 4;
      int sr = e >> 6, mc = e & 63;
      *(float4*)&pkS[sr][mc] = *(const float4*)&pkb[(size_t)(s0 + sr) * kM + mc];
    }
#pragma unroll
    for (int p = 0; p < 4; ++p) {
      int idx = p * 256 + tid;
      int sr = idx >> 6, dc = (idx & 63) * 4;
      *(float4*)&vS[sr][dc] = *(const float4*)&vb[(size_t)(s0 + sr) * kD + d0 + dc];
    }
    __syncthreads();
#pragma unroll
    for (int sr = 0; sr < 16; ++sr) {
      float a[4];
#pragma unroll
      for (int i = 0; i < 4; ++i) a[i] = pkS[sr][ty * 4 + i];
      float4 bv[4];
#pragma unroll
      for (int j = 0; j < 4; ++j) bv[j] = *(const float4*)&vS[sr][tx * 16 + j * 4];
#pragma unroll
      for (int i = 0; i < 4; ++i)
#pragma unroll
        for (int j = 0; j < 4; ++j) {
          acc[i][j].x += a[i] * bv[j].x;
          acc[i][j].y += a[i] * bv[j].y;
          acc[i][j].z += a[i] * bv[j].z;
          acc[i][j].w += a[i] * bv[j].w;
        }
    }
    __syncthreads();
  }
  float* pp = part + (((size_t)split * kB + b) * kM) * kD;
#pragma unroll
  for (int i = 0; i < 4; ++i)
#pragma unroll
    for (int j = 0; j < 4; ++j)
      *(float4*)&pp[(size_t)(ty * 4 + i) * kD + d0 + tx * 16 + j * 4] = acc[i][j];
}

__global__ __launch_bounds__(256) void kv_reduce_kernel(const float* __restrict__ part,
                                                        float* __restrict__ kvb) {
  int gid = blockIdx.x * 256 + threadIdx.x;
  float4 s = make_float4(0.f, 0.f, 0.f, 0.f);
#pragma unroll
  for (int sp = 0; sp < 16; ++sp) {
    float4 p = ((const float4*)part)[(size_t)sp * (kB * kM * kD / 4) + gid];
    s.x += p.x; s.y += p.y; s.z += p.z; s.w += p.w;
  }
  ((float4*)kvb)[gid] = s;
}

// ---------------------------------------------------------------------------
__global__ __launch_bounds__(256) void zero_pks_kernel(float* __restrict__ p) {
  ((float4*)p)[threadIdx.x] = make_float4(0.f, 0.f, 0.f, 0.f);
}

__global__ __launch_bounds__(256) void pksum_kernel(const float* __restrict__ pk,
                                                    float* __restrict__ pksum) {
  __shared__ float part[4][64];
  int b = blockIdx.x >> 4;
  int split = blockIdx.x & 15;
  int lane = threadIdx.x & 63, w = threadIdx.x >> 6;
  float s = 0.f;
  int base = split * 128 + w * 32;
  for (int i = 0; i < 32; ++i)
    s += pk[((size_t)b * kS + base + i) * kM + lane];
  part[w][lane] = s;
  __syncthreads();
  if (w == 0)
    atomicAdd(&pksum[b * kM + lane],
              part[0][lane] + part[1][lane] + part[2][lane] + part[3][lane]);
}

// ---------------------------------------------------------------------------
__global__ __launch_bounds__(256) void z_kernel(const float* __restrict__ pq,
    const float* __restrict__ pksum, float* __restrict__ z) {
  int row = blockIdx.x * 4 + (threadIdx.x >> 6);
  int lane = threadIdx.x & 63;
  int b = row >> 11;
  float v = pq[(size_t)row * kM + lane] * pksum[b * kM + lane];
#pragma unroll
  for (int off = 32; off; off >>= 1) v += __shfl_down(v, off);
  if (lane == 0) z[row] = v + 1e-6f;
}

// ---------------------------------------------------------------------------
// att[b,s,d] = (sum_m pq[b,s,m]*kv[b,m,d]) / z[b,s]  -> bf16 out
// ---------------------------------------------------------------------------
__global__ __launch_bounds__(256) void att_kernel(const float* __restrict__ pq,
    const float* __restrict__ kvm, const float* __restrict__ z,
    bf16* __restrict__ out) {
  __shared__ float pqS[64][68];
  __shared__ float kvS[64][68];
  const int d0 = blockIdx.x * 64, s0 = blockIdx.y * 64, b = blockIdx.z;
  const int tid = threadIdx.x;
  const int tx = tid & 15, ty = tid >> 4;
  for (int i = 0; i < 4; ++i) {
    int f = tid + i * 256;
    int r = f >> 4, c = (f & 15) * 4;
    *(float4*)&pqS[r][c] = *(const float4*)&pq[((size_t)(b * kS + s0 + r)) * kM + c];
    *(float4*)&kvS[r][c] = *(const float4*)&kvm[((size_t)b * kM + r) * kD + d0 + c];
  }
  __syncthreads();
  float acc[4][4] = {};
#pragma unroll
  for (int m = 0; m < kM; ++m) {
    float a[4];
#pragma unroll
    for (int i = 0; i < 4; ++i) a[i] = pqS[ty * 4 + i][m];
    float4 b4 = *(const float4*)&kvS[m][tx * 4];
    float bb[4] = {b4.x, b4.y, b4.z, b4.w};
#pragma unroll
    for (int i = 0; i < 4; ++i)
#pragma unroll
      for (int j = 0; j < 4; ++j) acc[i][j] += a[i] * bb[j];
  }
#pragma unroll
  for (int i = 0; i < 4; ++i) {
    int srow = s0 + ty * 4 + i;
    float zi = 1.0f / z[b * kS + srow];
    ushort4 u;
    u.x = f2bf_u16(acc[i][0] * zi);
    u.y = f2bf_u16(acc[i][1] * zi);
    u.z = f2bf_u16(acc[i][2] * zi);
    u.w = f2bf_u16(acc[i][3] * zi);
    *(ushort4*)&out[((size_t)(b * kS + srow)) * kD + d0 + tx * 4] = u;
  }
}

// ---------------------------------------------------------------------------
__global__ __launch_bounds__(256) void ln_kernel(const float* __restrict__ in,
    const float* __restrict__ g, const float* __restrict__ b,
    bf16* __restrict__ out) {
  __shared__ float ws1[4], ws2[4];
  int row = blockIdx.x, tid = threadIdx.x;
  float2 v = ((const float2*)(in + (size_t)row * kD))[tid];
  float s = v.x + v.y;
#pragma unroll
  for (int off = 32; off; off >>= 1) s += __shfl_down(s, off);
  if ((tid & 63) == 0) ws1[tid >> 6] = s;
  __syncthreads();
  float mean = (ws1[0] + ws1[1] + ws1[2] + ws1[3]) * (1.0f / kD);
  float dx = v.x - mean, dy = v.y - mean;
  float s2 = dx * dx + dy * dy;
#pragma unroll
  for (int off = 32; off; off >>= 1) s2 += __shfl_down(s2, off);
  if ((tid & 63) == 0) ws2[tid >> 6] = s2;
  __syncthreads();
  float var = (ws2[0] + ws2[1] + ws2[2] + ws2[3]) * (1.0f / kD);
  float rstd = rsqrtf(var + 1e-5f);
  float2 gg = ((const float2*)g)[tid];
  float2 bb = ((const float2*)b)[tid];
  ushort2 u;
  u.x = f2bf_u16(dx * rstd * gg.x + bb.x);
  u.y = f2bf_u16(dy * rstd * gg.y + bb.y);
  ((ushort2*)(out + (size_t)row * kD))[tid] = u;
}

// ---------------------------------------------------------------------------
__global__ __launch_bounds__(256) void cls_kernel(const float* __restrict__ h,
    const float* __restrict__ Wc1, const float* __restrict__ bc1,
    const float* __restrict__ Wc2, const float* __restrict__ bc2,
    float* __restrict__ out) {
  __shared__ float r0[4], r1[4];
  int b = blockIdx.x;
  int j = threadIdx.x;
  const float* p = h + (size_t)b * kS * kD;
  float acc = bc1[j];
  for (int i = 0; i < kD; ++i) acc += p[i] * Wc1[i * (kD / 2) + j];
  acc = fmaxf(acc, 0.f);
  float p0 = acc * Wc2[j * kC + 0];
  float p1 = acc * Wc2[j * kC + 1];
#pragma unroll
  for (int off = 32; off; off >>= 1) {
    p0 += __shfl_down(p0, off);
    p1 += __shfl_down(p1, off);
  }
  if ((j & 63) == 0) { r0[j >> 6] = p0; r1[j >> 6] = p1; }
  __syncthreads();
  if (j == 0) {
    out[b * kC + 0] = r0[0] + r0[1] + r0[2] + r0[3] + bc2[0];
    out[b * kC + 1] = r1[0] + r1[1] + r1[2] + r1[3] + bc2[1];
  }
}

// ---------------------------------------------------------------------------
extern "C" void kernel_launch(void* const* d_in, const int* in_sizes, int n_in,
                              void* d_out, int out_size, void* d_ws, size_t ws_size,
                              hipStream_t stream) {
  const int*   x    = (const int*)  d_in[0];
  const float* emb  = (const float*)d_in[1];
  const float* pos  = (const float*)d_in[2];
  const float* Wq   = (const float*)d_in[3];
  const float* bq   = (const float*)d_in[4];
  const float* Wk   = (const float*)d_in[5];
  const float* bk   = (const float*)d_in[6];
  const float* Wv   = (const float*)d_in[7];
  const float* bv   = (const float*)d_in[8];
  const float* P    = (const float*)d_in[9];
  const float* Wo   = (const float*)d_in[10];
  const float* bo   = (const float*)d_in[11];
  const float* ln_g = (const float*)d_in[12];
  const float* ln_b = (const float*)d_in[13];
  const float* W1   = (const float*)d_in[14];
  const float* b1   = (const float*)d_in[15];
  const float* W2   = (const float*)d_in[16];
  const float* b2   = (const float*)d_in[17];
  const float* Wc1  = (const float*)d_in[18];
  const float* bc1  = (const float*)d_in[19];
  const float* Wc2  = (const float*)d_in[20];
  const float* bc2  = (const float*)d_in[21];
  float* out = (float*)d_out;

  // Workspace layout (~216 MB; proven OK)
  float* h   = (float*)d_ws;                   // kBS*kD f32         64 MB
  float* t0  = h   + (size_t)kBS * kD;         // kBS*kD f32         64 MB (v, Wo out; F aliases)
  float* pq  = t0  + (size_t)kBS * kD;         // kBS*kM              8 MB
  float* pk  = pq  + (size_t)kBS * kM;         // kBS*kM              8 MB
  float* kvb = pk  + (size_t)kBS * kM;         // kB*kM*kD            2 MB
  float* pks = kvb + (size_t)kB * kM * kD;     // kB*kM
  float* zb  = pks + (size_t)kB * kM;          // kBS
  float* bqp = zb  + kBS;                      // kM (folded biases)
  float* bkp = bqp + kM;                       // kM
  bf16* hb   = (bf16*)(bkp + kM);              // kBS*kD bf16        32 MB
  bf16* ab   = hb + (size_t)kBS * kD;          // kBS*kD bf16        32 MB (kv partials, att, hn)
  bf16* Wqpt = ab  + (size_t)kBS * kD;         // kM*kD folded (Wq@P)^T
  bf16* Wkpt = Wqpt + (size_t)kM * kD;         // kM*kD
  bf16* Wvt  = Wkpt + (size_t)kM * kD;         // kD*kD
  bf16* Wot  = Wvt + (size_t)kD * kD;          // kD*kD
  bf16* W1t  = Wot + (size_t)kD * kD;          // kH*kD
  bf16* W2t  = W1t + (size_t)kD * kH;          // kD*kH
  bf16* F    = (bf16*)t0;                      // 16384*kH bf16 aliases t0 (64 MB)
  float* kvpart = (float*)ab;                  // 16 splits * kB*kM*kD f32 = 32 MB (dead ab)

  embed_kernel<<<kBS * (kD / 4) / 256, 256, 0, stream>>>(x, emb, pos, h, hb);

  const dim3 gDD(kD / 128, kBS / 128);   // (4, 256)

  for (int l = 0; l < kL; ++l) {
    const float* Pl = P + (size_t)l * kD * kM;

    // Fold P into Wq/Wk (exact algebra); transpose-cast Wv/Wo/W1/W2
    wfold_kernel<<<128, 256, 0, stream>>>(Wq + (size_t)l * kD * kD, Pl, Wqpt);
    wfold_kernel<<<128, 256, 0, stream>>>(Wk + (size_t)l * kD * kD, Pl, Wkpt);
    bfold_kernel<<<1, 128, 0, stream>>>(bq + l * kD, bk + l * kD, Pl, bqp, bkp);
    transpose_cast_kernel<<<dim3(kD / 32, kD / 32), 256, 0, stream>>>(
        Wv + (size_t)l * kD * kD, Wvt, kD, kD);
    transpose_cast_kernel<<<dim3(kD / 32, kD / 32), 256, 0, stream>>>(
        Wo + (size_t)l * kD * kD, Wot, kD, kD);
    transpose_cast_kernel<<<dim3(kD / 32, kH / 32), 256, 0, stream>>>(
        W1 + (size_t)l * kD * kH, W1t, kD, kH);
    transpose_cast_kernel<<<dim3(kH / 32, kD / 32), 256, 0, stream>>>(
        W2 + (size_t)l * kH * kD, W2t, kH, kD);

    // pq = elu(h@(WqP) + bq@P)+1 ; pk likewise (skinny MFMA, N=64)
    skinny_elu_gemm<<<kBS / 128, 256, 0, stream>>>(hb, Wqpt, bqp, pq);
    skinny_elu_gemm<<<kBS / 128, 256, 0, stream>>>(hb, Wkpt, bkp, pk);
    // v -> t0 (f32)
    mfma_gemm<0, false, true, false><<<gDD, 256, 0, stream>>>(
        hb, Wvt, bv + l * kD, nullptr, t0, nullptr, kD, kD);
    // kv via split partials (no atomics) + reduce; pksum; z
    kv_split_kernel<<<dim3(kD / 256, kB, 16), 256, 0, stream>>>(pk, t0, kvpart);
    kv_reduce_kernel<<<kB * kM * kD / 1024, 256, 0, stream>>>(kvpart, kvb);
    zero_pks_kernel<<<1, 256, 0, stream>>>(pks);
    pksum_kernel<<<kB * 16, 256, 0, stream>>>(pk, pks);
    z_kernel<<<kBS / 4, 256, 0, stream>>>(pq, pks, zb);
    // att -> ab (bf16)  [kvpart dead; att fully overwrites ab]
    att_kernel<<<dim3(kD / 64, kS / 64, kB), 256, 0, stream>>>(pq, kvb, zb, ab);
    // att @ Wo + bo -> t0 (f32)
    mfma_gemm<0, false, true, false><<<gDD, 256, 0, stream>>>(
        ab, Wot, bo + l * kD, nullptr, t0, nullptr, kD, kD);
    // LN -> ab (bf16 hn)   [t0 dead after this; F aliases it]
    ln_kernel<<<kBS, 256, 0, stream>>>(t0, ln_g + l * kD, ln_b + l * kD, ab);
    // FFN in 2 row-chunks of 16384
    for (int c = 0; c < 2; ++c) {
      size_t ro = (size_t)c * 16384;
      mfma_gemm<2, false, false, true><<<dim3(kH / 128, 16384 / 128), 256, 0, stream>>>(
          ab + ro * kD, W1t, b1 + l * kH, nullptr, nullptr, F, kD, kH);
      mfma_gemm<0, true, true, true><<<dim3(kD / 128, 16384 / 128), 256, 0, stream>>>(
          F, W2t, b2 + l * kD, h + ro * kD, h + ro * kD, hb + ro * kD, kH, kD);
    }
  }

  cls_kernel<<<kB, 256, 0, stream>>>(h, Wc1, bc1, Wc2, bc2, out);
}

// Round 7
// 2195.758 us; speedup vs baseline: 5.2556x; 1.0259x over previous
//
#include <hip/hip_runtime.h>
#include <hip/hip_bf16.h>
#include <math.h>

constexpr int kV = 32000;
constexpr int kD = 512;
constexpr int kC = 2;
constexpr int kS = 2048;
constexpr int kL = 4;
constexpr int kM = 64;
constexpr int kB = 16;
constexpr int kH = 2048;
constexpr int kBS = kB * kS; // 32768

typedef __hip_bfloat16 bf16;
using bf16x8 = __attribute__((ext_vector_type(8))) short;
using f32x4  = __attribute__((ext_vector_type(4))) float;

#define GLOBAL_LOAD_LDS16(gp, lp)                                              \
  __builtin_amdgcn_global_load_lds(                                            \
      (const __attribute__((address_space(1))) void*)(gp),                     \
      (__attribute__((address_space(3))) void*)(lp), 16, 0, 0)

__device__ inline unsigned short f2bf_u16(float f) {
  bf16 b = __float2bfloat16(f);
  return *reinterpret_cast<unsigned short*>(&b);
}

// ---------------------------------------------------------------------------
__global__ __launch_bounds__(256) void embed_kernel(const int* __restrict__ x,
    const float* __restrict__ emb, const float* __restrict__ pos,
    float* __restrict__ h, bf16* __restrict__ hb) {
  int tid = blockIdx.x * 256 + threadIdx.x;
  int row = tid >> 7;
  int d4  = tid & 127;
  int tok = x[row];
  int s   = row & (kS - 1);
  float4 e = ((const float4*)emb)[(size_t)tok * 128 + d4];
  float4 p = ((const float4*)pos)[(size_t)s * 128 + d4];
  float4 o;
  o.x = e.x + p.x; o.y = e.y + p.y; o.z = e.z + p.z; o.w = e.w + p.w;
  ((float4*)h)[(size_t)row * 128 + d4] = o;
  ushort4 ub;
  ub.x = f2bf_u16(o.x); ub.y = f2bf_u16(o.y);
  ub.z = f2bf_u16(o.z); ub.w = f2bf_u16(o.w);
  ((ushort4*)hb)[(size_t)row * 128 + d4] = ub;
}

// ---------------------------------------------------------------------------
__global__ __launch_bounds__(256) void transpose_cast_kernel(
    const float* __restrict__ W, bf16* __restrict__ Wt, int K, int N) {
  __shared__ float tile[32][33];
  const int k0 = blockIdx.x * 32, n0 = blockIdx.y * 32;
  int tx = threadIdx.x & 31, ty = threadIdx.x >> 5;
#pragma unroll
  for (int i = 0; i < 32; i += 8)
    tile[ty + i][tx] = W[(size_t)(k0 + ty + i) * N + n0 + tx];
  __syncthreads();
#pragma unroll
  for (int i = 0; i < 32; i += 8)
    Wt[(size_t)(n0 + ty + i) * K + k0 + tx] = __float2bfloat16(tile[tx][ty + i]);
}

// ---------------------------------------------------------------------------
__global__ __launch_bounds__(256) void wfold_kernel(const float* __restrict__ W,
    const float* __restrict__ P, bf16* __restrict__ Wt) {
  int gid = blockIdx.x * 256 + threadIdx.x;
  int m = gid & (kM - 1);
  int kk = gid >> 6;
  float acc = 0.f;
  for (int c = 0; c < kD; ++c) acc += W[(size_t)kk * kD + c] * P[(size_t)c * kM + m];
  Wt[(size_t)m * kD + kk] = __float2bfloat16(acc);
}

__global__ __launch_bounds__(128) void bfold_kernel(const float* __restrict__ bq,
    const float* __restrict__ bk, const float* __restrict__ P,
    float* __restrict__ bqp, float* __restrict__ bkp) {
  int m = threadIdx.x & (kM - 1);
  const float* src = (threadIdx.x >> 6) ? bk : bq;
  float* dst = (threadIdx.x >> 6) ? bkp : bqp;
  float acc = 0.f;
  for (int c = 0; c < kD; ++c) acc += src[c] * P[(size_t)c * kM + m];
  dst[m] = acc;
}

// ---------------------------------------------------------------------------
// bf16 MFMA GEMM, tile 128 x BN (BN=128 or 64), BK=32, 256 threads.
// BN=64 doubles the grid for N=512 GEMMs (occupancy/latency fix).
// XOR-swizzled LDS (0 bank conflicts) + XCD-aware block remap.
// ---------------------------------------------------------------------------
template <int BN, int ACT, bool HAS_RES, bool WRITE_F32, bool WRITE_BF16>
__global__ __launch_bounds__(256) void mfma_gemm(
    const bf16* __restrict__ A, const bf16* __restrict__ Wt,
    const float* __restrict__ bias, const float* __restrict__ res,
    float* __restrict__ C, bf16* __restrict__ Cb, int K, int N) {
  constexpr int NJ = BN / 32;                 // col tiles per wave
  __shared__ short As[128 * 32];
  __shared__ short Bs[BN * 32];
  const int tid  = threadIdx.x;
  const int lane = tid & 63;
  const int wave = tid >> 6;
  const int nx = gridDim.x;
  const int b_lin = blockIdx.y * nx + blockIdx.x;
  const int stripe = b_lin / (nx * 8);
  const int rem = b_lin - stripe * (nx * 8);
  const int row0 = (stripe * 8 + (rem & 7)) * 128;
  const int col0 = (rem >> 3) * BN;
  const int wr = (wave & 1) * 64;
  const int wc = (wave >> 1) * (BN / 2);
  const int lcol = lane & 15;
  const int quad = lane >> 4;

  f32x4 acc[4][NJ];
#pragma unroll
  for (int i = 0; i < 4; ++i)
#pragma unroll
    for (int j = 0; j < NJ; ++j) acc[i][j] = (f32x4){0.f, 0.f, 0.f, 0.f};

  for (int k0 = 0; k0 < K; k0 += 32) {
#pragma unroll
    for (int p = 0; p < 2; ++p) {
      int idx = p * 256 + tid;
      int r = idx >> 2;
      int kc = (idx & 3) ^ ((r >> 1) & 3);
      GLOBAL_LOAD_LDS16(&A[(size_t)(row0 + r) * K + k0 + kc * 8], &As[idx * 8]);
    }
    if (BN == 128) {
#pragma unroll
      for (int p = 0; p < 2; ++p) {
        int idx = p * 256 + tid;
        int r = idx >> 2;
        int kc = (idx & 3) ^ ((r >> 1) & 3);
        GLOBAL_LOAD_LDS16(&Wt[(size_t)(col0 + r) * K + k0 + kc * 8], &Bs[idx * 8]);
      }
    } else {
      int r = tid >> 2;
      int kc = (tid & 3) ^ ((r >> 1) & 3);
      GLOBAL_LOAD_LDS16(&Wt[(size_t)(col0 + r) * K + k0 + kc * 8], &Bs[tid * 8]);
    }
    __syncthreads();
    bf16x8 af[4], bfr[NJ];
#pragma unroll
    for (int i = 0; i < 4; ++i) {
      int rr = wr + i * 16 + lcol;
      af[i] = *(const bf16x8*)&As[(rr * 4 + (quad ^ ((rr >> 1) & 3))) * 8];
    }
#pragma unroll
    for (int j = 0; j < NJ; ++j) {
      int rr = wc + j * 16 + lcol;
      bfr[j] = *(const bf16x8*)&Bs[(rr * 4 + (quad ^ ((rr >> 1) & 3))) * 8];
    }
#pragma unroll
    for (int i = 0; i < 4; ++i)
#pragma unroll
      for (int j = 0; j < NJ; ++j)
        acc[i][j] = __builtin_amdgcn_mfma_f32_16x16x32_bf16(af[i], bfr[j], acc[i][j], 0, 0, 0);
    __syncthreads();
  }

#pragma unroll
  for (int i = 0; i < 4; ++i) {
#pragma unroll
    for (int r = 0; r < 4; ++r) {
      int grow = row0 + wr + i * 16 + quad * 4 + r;
#pragma unroll
      for (int j = 0; j < NJ; ++j) {
        int gcol = col0 + wc + j * 16 + lcol;
        float v = acc[i][j][r] + bias[gcol];
        if (ACT == 2) v = 0.5f * v * (1.0f + erff(v * 0.70710678118654752f));
        size_t off = (size_t)grow * N + gcol;
        if (HAS_RES) v += res[off];
        if (WRITE_F32) C[off] = v;
        if (WRITE_BF16) Cb[off] = __float2bfloat16(v);
      }
    }
  }
}

// ---------------------------------------------------------------------------
// Skinny MFMA GEMM (N=64, K=512): C = elu(A @ Wt^T + bias)+1, fp32 out.
// BM=64, 512 blocks (2/CU); each wave handles one 16-col tile, 4 row tiles.
// ---------------------------------------------------------------------------
__global__ __launch_bounds__(256) void skinny_elu_gemm(
    const bf16* __restrict__ A, const bf16* __restrict__ Wt,
    const float* __restrict__ bias, float* __restrict__ C) {
  __shared__ short As[64 * 32];
  __shared__ short Bs[64 * 32];
  const int tid  = threadIdx.x;
  const int lane = tid & 63;
  const int wave = tid >> 6;
  const int row0 = blockIdx.x * 64;
  const int lcol = lane & 15;
  const int quad = lane >> 4;

  f32x4 acc[4];
#pragma unroll
  for (int i = 0; i < 4; ++i) acc[i] = (f32x4){0.f, 0.f, 0.f, 0.f};

  for (int k0 = 0; k0 < kD; k0 += 32) {
    {
      int r = tid >> 2;
      int kc = (tid & 3) ^ ((r >> 1) & 3);
      GLOBAL_LOAD_LDS16(&A[(size_t)(row0 + r) * kD + k0 + kc * 8], &As[tid * 8]);
      GLOBAL_LOAD_LDS16(&Wt[(size_t)r * kD + k0 + kc * 8], &Bs[tid * 8]);
    }
    __syncthreads();
    bf16x8 af[4], bfr;
#pragma unroll
    for (int i = 0; i < 4; ++i) {
      int rr = i * 16 + lcol;
      af[i] = *(const bf16x8*)&As[(rr * 4 + (quad ^ ((rr >> 1) & 3))) * 8];
    }
    {
      int rr = wave * 16 + lcol;
      bfr = *(const bf16x8*)&Bs[(rr * 4 + (quad ^ ((rr >> 1) & 3))) * 8];
    }
#pragma unroll
    for (int i = 0; i < 4; ++i)
      acc[i] = __builtin_amdgcn_mfma_f32_16x16x32_bf16(af[i], bfr, acc[i], 0, 0, 0);
    __syncthreads();
  }

#pragma unroll
  for (int i = 0; i < 4; ++i) {
#pragma unroll
    for (int r = 0; r < 4; ++r) {
      int grow = row0 + i * 16 + quad * 4 + r;
      int gcol = wave * 16 + lcol;
      float v = acc[i][r] + bias[gcol];
      v = (v > 0.f) ? (v + 1.f) : expf(v);
      C[(size_t)grow * kM + gcol] = v;
    }
  }
}

// ---------------------------------------------------------------------------
__global__ __launch_bounds__(256) void kv_split_kernel(const float* __restrict__ pk,
    const float* __restrict__ v, float* __restrict__ part) {
  __shared__ float pkS[16][64];
  __shared__ float vS[16][256];
  const int d0 = blockIdx.x * 256, b = blockIdx.y, split = blockIdx.z;
  const int s_beg = split * 128;
  const float* pkb = pk + (size_t)b * kS * kM;
  const float* vb  = v  + (size_t)b * kS * kD;
  const int tid = threadIdx.x;
  const int tx = tid & 15, ty = tid >> 4;
  float4 acc[4][4];
#pragma unroll
  for (int i = 0; i < 4; ++i)
#pragma unroll
    for (int j = 0; j < 4; ++j) acc[i][j] = make_float4(0.f, 0.f, 0.f, 0.f);

  for (int s0 = s_beg; s0 < s_beg + 128; s0 += 16) {
    {
      int e = tid * 4;
      int sr = e >> 6, mc = e & 63;
      *(float4*)&pkS[sr][mc] = *(const float4*)&pkb[(size_t)(s0 + sr) * kM + mc];
    }
#pragma unroll
    for (int p = 0; p < 4; ++p) {
      int idx = p * 256 + tid;
      int sr = idx >> 6, dc = (idx & 63) * 4;
      *(float4*)&vS[sr][dc] = *(const float4*)&vb[(size_t)(s0 + sr) * kD + d0 + dc];
    }
    __syncthreads();
#pragma unroll
    for (int sr = 0; sr < 16; ++sr) {
      float a[4];
#pragma unroll
      for (int i = 0; i < 4; ++i) a[i] = pkS[sr][ty * 4 + i];
      float4 bv[4];
#pragma unroll
      for (int j = 0; j < 4; ++j) bv[j] = *(const float4*)&vS[sr][tx * 16 + j * 4];
#pragma unroll
      for (int i = 0; i < 4; ++i)
#pragma unroll
        for (int j = 0; j < 4; ++j) {
          acc[i][j].x += a[i] * bv[j].x;
          acc[i][j].y += a[i] * bv[j].y;
          acc[i][j].z += a[i] * bv[j].z;
          acc[i][j].w += a[i] * bv[j].w;
        }
    }
    __syncthreads();
  }
  float* pp = part + (((size_t)split * kB + b) * kM) * kD;
#pragma unroll
  for (int i = 0; i < 4; ++i)
#pragma unroll
    for (int j = 0; j < 4; ++j)
      *(float4*)&pp[(size_t)(ty * 4 + i) * kD + d0 + tx * 16 + j * 4] = acc[i][j];
}

__global__ __launch_bounds__(256) void kv_reduce_kernel(const float* __restrict__ part,
                                                        float* __restrict__ kvb) {
  int gid = blockIdx.x * 256 + threadIdx.x;
  float4 s = make_float4(0.f, 0.f, 0.f, 0.f);
#pragma unroll
  for (int sp = 0; sp < 16; ++sp) {
    float4 p = ((const float4*)part)[(size_t)sp * (kB * kM * kD / 4) + gid];
    s.x += p.x; s.y += p.y; s.z += p.z; s.w += p.w;
  }
  ((float4*)kvb)[gid] = s;
}

// ---------------------------------------------------------------------------
__global__ __launch_bounds__(256) void zero_pks_kernel(float* __restrict__ p) {
  ((float4*)p)[threadIdx.x] = make_float4(0.f, 0.f, 0.f, 0.f);
}

__global__ __launch_bounds__(256) void pksum_kernel(const float* __restrict__ pk,
                                                    float* __restrict__ pksum) {
  __shared__ float part[4][64];
  int b = blockIdx.x >> 4;
  int split = blockIdx.x & 15;
  int lane = threadIdx.x & 63, w = threadIdx.x >> 6;
  float s = 0.f;
  int base = split * 128 + w * 32;
  for (int i = 0; i < 32; ++i)
    s += pk[((size_t)b * kS + base + i) * kM + lane];
  part[w][lane] = s;
  __syncthreads();
  if (w == 0)
    atomicAdd(&pksum[b * kM + lane],
              part[0][lane] + part[1][lane] + part[2][lane] + part[3][lane]);
}

// ---------------------------------------------------------------------------
__global__ __launch_bounds__(256) void z_kernel(const float* __restrict__ pq,
    const float* __restrict__ pksum, float* __restrict__ z) {
  int row = blockIdx.x * 4 + (threadIdx.x >> 6);
  int lane = threadIdx.x & 63;
  int b = row >> 11;
  float v = pq[(size_t)row * kM + lane] * pksum[b * kM + lane];
#pragma unroll
  for (int off = 32; off; off >>= 1) v += __shfl_down(v, off);
  if (lane == 0) z[row] = v + 1e-6f;
}

// ---------------------------------------------------------------------------
__global__ __launch_bounds__(256) void att_kernel(const float* __restrict__ pq,
    const float* __restrict__ kvm, const float* __restrict__ z,
    bf16* __restrict__ out) {
  __shared__ float pqS[64][68];
  __shared__ float kvS[64][68];
  const int d0 = blockIdx.x * 64, s0 = blockIdx.y * 64, b = blockIdx.z;
  const int tid = threadIdx.x;
  const int tx = tid & 15, ty = tid >> 4;
  for (int i = 0; i < 4; ++i) {
    int f = tid + i * 256;
    int r = f >> 4, c = (f & 15) * 4;
    *(float4*)&pqS[r][c] = *(const float4*)&pq[((size_t)(b * kS + s0 + r)) * kM + c];
    *(float4*)&kvS[r][c] = *(const float4*)&kvm[((size_t)b * kM + r) * kD + d0 + c];
  }
  __syncthreads();
  float acc[4][4] = {};
#pragma unroll
  for (int m = 0; m < kM; ++m) {
    float a[4];
#pragma unroll
    for (int i = 0; i < 4; ++i) a[i] = pqS[ty * 4 + i][m];
    float4 b4 = *(const float4*)&kvS[m][tx * 4];
    float bb[4] = {b4.x, b4.y, b4.z, b4.w};
#pragma unroll
    for (int i = 0; i < 4; ++i)
#pragma unroll
      for (int j = 0; j < 4; ++j) acc[i][j] += a[i] * bb[j];
  }
#pragma unroll
  for (int i = 0; i < 4; ++i) {
    int srow = s0 + ty * 4 + i;
    float zi = 1.0f / z[b * kS + srow];
    ushort4 u;
    u.x = f2bf_u16(acc[i][0] * zi);
    u.y = f2bf_u16(acc[i][1] * zi);
    u.z = f2bf_u16(acc[i][2] * zi);
    u.w = f2bf_u16(acc[i][3] * zi);
    *(ushort4*)&out[((size_t)(b * kS + srow)) * kD + d0 + tx * 4] = u;
  }
}

// ---------------------------------------------------------------------------
__global__ __launch_bounds__(256) void ln_kernel(const float* __restrict__ in,
    const float* __restrict__ g, const float* __restrict__ b,
    bf16* __restrict__ out) {
  __shared__ float ws1[4], ws2[4];
  int row = blockIdx.x, tid = threadIdx.x;
  float2 v = ((const float2*)(in + (size_t)row * kD))[tid];
  float s = v.x + v.y;
#pragma unroll
  for (int off = 32; off; off >>= 1) s += __shfl_down(s, off);
  if ((tid & 63) == 0) ws1[tid >> 6] = s;
  __syncthreads();
  float mean = (ws1[0] + ws1[1] + ws1[2] + ws1[3]) * (1.0f / kD);
  float dx = v.x - mean, dy = v.y - mean;
  float s2 = dx * dx + dy * dy;
#pragma unroll
  for (int off = 32; off; off >>= 1) s2 += __shfl_down(s2, off);
  if ((tid & 63) == 0) ws2[tid >> 6] = s2;
  __syncthreads();
  float var = (ws2[0] + ws2[1] + ws2[2] + ws2[3]) * (1.0f / kD);
  float rstd = rsqrtf(var + 1e-5f);
  float2 gg = ((const float2*)g)[tid];
  float2 bb = ((const float2*)b)[tid];
  ushort2 u;
  u.x = f2bf_u16(dx * rstd * gg.x + bb.x);
  u.y = f2bf_u16(dy * rstd * gg.y + bb.y);
  ((ushort2*)(out + (size_t)row * kD))[tid] = u;
}

// ---------------------------------------------------------------------------
__global__ __launch_bounds__(256) void cls_kernel(const float* __restrict__ h,
    const float* __restrict__ Wc1, const float* __restrict__ bc1,
    const float* __restrict__ Wc2, const float* __restrict__ bc2,
    float* __restrict__ out) {
  __shared__ float r0[4], r1[4];
  int b = blockIdx.x;
  int j = threadIdx.x;
  const float* p = h + (size_t)b * kS * kD;
  float acc = bc1[j];
  for (int i = 0; i < kD; ++i) acc += p[i] * Wc1[i * (kD / 2) + j];
  acc = fmaxf(acc, 0.f);
  float p0 = acc * Wc2[j * kC + 0];
  float p1 = acc * Wc2[j * kC + 1];
#pragma unroll
  for (int off = 32; off; off >>= 1) {
    p0 += __shfl_down(p0, off);
    p1 += __shfl_down(p1, off);
  }
  if ((j & 63) == 0) { r0[j >> 6] = p0; r1[j >> 6] = p1; }
  __syncthreads();
  if (j == 0) {
    out[b * kC + 0] = r0[0] + r0[1] + r0[2] + r0[3] + bc2[0];
    out[b * kC + 1] = r1[0] + r1[1] + r1[2] + r1[3] + bc2[1];
  }
}

// ---------------------------------------------------------------------------
extern "C" void kernel_launch(void* const* d_in, const int* in_sizes, int n_in,
                              void* d_out, int out_size, void* d_ws, size_t ws_size,
                              hipStream_t stream) {
  const int*   x    = (const int*)  d_in[0];
  const float* emb  = (const float*)d_in[1];
  const float* pos  = (const float*)d_in[2];
  const float* Wq   = (const float*)d_in[3];
  const float* bq   = (const float*)d_in[4];
  const float* Wk   = (const float*)d_in[5];
  const float* bk   = (const float*)d_in[6];
  const float* Wv   = (const float*)d_in[7];
  const float* bv   = (const float*)d_in[8];
  const float* P    = (const float*)d_in[9];
  const float* Wo   = (const float*)d_in[10];
  const float* bo   = (const float*)d_in[11];
  const float* ln_g = (const float*)d_in[12];
  const float* ln_b = (const float*)d_in[13];
  const float* W1   = (const float*)d_in[14];
  const float* b1   = (const float*)d_in[15];
  const float* W2   = (const float*)d_in[16];
  const float* b2   = (const float*)d_in[17];
  const float* Wc1  = (const float*)d_in[18];
  const float* bc1  = (const float*)d_in[19];
  const float* Wc2  = (const float*)d_in[20];
  const float* bc2  = (const float*)d_in[21];
  float* out = (float*)d_out;

  float* h   = (float*)d_ws;                   // 64 MB
  float* t0  = h   + (size_t)kBS * kD;         // 64 MB (v, Wo out; F aliases)
  float* pq  = t0  + (size_t)kBS * kD;         // 8 MB
  float* pk  = pq  + (size_t)kBS * kM;         // 8 MB
  float* kvb = pk  + (size_t)kBS * kM;         // 2 MB
  float* pks = kvb + (size_t)kB * kM * kD;
  float* zb  = pks + (size_t)kB * kM;
  float* bqp = zb  + kBS;
  float* bkp = bqp + kM;
  bf16* hb   = (bf16*)(bkp + kM);              // 32 MB
  bf16* ab   = hb + (size_t)kBS * kD;          // 32 MB (kv partials, att, hn)
  bf16* Wqpt = ab  + (size_t)kBS * kD;
  bf16* Wkpt = Wqpt + (size_t)kM * kD;
  bf16* Wvt  = Wkpt + (size_t)kM * kD;
  bf16* Wot  = Wvt + (size_t)kD * kD;
  bf16* W1t  = Wot + (size_t)kD * kD;
  bf16* W2t  = W1t + (size_t)kD * kH;
  bf16* F    = (bf16*)t0;
  float* kvpart = (float*)ab;

  embed_kernel<<<kBS * (kD / 4) / 256, 256, 0, stream>>>(x, emb, pos, h, hb);

  const dim3 gN512(kD / 64, kBS / 128);   // (8, 256) BN=64 grids

  for (int l = 0; l < kL; ++l) {
    const float* Pl = P + (size_t)l * kD * kM;

    wfold_kernel<<<128, 256, 0, stream>>>(Wq + (size_t)l * kD * kD, Pl, Wqpt);
    wfold_kernel<<<128, 256, 0, stream>>>(Wk + (size_t)l * kD * kD, Pl, Wkpt);
    bfold_kernel<<<1, 128, 0, stream>>>(bq + l * kD, bk + l * kD, Pl, bqp, bkp);
    transpose_cast_kernel<<<dim3(kD / 32, kD / 32), 256, 0, stream>>>(
        Wv + (size_t)l * kD * kD, Wvt, kD, kD);
    transpose_cast_kernel<<<dim3(kD / 32, kD / 32), 256, 0, stream>>>(
        Wo + (size_t)l * kD * kD, Wot, kD, kD);
    transpose_cast_kernel<<<dim3(kD / 32, kH / 32), 256, 0, stream>>>(
        W1 + (size_t)l * kD * kH, W1t, kD, kH);
    transpose_cast_kernel<<<dim3(kH / 32, kD / 32), 256, 0, stream>>>(
        W2 + (size_t)l * kH * kD, W2t, kH, kD);

    // pq = elu(h@(WqP) + bq@P)+1 ; pk likewise (skinny MFMA, BM=64)
    skinny_elu_gemm<<<kBS / 64, 256, 0, stream>>>(hb, Wqpt, bqp, pq);
    skinny_elu_gemm<<<kBS / 64, 256, 0, stream>>>(hb, Wkpt, bkp, pk);
    // v -> t0 (f32), BN=64
    mfma_gemm<64, 0, false, true, false><<<gN512, 256, 0, stream>>>(
        hb, Wvt, bv + l * kD, nullptr, t0, nullptr, kD, kD);
    // kv partials + reduce; pksum; z
    kv_split_kernel<<<dim3(kD / 256, kB, 16), 256, 0, stream>>>(pk, t0, kvpart);
    kv_reduce_kernel<<<kB * kM * kD / 1024, 256, 0, stream>>>(kvpart, kvb);
    zero_pks_kernel<<<1, 256, 0, stream>>>(pks);
    pksum_kernel<<<kB * 16, 256, 0, stream>>>(pk, pks);
    z_kernel<<<kBS / 4, 256, 0, stream>>>(pq, pks, zb);
    // att -> ab (bf16)
    att_kernel<<<dim3(kD / 64, kS / 64, kB), 256, 0, stream>>>(pq, kvb, zb, ab);
    // att @ Wo + bo -> t0 (f32), BN=64
    mfma_gemm<64, 0, false, true, false><<<gN512, 256, 0, stream>>>(
        ab, Wot, bo + l * kD, nullptr, t0, nullptr, kD, kD);
    // LN -> ab (bf16 hn)
    ln_kernel<<<kBS, 256, 0, stream>>>(t0, ln_g + l * kD, ln_b + l * kD, ab);
    // FFN in 2 row-chunks of 16384: W1 BN=128, W2 BN=64
    for (int c = 0; c < 2; ++c) {
      size_t ro = (size_t)c * 16384;
      mfma_gemm<128, 2, false, false, true><<<dim3(kH / 128, 16384 / 128), 256, 0, stream>>>(
          ab + ro * kD, W1t, b1 + l * kH, nullptr, nullptr, F, kD, kH);
      mfma_gemm<64, 0, true, true, true><<<dim3(kD / 64, 16384 / 128), 256, 0, stream>>>(
          F, W2t, b2 + l * kD, h + ro * kD, h + ro * kD, hb + ro * kD, kH, kD);
    }
  }

  cls_kernel<<<kB, 256, 0, stream>>>(h, Wc1, bc1, Wc2, bc2, out);
}

// Round 8
// 2103.826 us; speedup vs baseline: 5.4853x; 1.0437x over previous
//
#include <hip/hip_runtime.h>
#include <hip/hip_bf16.h>
#include <math.h>

constexpr int kV = 32000;
constexpr int kD = 512;
constexpr int kC = 2;
constexpr int kS = 2048;
constexpr int kL = 4;
constexpr int kM = 64;
constexpr int kB = 16;
constexpr int kH = 2048;
constexpr int kBS = kB * kS; // 32768

typedef __hip_bfloat16 bf16;
using bf16x8 = __attribute__((ext_vector_type(8))) short;
using f32x4  = __attribute__((ext_vector_type(4))) float;

#define GLOBAL_LOAD_LDS16(gp, lp)                                              \
  __builtin_amdgcn_global_load_lds(                                            \
      (const __attribute__((address_space(1))) void*)(gp),                     \
      (__attribute__((address_space(3))) void*)(lp), 16, 0, 0)

__device__ inline unsigned short f2bf_u16(float f) {
  bf16 b = __float2bfloat16(f);
  return *reinterpret_cast<unsigned short*>(&b);
}

// ---------------------------------------------------------------------------
__global__ __launch_bounds__(256) void embed_kernel(const int* __restrict__ x,
    const float* __restrict__ emb, const float* __restrict__ pos,
    float* __restrict__ h, bf16* __restrict__ hb) {
  int tid = blockIdx.x * 256 + threadIdx.x;
  int row = tid >> 7;
  int d4  = tid & 127;
  int tok = x[row];
  int s   = row & (kS - 1);
  float4 e = ((const float4*)emb)[(size_t)tok * 128 + d4];
  float4 p = ((const float4*)pos)[(size_t)s * 128 + d4];
  float4 o;
  o.x = e.x + p.x; o.y = e.y + p.y; o.z = e.z + p.z; o.w = e.w + p.w;
  ((float4*)h)[(size_t)row * 128 + d4] = o;
  ushort4 ub;
  ub.x = f2bf_u16(o.x); ub.y = f2bf_u16(o.y);
  ub.z = f2bf_u16(o.z); ub.w = f2bf_u16(o.w);
  ((ushort4*)hb)[(size_t)row * 128 + d4] = ub;
}

// ---------------------------------------------------------------------------
__global__ __launch_bounds__(256) void transpose_cast_kernel(
    const float* __restrict__ W, bf16* __restrict__ Wt, int K, int N) {
  __shared__ float tile[32][33];
  const int k0 = blockIdx.x * 32, n0 = blockIdx.y * 32;
  int tx = threadIdx.x & 31, ty = threadIdx.x >> 5;
#pragma unroll
  for (int i = 0; i < 32; i += 8)
    tile[ty + i][tx] = W[(size_t)(k0 + ty + i) * N + n0 + tx];
  __syncthreads();
#pragma unroll
  for (int i = 0; i < 32; i += 8)
    Wt[(size_t)(n0 + ty + i) * K + k0 + tx] = __float2bfloat16(tile[tx][ty + i]);
}

// plain cast fp32 -> bf16, n/1024 blocks
__global__ __launch_bounds__(256) void cast_bf16_kernel(
    const float* __restrict__ src, bf16* __restrict__ dst) {
  int gid = blockIdx.x * 256 + threadIdx.x;
  float4 v = ((const float4*)src)[gid];
  ushort4 u;
  u.x = f2bf_u16(v.x); u.y = f2bf_u16(v.y);
  u.z = f2bf_u16(v.z); u.w = f2bf_u16(v.w);
  ((ushort4*)dst)[gid] = u;
}

__global__ __launch_bounds__(256) void zero512_kernel(float* __restrict__ p) {
  if (threadIdx.x < 128) ((float4*)p)[threadIdx.x] = make_float4(0.f, 0.f, 0.f, 0.f);
}

// ---------------------------------------------------------------------------
__global__ __launch_bounds__(256) void wfold_kernel(const float* __restrict__ W,
    const float* __restrict__ P, bf16* __restrict__ Wt) {
  int gid = blockIdx.x * 256 + threadIdx.x;
  int m = gid & (kM - 1);
  int kk = gid >> 6;
  float acc = 0.f;
  for (int c = 0; c < kD; ++c) acc += W[(size_t)kk * kD + c] * P[(size_t)c * kM + m];
  Wt[(size_t)m * kD + kk] = __float2bfloat16(acc);
}

__global__ __launch_bounds__(128) void bfold_kernel(const float* __restrict__ bq,
    const float* __restrict__ bk, const float* __restrict__ P,
    float* __restrict__ bqp, float* __restrict__ bkp) {
  int m = threadIdx.x & (kM - 1);
  const float* src = (threadIdx.x >> 6) ? bk : bq;
  float* dst = (threadIdx.x >> 6) ? bkp : bqp;
  float acc = 0.f;
  for (int c = 0; c < kD; ++c) acc += src[c] * P[(size_t)c * kM + m];
  dst[m] = acc;
}

// bvWo[d] = sum_e bv[e] * Wo[e][d]
__global__ __launch_bounds__(256) void bvwo_kernel(const float* __restrict__ bv,
    const float* __restrict__ Wo, float* __restrict__ bvWo) {
  int d = blockIdx.x * 256 + threadIdx.x;
  float acc = 0.f;
  for (int e = 0; e < kD; ++e) acc += bv[e] * Wo[(size_t)e * kD + d];
  bvWo[d] = acc;
}

// ---------------------------------------------------------------------------
// bf16 MFMA GEMM, tile 128 x BN (128|64), BK=32, 256 threads.
// HAS_OUTER: bias = rowv[row]*colv[col] instead of bias[col] (for kvo).
// XOR-swizzled LDS; XCD remap generalized to small grids (SH).
// ---------------------------------------------------------------------------
template <int BN, int ACT, bool HAS_RES, bool HAS_OUTER, bool WRITE_F32, bool WRITE_BF16>
__global__ __launch_bounds__(256) void mfma_gemm(
    const bf16* __restrict__ A, const bf16* __restrict__ Wt,
    const float* __restrict__ bias, const float* __restrict__ rowv,
    const float* __restrict__ colv, const float* __restrict__ res,
    float* __restrict__ C, bf16* __restrict__ Cb, int K, int N) {
  constexpr int NJ = BN / 32;
  __shared__ short As[128 * 32];
  __shared__ short Bs[BN * 32];
  const int tid  = threadIdx.x;
  const int lane = tid & 63;
  const int wave = tid >> 6;
  const int nx = gridDim.x;
  const int SH = (gridDim.y & 7) ? gridDim.y : 8;   // stripe height
  const int b_lin = blockIdx.y * nx + blockIdx.x;
  const int stripe = b_lin / (nx * SH);
  const int rem = b_lin - stripe * (nx * SH);
  const int row0 = (stripe * SH + (rem % SH)) * 128;
  const int col0 = (rem / SH) * BN;
  const int wr = (wave & 1) * 64;
  const int wc = (wave >> 1) * (BN / 2);
  const int lcol = lane & 15;
  const int quad = lane >> 4;

  f32x4 acc[4][NJ];
#pragma unroll
  for (int i = 0; i < 4; ++i)
#pragma unroll
    for (int j = 0; j < NJ; ++j) acc[i][j] = (f32x4){0.f, 0.f, 0.f, 0.f};

  for (int k0 = 0; k0 < K; k0 += 32) {
#pragma unroll
    for (int p = 0; p < 2; ++p) {
      int idx = p * 256 + tid;
      int r = idx >> 2;
      int kc = (idx & 3) ^ ((r >> 1) & 3);
      GLOBAL_LOAD_LDS16(&A[(size_t)(row0 + r) * K + k0 + kc * 8], &As[idx * 8]);
    }
    if (BN == 128) {
#pragma unroll
      for (int p = 0; p < 2; ++p) {
        int idx = p * 256 + tid;
        int r = idx >> 2;
        int kc = (idx & 3) ^ ((r >> 1) & 3);
        GLOBAL_LOAD_LDS16(&Wt[(size_t)(col0 + r) * K + k0 + kc * 8], &Bs[idx * 8]);
      }
    } else {
      int r = tid >> 2;
      int kc = (tid & 3) ^ ((r >> 1) & 3);
      GLOBAL_LOAD_LDS16(&Wt[(size_t)(col0 + r) * K + k0 + kc * 8], &Bs[tid * 8]);
    }
    __syncthreads();
    bf16x8 af[4], bfr[NJ];
#pragma unroll
    for (int i = 0; i < 4; ++i) {
      int rr = wr + i * 16 + lcol;
      af[i] = *(const bf16x8*)&As[(rr * 4 + (quad ^ ((rr >> 1) & 3))) * 8];
    }
#pragma unroll
    for (int j = 0; j < NJ; ++j) {
      int rr = wc + j * 16 + lcol;
      bfr[j] = *(const bf16x8*)&Bs[(rr * 4 + (quad ^ ((rr >> 1) & 3))) * 8];
    }
#pragma unroll
    for (int i = 0; i < 4; ++i)
#pragma unroll
      for (int j = 0; j < NJ; ++j)
        acc[i][j] = __builtin_amdgcn_mfma_f32_16x16x32_bf16(af[i], bfr[j], acc[i][j], 0, 0, 0);
    __syncthreads();
  }

#pragma unroll
  for (int i = 0; i < 4; ++i) {
#pragma unroll
    for (int r = 0; r < 4; ++r) {
      int grow = row0 + wr + i * 16 + quad * 4 + r;
#pragma unroll
      for (int j = 0; j < NJ; ++j) {
        int gcol = col0 + wc + j * 16 + lcol;
        float v = acc[i][j][r];
        if (HAS_OUTER) v += rowv[grow] * colv[gcol];
        else v += bias[gcol];
        if (ACT == 2) v = 0.5f * v * (1.0f + erff(v * 0.70710678118654752f));
        size_t off = (size_t)grow * N + gcol;
        if (HAS_RES) v += res[off];
        if (WRITE_F32) C[off] = v;
        if (WRITE_BF16) Cb[off] = __float2bfloat16(v);
      }
    }
  }
}

// ---------------------------------------------------------------------------
// Dual skinny MFMA GEMM: pq = elu(A@Wq^T + bq)+1 AND pk = elu(A@Wk^T + bk)+1.
// BM=64; shared A-tile; Bs holds both weight sets (rows 0-63 q, 64-127 k).
// ---------------------------------------------------------------------------
__global__ __launch_bounds__(256) void skinny_dual_gemm(
    const bf16* __restrict__ A, const bf16* __restrict__ Wq,
    const bf16* __restrict__ Wk, const float* __restrict__ bq,
    const float* __restrict__ bk, float* __restrict__ pq,
    float* __restrict__ pk) {
  __shared__ short As[64 * 32];
  __shared__ short Bs[128 * 32];
  const int tid  = threadIdx.x;
  const int lane = tid & 63;
  const int wave = tid >> 6;
  const int row0 = blockIdx.x * 64;
  const int lcol = lane & 15;
  const int quad = lane >> 4;

  f32x4 accq[4], acck[4];
#pragma unroll
  for (int i = 0; i < 4; ++i) {
    accq[i] = (f32x4){0.f, 0.f, 0.f, 0.f};
    acck[i] = (f32x4){0.f, 0.f, 0.f, 0.f};
  }

  for (int k0 = 0; k0 < kD; k0 += 32) {
    {
      int r = tid >> 2;
      int kc = (tid & 3) ^ ((r >> 1) & 3);
      GLOBAL_LOAD_LDS16(&A[(size_t)(row0 + r) * kD + k0 + kc * 8], &As[tid * 8]);
    }
#pragma unroll
    for (int p = 0; p < 2; ++p) {
      int idx = p * 256 + tid;
      int r = idx >> 2;
      int kc = (idx & 3) ^ ((r >> 1) & 3);
      const bf16* src = (r < 64) ? &Wq[(size_t)r * kD + k0 + kc * 8]
                                 : &Wk[(size_t)(r - 64) * kD + k0 + kc * 8];
      GLOBAL_LOAD_LDS16(src, &Bs[idx * 8]);
    }
    __syncthreads();
    bf16x8 af[4], bq_f, bk_f;
#pragma unroll
    for (int i = 0; i < 4; ++i) {
      int rr = i * 16 + lcol;
      af[i] = *(const bf16x8*)&As[(rr * 4 + (quad ^ ((rr >> 1) & 3))) * 8];
    }
    {
      int rr = wave * 16 + lcol;
      bq_f = *(const bf16x8*)&Bs[(rr * 4 + (quad ^ ((rr >> 1) & 3))) * 8];
      int rr2 = 64 + wave * 16 + lcol;
      bk_f = *(const bf16x8*)&Bs[(rr2 * 4 + (quad ^ ((rr2 >> 1) & 3))) * 8];
    }
#pragma unroll
    for (int i = 0; i < 4; ++i) {
      accq[i] = __builtin_amdgcn_mfma_f32_16x16x32_bf16(af[i], bq_f, accq[i], 0, 0, 0);
      acck[i] = __builtin_amdgcn_mfma_f32_16x16x32_bf16(af[i], bk_f, acck[i], 0, 0, 0);
    }
    __syncthreads();
  }

#pragma unroll
  for (int i = 0; i < 4; ++i) {
#pragma unroll
    for (int r = 0; r < 4; ++r) {
      int grow = row0 + i * 16 + quad * 4 + r;
      int gcol = wave * 16 + lcol;
      float vq = accq[i][r] + bq[gcol];
      vq = (vq > 0.f) ? (vq + 1.f) : expf(vq);
      pq[(size_t)grow * kM + gcol] = vq;
      float vk = acck[i][r] + bk[gcol];
      vk = (vk > 0.f) ? (vk + 1.f) : expf(vk);
      pk[(size_t)grow * kM + gcol] = vk;
    }
  }
}

// ---------------------------------------------------------------------------
// kvh split: part[split][b][m][c] = sum_{s in 128-chunk} pk[b,s,m]*hb[b,s,c]
// hb is bf16, converted during staging; accumulation fp32.
// ---------------------------------------------------------------------------
__global__ __launch_bounds__(256) void kvh_split_kernel(const float* __restrict__ pk,
    const bf16* __restrict__ hb, float* __restrict__ part) {
  __shared__ float pkS[16][64];
  __shared__ float vS[16][256];
  const int d0 = blockIdx.x * 256, b = blockIdx.y, split = blockIdx.z;
  const int s_beg = split * 128;
  const float* pkb = pk + (size_t)b * kS * kM;
  const bf16* hbb  = hb + (size_t)b * kS * kD;
  const int tid = threadIdx.x;
  const int tx = tid & 15, ty = tid >> 4;
  float4 acc[4][4];
#pragma unroll
  for (int i = 0; i < 4; ++i)
#pragma unroll
    for (int j = 0; j < 4; ++j) acc[i][j] = make_float4(0.f, 0.f, 0.f, 0.f);

  for (int s0 = s_beg; s0 < s_beg + 128; s0 += 16) {
    {
      int e = tid * 4;
      int sr = e >> 6, mc = e & 63;
      *(float4*)&pkS[sr][mc] = *(const float4*)&pkb[(size_t)(s0 + sr) * kM + mc];
    }
#pragma unroll
    for (int p = 0; p < 2; ++p) {
      int idx = p * 256 + tid;
      int sr = idx >> 5, dc8 = idx & 31;   // 32 chunks of 8 bf16 per 256-col row
      uint4 raw = *(const uint4*)&hbb[(size_t)(s0 + sr) * kD + d0 + dc8 * 8];
      float4 f0, f1;
      f0.x = __uint_as_float(raw.x << 16);
      f0.y = __uint_as_float(raw.x & 0xffff0000u);
      f0.z = __uint_as_float(raw.y << 16);
      f0.w = __uint_as_float(raw.y & 0xffff0000u);
      f1.x = __uint_as_float(raw.z << 16);
      f1.y = __uint_as_float(raw.z & 0xffff0000u);
      f1.z = __uint_as_float(raw.w << 16);
      f1.w = __uint_as_float(raw.w & 0xffff0000u);
      *(float4*)&vS[sr][dc8 * 8]     = f0;
      *(float4*)&vS[sr][dc8 * 8 + 4] = f1;
    }
    __syncthreads();
#pragma unroll
    for (int sr = 0; sr < 16; ++sr) {
      float a[4];
#pragma unroll
      for (int i = 0; i < 4; ++i) a[i] = pkS[sr][ty * 4 + i];
      float4 bv4[4];
#pragma unroll
      for (int j = 0; j < 4; ++j) bv4[j] = *(const float4*)&vS[sr][tx * 16 + j * 4];
#pragma unroll
      for (int i = 0; i < 4; ++i)
#pragma unroll
        for (int j = 0; j < 4; ++j) {
          acc[i][j].x += a[i] * bv4[j].x;
          acc[i][j].y += a[i] * bv4[j].y;
          acc[i][j].z += a[i] * bv4[j].z;
          acc[i][j].w += a[i] * bv4[j].w;
        }
    }
    __syncthreads();
  }
  float* pp = part + (((size_t)split * kB + b) * kM) * kD;
#pragma unroll
  for (int i = 0; i < 4; ++i)
#pragma unroll
    for (int j = 0; j < 4; ++j)
      *(float4*)&pp[(size_t)(ty * 4 + i) * kD + d0 + tx * 16 + j * 4] = acc[i][j];
}

// reduce 16 partials -> kvhb (bf16, rows (b*kM+m), cols c)
__global__ __launch_bounds__(256) void kvh_reduce_kernel(const float* __restrict__ part,
                                                         bf16* __restrict__ kvhb) {
  int gid = blockIdx.x * 256 + threadIdx.x;
  float4 s = make_float4(0.f, 0.f, 0.f, 0.f);
#pragma unroll
  for (int sp = 0; sp < 16; ++sp) {
    float4 p = ((const float4*)part)[(size_t)sp * (kB * kM * kD / 4) + gid];
    s.x += p.x; s.y += p.y; s.z += p.z; s.w += p.w;
  }
  ushort4 u;
  u.x = f2bf_u16(s.x); u.y = f2bf_u16(s.y);
  u.z = f2bf_u16(s.z); u.w = f2bf_u16(s.w);
  ((ushort4*)kvhb)[gid] = u;
}

// ---------------------------------------------------------------------------
__global__ __launch_bounds__(256) void zero_pks_kernel(float* __restrict__ p) {
  ((float4*)p)[threadIdx.x] = make_float4(0.f, 0.f, 0.f, 0.f);
}

__global__ __launch_bounds__(256) void pksum_kernel(const float* __restrict__ pk,
                                                    float* __restrict__ pksum) {
  __shared__ float part[4][64];
  int b = blockIdx.x >> 4;
  int split = blockIdx.x & 15;
  int lane = threadIdx.x & 63, w = threadIdx.x >> 6;
  float s = 0.f;
  int base = split * 128 + w * 32;
  for (int i = 0; i < 32; ++i)
    s += pk[((size_t)b * kS + base + i) * kM + lane];
  part[w][lane] = s;
  __syncthreads();
  if (w == 0)
    atomicAdd(&pksum[b * kM + lane],
              part[0][lane] + part[1][lane] + part[2][lane] + part[3][lane]);
}

// ---------------------------------------------------------------------------
__global__ __launch_bounds__(256) void z_kernel(const float* __restrict__ pq,
    const float* __restrict__ pksum, float* __restrict__ z) {
  int row = blockIdx.x * 4 + (threadIdx.x >> 6);
  int lane = threadIdx.x & 63;
  int b = row >> 11;
  float v = pq[(size_t)row * kM + lane] * pksum[b * kM + lane];
#pragma unroll
  for (int off = 32; off; off >>= 1) v += __shfl_down(v, off);
  if (lane == 0) z[row] = v + 1e-6f;
}

// ---------------------------------------------------------------------------
// atth[b,s,d] = (sum_m pq[b,s,m]*kvo[b,m,d]) / z[b,s] + bo[d]   -> f32 out
// ---------------------------------------------------------------------------
__global__ __launch_bounds__(256) void att_kernel(const float* __restrict__ pq,
    const float* __restrict__ kvo, const float* __restrict__ z,
    const float* __restrict__ bo, float* __restrict__ outf) {
  __shared__ float pqS[64][68];
  __shared__ float kvS[64][68];
  const int d0 = blockIdx.x * 64, s0 = blockIdx.y * 64, b = blockIdx.z;
  const int tid = threadIdx.x;
  const int tx = tid & 15, ty = tid >> 4;
  for (int i = 0; i < 4; ++i) {
    int f = tid + i * 256;
    int r = f >> 4, c = (f & 15) * 4;
    *(float4*)&pqS[r][c] = *(const float4*)&pq[((size_t)(b * kS + s0 + r)) * kM + c];
    *(float4*)&kvS[r][c] = *(const float4*)&kvo[((size_t)b * kM + r) * kD + d0 + c];
  }
  __syncthreads();
  float acc[4][4] = {};
#pragma unroll
  for (int m = 0; m < kM; ++m) {
    float a[4];
#pragma unroll
    for (int i = 0; i < 4; ++i) a[i] = pqS[ty * 4 + i][m];
    float4 b4 = *(const float4*)&kvS[m][tx * 4];
    float bb[4] = {b4.x, b4.y, b4.z, b4.w};
#pragma unroll
    for (int i = 0; i < 4; ++i)
#pragma unroll
      for (int j = 0; j < 4; ++j) acc[i][j] += a[i] * bb[j];
  }
  float4 bo4 = *(const float4*)&bo[d0 + tx * 4];
#pragma unroll
  for (int i = 0; i < 4; ++i) {
    int srow = s0 + ty * 4 + i;
    float zi = 1.0f / z[b * kS + srow];
    float4 o;
    o.x = acc[i][0] * zi + bo4.x;
    o.y = acc[i][1] * zi + bo4.y;
    o.z = acc[i][2] * zi + bo4.z;
    o.w = acc[i][3] * zi + bo4.w;
    *(float4*)&outf[((size_t)(b * kS + srow)) * kD + d0 + tx * 4] = o;
  }
}

// ---------------------------------------------------------------------------
__global__ __launch_bounds__(256) void ln_kernel(const float* __restrict__ in,
    const float* __restrict__ g, const float* __restrict__ b,
    bf16* __restrict__ out) {
  __shared__ float ws1[4], ws2[4];
  int row = blockIdx.x, tid = threadIdx.x;
  float2 v = ((const float2*)(in + (size_t)row * kD))[tid];
  float s = v.x + v.y;
#pragma unroll
  for (int off = 32; off; off >>= 1) s += __shfl_down(s, off);
  if ((tid & 63) == 0) ws1[tid >> 6] = s;
  __syncthreads();
  float mean = (ws1[0] + ws1[1] + ws1[2] + ws1[3]) * (1.0f / kD);
  float dx = v.x - mean, dy = v.y - mean;
  float s2 = dx * dx + dy * dy;
#pragma unroll
  for (int off = 32; off; off >>= 1) s2 += __shfl_down(s2, off);
  if ((tid & 63) == 0) ws2[tid >> 6] = s2;
  __syncthreads();
  float var = (ws2[0] + ws2[1] + ws2[2] + ws2[3]) * (1.0f / kD);
  float rstd = rsqrtf(var + 1e-5f);
  float2 gg = ((const float2*)g)[tid];
  float2 bb = ((const float2*)b)[tid];
  ushort2 u;
  u.x = f2bf_u16(dx * rstd * gg.x + bb.x);
  u.y = f2bf_u16(dy * rstd * gg.y + bb.y);
  ((ushort2*)(out + (size_t)row * kD))[tid] = u;
}

// ---------------------------------------------------------------------------
__global__ __launch_bounds__(256) void cls_kernel(const float* __restrict__ h,
    const float* __restrict__ Wc1, const float* __restrict__ bc1,
    const float* __restrict__ Wc2, const float* __restrict__ bc2,
    float* __restrict__ out) {
  __shared__ float r0[4], r1[4];
  int b = blockIdx.x;
  int j = threadIdx.x;
  const float* p = h + (size_t)b * kS * kD;
  float acc = bc1[j];
  for (int i = 0; i < kD; ++i) acc += p[i] * Wc1[i * (kD / 2) + j];
  acc = fmaxf(acc, 0.f);
  float p0 = acc * Wc2[j * kC + 0];
  float p1 = acc * Wc2[j * kC + 1];
#pragma unroll
  for (int off = 32; off; off >>= 1) {
    p0 += __shfl_down(p0, off);
    p1 += __shfl_down(p1, off);
  }
  if ((j & 63) == 0) { r0[j >> 6] = p0; r1[j >> 6] = p1; }
  __syncthreads();
  if (j == 0) {
    out[b * kC + 0] = r0[0] + r0[1] + r0[2] + r0[3] + bc2[0];
    out[b * kC + 1] = r1[0] + r1[1] + r1[2] + r1[3] + bc2[1];
  }
}

// ---------------------------------------------------------------------------
extern "C" void kernel_launch(void* const* d_in, const int* in_sizes, int n_in,
                              void* d_out, int out_size, void* d_ws, size_t ws_size,
                              hipStream_t stream) {
  const int*   x    = (const int*)  d_in[0];
  const float* emb  = (const float*)d_in[1];
  const float* pos  = (const float*)d_in[2];
  const float* Wq   = (const float*)d_in[3];
  const float* bq   = (const float*)d_in[4];
  const float* Wk   = (const float*)d_in[5];
  const float* bk   = (const float*)d_in[6];
  const float* Wv   = (const float*)d_in[7];
  const float* bv   = (const float*)d_in[8];
  const float* P    = (const float*)d_in[9];
  const float* Wo   = (const float*)d_in[10];
  const float* bo   = (const float*)d_in[11];
  const float* ln_g = (const float*)d_in[12];
  const float* ln_b = (const float*)d_in[13];
  const float* W1   = (const float*)d_in[14];
  const float* b1   = (const float*)d_in[15];
  const float* W2   = (const float*)d_in[16];
  const float* b2   = (const float*)d_in[17];
  const float* Wc1  = (const float*)d_in[18];
  const float* bc1  = (const float*)d_in[19];
  const float* Wc2  = (const float*)d_in[20];
  const float* bc2  = (const float*)d_in[21];
  float* out = (float*)d_out;

  // fp32 region
  float* h    = (float*)d_ws;                    // 64 MB
  float* t0   = h    + (size_t)kBS * kD;         // 64 MB (atth f32; F aliases)
  float* pq   = t0   + (size_t)kBS * kD;         // 8 MB
  float* pk   = pq   + (size_t)kBS * kM;         // 8 MB
  float* kvo  = pk   + (size_t)kBS * kM;         // 2 MB  (kv@Wv@Wo, f32)
  float* pks  = kvo  + (size_t)kB * kM * kD;     // kB*kM
  float* zb   = pks  + (size_t)kB * kM;          // kBS
  float* bqp  = zb   + kBS;
  float* bkp  = bqp  + kM;
  float* bvWo = bkp  + kM;                       // kD
  float* zeros= bvWo + kD;                       // kD
  // bf16 region
  bf16* hb    = (bf16*)(zeros + kD);             // 32 MB
  bf16* ab    = hb + (size_t)kBS * kD;           // 32 MB (kvh partials alias; hn)
  bf16* Wqpt  = ab  + (size_t)kBS * kD;          // kM*kD
  bf16* Wkpt  = Wqpt + (size_t)kM * kD;          // kM*kD
  bf16* Wot   = Wkpt + (size_t)kM * kD;          // kD*kD (Wo^T)
  bf16* Wvc   = Wot + (size_t)kD * kD;           // kD*kD (Wv cast, native layout)
  bf16* WvWot = Wvc + (size_t)kD * kD;           // kD*kD ((Wv@Wo)^T)
  bf16* W1t   = WvWot + (size_t)kD * kD;         // kH*kD
  bf16* W2t   = W1t + (size_t)kD * kH;           // kD*kH
  bf16* kvhb  = W2t + (size_t)kD * kH;           // kB*kM*kD bf16 (1 MB)
  bf16* F     = (bf16*)t0;                       // FFN intermediate aliases t0
  float* kvpart = (float*)ab;                    // 16 × kB*kM*kD f32 = 32 MB

  zero512_kernel<<<1, 256, 0, stream>>>(zeros);
  embed_kernel<<<kBS * (kD / 4) / 256, 256, 0, stream>>>(x, emb, pos, h, hb);

  for (int l = 0; l < kL; ++l) {
    const float* Pl = P + (size_t)l * kD * kM;

    // ---- per-layer weight prep ----
    wfold_kernel<<<128, 256, 0, stream>>>(Wq + (size_t)l * kD * kD, Pl, Wqpt);
    wfold_kernel<<<128, 256, 0, stream>>>(Wk + (size_t)l * kD * kD, Pl, Wkpt);
    bfold_kernel<<<1, 128, 0, stream>>>(bq + l * kD, bk + l * kD, Pl, bqp, bkp);
    transpose_cast_kernel<<<dim3(kD / 32, kD / 32), 256, 0, stream>>>(
        Wo + (size_t)l * kD * kD, Wot, kD, kD);
    cast_bf16_kernel<<<kD * kD / 1024, 256, 0, stream>>>(Wv + (size_t)l * kD * kD, Wvc);
    // WvWot[d][c] = sum_e Wot[d][e] * Wv[c][e]  (MFMA, M=512,N=512,K=512)
    mfma_gemm<64, 0, false, false, false, true><<<dim3(8, 4), 256, 0, stream>>>(
        Wot, Wvc, zeros, nullptr, nullptr, nullptr, nullptr, WvWot, kD, kD);
    bvwo_kernel<<<2, 256, 0, stream>>>(bv + l * kD, Wo + (size_t)l * kD * kD, bvWo);
    transpose_cast_kernel<<<dim3(kD / 32, kH / 32), 256, 0, stream>>>(
        W1 + (size_t)l * kD * kH, W1t, kD, kH);
    transpose_cast_kernel<<<dim3(kH / 32, kD / 32), 256, 0, stream>>>(
        W2 + (size_t)l * kH * kD, W2t, kH, kD);

    // ---- attention (folded) ----
    skinny_dual_gemm<<<kBS / 64, 256, 0, stream>>>(hb, Wqpt, Wkpt, bqp, bkp, pq, pk);
    kvh_split_kernel<<<dim3(kD / 256, kB, 16), 256, 0, stream>>>(pk, hb, kvpart);
    kvh_reduce_kernel<<<kB * kM * kD / 1024, 256, 0, stream>>>(kvpart, kvhb);
    zero_pks_kernel<<<1, 256, 0, stream>>>(pks);
    pksum_kernel<<<kB * 16, 256, 0, stream>>>(pk, pks);
    z_kernel<<<kBS / 4, 256, 0, stream>>>(pq, pks, zb);
    // kvo = kvh @ WvWo + pksum ⊗ bvWo   (M=1024, N=512, K=512)
    mfma_gemm<64, 0, false, true, true, false><<<dim3(8, 8), 256, 0, stream>>>(
        kvhb, WvWot, nullptr, pks, bvWo, nullptr, kvo, nullptr, kD, kD);
    // atth = pq@kvo/z + bo -> t0 (f32)
    att_kernel<<<dim3(kD / 64, kS / 64, kB), 256, 0, stream>>>(pq, kvo, zb, bo + l * kD, t0);
    // LN -> ab (bf16 hn); t0 dead after (F aliases)
    ln_kernel<<<kBS, 256, 0, stream>>>(t0, ln_g + l * kD, ln_b + l * kD, ab);
    // ---- FFN in 2 row-chunks of 16384 ----
    for (int c = 0; c < 2; ++c) {
      size_t ro = (size_t)c * 16384;
      mfma_gemm<128, 2, false, false, false, true><<<dim3(kH / 128, 16384 / 128), 256, 0, stream>>>(
          ab + ro * kD, W1t, b1 + l * kH, nullptr, nullptr, nullptr, nullptr, F, kD, kH);
      mfma_gemm<64, 0, true, false, true, true><<<dim3(kD / 64, 16384 / 128), 256, 0, stream>>>(
          F, W2t, b2 + l * kD, nullptr, nullptr, h + ro * kD, h + ro * kD, hb + ro * kD, kH, kD);
    }
  }

  cls_kernel<<<kB, 256, 0, stream>>>(h, Wc1, bc1, Wc2, bc2, out);
}

// Round 9
// 1933.962 us; speedup vs baseline: 5.9670x; 1.0878x over previous
//
#include <hip/hip_runtime.h>
#include <hip/hip_bf16.h>
#include <math.h>

constexpr int kV = 32000;
constexpr int kD = 512;
constexpr int kC = 2;
constexpr int kS = 2048;
constexpr int kL = 4;
constexpr int kM = 64;
constexpr int kB = 16;
constexpr int kH = 2048;
constexpr int kBS = kB * kS; // 32768

typedef __hip_bfloat16 bf16;
using bf16x8 = __attribute__((ext_vector_type(8))) short;
using f32x4  = __attribute__((ext_vector_type(4))) float;

#define GLOBAL_LOAD_LDS16(gp, lp)                                              \
  __builtin_amdgcn_global_load_lds(                                            \
      (const __attribute__((address_space(1))) void*)(gp),                     \
      (__attribute__((address_space(3))) void*)(lp), 16, 0, 0)

__device__ inline unsigned short f2bf_u16(float f) {
  bf16 b = __float2bfloat16(f);
  return *reinterpret_cast<unsigned short*>(&b);
}

// ---------------------------------------------------------------------------
__global__ __launch_bounds__(256) void embed_kernel(const int* __restrict__ x,
    const float* __restrict__ emb, const float* __restrict__ pos,
    float* __restrict__ h, bf16* __restrict__ hb) {
  int tid = blockIdx.x * 256 + threadIdx.x;
  int row = tid >> 7;
  int d4  = tid & 127;
  int tok = x[row];
  int s   = row & (kS - 1);
  float4 e = ((const float4*)emb)[(size_t)tok * 128 + d4];
  float4 p = ((const float4*)pos)[(size_t)s * 128 + d4];
  float4 o;
  o.x = e.x + p.x; o.y = e.y + p.y; o.z = e.z + p.z; o.w = e.w + p.w;
  ((float4*)h)[(size_t)row * 128 + d4] = o;
  ushort4 ub;
  ub.x = f2bf_u16(o.x); ub.y = f2bf_u16(o.y);
  ub.z = f2bf_u16(o.z); ub.w = f2bf_u16(o.w);
  ((ushort4*)hb)[(size_t)row * 128 + d4] = ub;
}

// ---------------------------------------------------------------------------
__global__ __launch_bounds__(256) void transpose_cast_kernel(
    const float* __restrict__ W, bf16* __restrict__ Wt, int K, int N) {
  __shared__ float tile[32][33];
  const int k0 = blockIdx.x * 32, n0 = blockIdx.y * 32;
  int tx = threadIdx.x & 31, ty = threadIdx.x >> 5;
#pragma unroll
  for (int i = 0; i < 32; i += 8)
    tile[ty + i][tx] = W[(size_t)(k0 + ty + i) * N + n0 + tx];
  __syncthreads();
#pragma unroll
  for (int i = 0; i < 32; i += 8)
    Wt[(size_t)(n0 + ty + i) * K + k0 + tx] = __float2bfloat16(tile[tx][ty + i]);
}

__global__ __launch_bounds__(256) void cast_bf16_kernel(
    const float* __restrict__ src, bf16* __restrict__ dst) {
  int gid = blockIdx.x * 256 + threadIdx.x;
  float4 v = ((const float4*)src)[gid];
  ushort4 u;
  u.x = f2bf_u16(v.x); u.y = f2bf_u16(v.y);
  u.z = f2bf_u16(v.z); u.w = f2bf_u16(v.w);
  ((ushort4*)dst)[gid] = u;
}

__global__ __launch_bounds__(256) void zero512_kernel(float* __restrict__ p) {
  if (threadIdx.x < 128) ((float4*)p)[threadIdx.x] = make_float4(0.f, 0.f, 0.f, 0.f);
}

// ---------------------------------------------------------------------------
__global__ __launch_bounds__(256) void wfold_kernel(const float* __restrict__ W,
    const float* __restrict__ P, bf16* __restrict__ Wt) {
  int gid = blockIdx.x * 256 + threadIdx.x;
  int m = gid & (kM - 1);
  int kk = gid >> 6;
  float acc = 0.f;
  for (int c = 0; c < kD; ++c) acc += W[(size_t)kk * kD + c] * P[(size_t)c * kM + m];
  Wt[(size_t)m * kD + kk] = __float2bfloat16(acc);
}

__global__ __launch_bounds__(128) void bfold_kernel(const float* __restrict__ bq,
    const float* __restrict__ bk, const float* __restrict__ P,
    float* __restrict__ bqp, float* __restrict__ bkp) {
  int m = threadIdx.x & (kM - 1);
  const float* src = (threadIdx.x >> 6) ? bk : bq;
  float* dst = (threadIdx.x >> 6) ? bkp : bqp;
  float acc = 0.f;
  for (int c = 0; c < kD; ++c) acc += src[c] * P[(size_t)c * kM + m];
  dst[m] = acc;
}

__global__ __launch_bounds__(256) void bvwo_kernel(const float* __restrict__ bv,
    const float* __restrict__ Wo, float* __restrict__ bvWo) {
  int d = blockIdx.x * 256 + threadIdx.x;
  float acc = 0.f;
  for (int e = 0; e < kD; ++e) acc += bv[e] * Wo[(size_t)e * kD + d];
  bvWo[d] = acc;
}

// ---------------------------------------------------------------------------
// bf16 MFMA GEMM, tile 128 x BN (128|64), BK in {32,64}, 256 threads.
// BK=64 halves barrier count (16 MFMAs per barrier-pair for BN=64).
// Swizzle: BK=32 -> slot^( (r>>1)&3 ); BK=64 -> slot^( r&7 ). Both 2-way max.
// ---------------------------------------------------------------------------
template <int BK, int BN, int ACT, bool HAS_RES, bool HAS_OUTER, bool WRITE_F32, bool WRITE_BF16>
__global__ __launch_bounds__(256) void mfma_gemm(
    const bf16* __restrict__ A, const bf16* __restrict__ Wt,
    const float* __restrict__ bias, const float* __restrict__ rowv,
    const float* __restrict__ colv, const float* __restrict__ res,
    float* __restrict__ C, bf16* __restrict__ Cb, int K, int N) {
  constexpr int NJ = BN / 32;
  constexpr int CPR = BK / 8;            // 16B chunks per row
  constexpr int SW = (BK == 32) ? 1 : 0; // swizzle shift
  __shared__ short As[128 * BK];
  __shared__ short Bs[BN * BK];
  const int tid  = threadIdx.x;
  const int lane = tid & 63;
  const int wave = tid >> 6;
  const int nx = gridDim.x;
  const int SH = (gridDim.y & 7) ? gridDim.y : 8;
  const int b_lin = blockIdx.y * nx + blockIdx.x;
  const int stripe = b_lin / (nx * SH);
  const int rem = b_lin - stripe * (nx * SH);
  const int row0 = (stripe * SH + (rem % SH)) * 128;
  const int col0 = (rem / SH) * BN;
  const int wr = (wave & 1) * 64;
  const int wc = (wave >> 1) * (BN / 2);
  const int lcol = lane & 15;
  const int quad = lane >> 4;

  f32x4 acc[4][NJ];
#pragma unroll
  for (int i = 0; i < 4; ++i)
#pragma unroll
    for (int j = 0; j < NJ; ++j) acc[i][j] = (f32x4){0.f, 0.f, 0.f, 0.f};

  for (int k0 = 0; k0 < K; k0 += BK) {
#pragma unroll
    for (int p = 0; p < 128 * CPR / 256; ++p) {
      int idx = p * 256 + tid;
      int r = idx / CPR;
      int kc = (idx % CPR) ^ ((r >> SW) & (CPR - 1));
      GLOBAL_LOAD_LDS16(&A[(size_t)(row0 + r) * K + k0 + kc * 8], &As[idx * 8]);
    }
#pragma unroll
    for (int p = 0; p < BN * CPR / 256; ++p) {
      int idx = p * 256 + tid;
      int r = idx / CPR;
      int kc = (idx % CPR) ^ ((r >> SW) & (CPR - 1));
      GLOBAL_LOAD_LDS16(&Wt[(size_t)(col0 + r) * K + k0 + kc * 8], &Bs[idx * 8]);
    }
    __syncthreads();
#pragma unroll
    for (int kh = 0; kh < BK / 32; ++kh) {
      bf16x8 af[4], bfr[NJ];
#pragma unroll
      for (int i = 0; i < 4; ++i) {
        int rr = wr + i * 16 + lcol;
        int slot = (kh * 4 + quad) ^ ((rr >> SW) & (CPR - 1));
        af[i] = *(const bf16x8*)&As[(rr * CPR + slot) * 8];
      }
#pragma unroll
      for (int j = 0; j < NJ; ++j) {
        int rr = wc + j * 16 + lcol;
        int slot = (kh * 4 + quad) ^ ((rr >> SW) & (CPR - 1));
        bfr[j] = *(const bf16x8*)&Bs[(rr * CPR + slot) * 8];
      }
#pragma unroll
      for (int i = 0; i < 4; ++i)
#pragma unroll
        for (int j = 0; j < NJ; ++j)
          acc[i][j] = __builtin_amdgcn_mfma_f32_16x16x32_bf16(af[i], bfr[j], acc[i][j], 0, 0, 0);
    }
    __syncthreads();
  }

#pragma unroll
  for (int i = 0; i < 4; ++i) {
#pragma unroll
    for (int r = 0; r < 4; ++r) {
      int grow = row0 + wr + i * 16 + quad * 4 + r;
#pragma unroll
      for (int j = 0; j < NJ; ++j) {
        int gcol = col0 + wc + j * 16 + lcol;
        float v = acc[i][j][r];
        if (HAS_OUTER) v += rowv[grow] * colv[gcol];
        else v += bias[gcol];
        if (ACT == 2) v = 0.5f * v * (1.0f + erff(v * 0.70710678118654752f));
        size_t off = (size_t)grow * N + gcol;
        if (HAS_RES) v += res[off];
        if (WRITE_F32) C[off] = v;
        if (WRITE_BF16) Cb[off] = __float2bfloat16(v);
      }
    }
  }
}

// ---------------------------------------------------------------------------
// Dual skinny MFMA GEMM: pq = elu(A@Wq^T + bq)+1 AND pk = elu(A@Wk^T + bk)+1.
// ---------------------------------------------------------------------------
__global__ __launch_bounds__(256) void skinny_dual_gemm(
    const bf16* __restrict__ A, const bf16* __restrict__ Wq,
    const bf16* __restrict__ Wk, const float* __restrict__ bq,
    const float* __restrict__ bk, float* __restrict__ pq,
    float* __restrict__ pk) {
  __shared__ short As[64 * 32];
  __shared__ short Bs[128 * 32];
  const int tid  = threadIdx.x;
  const int lane = tid & 63;
  const int wave = tid >> 6;
  const int row0 = blockIdx.x * 64;
  const int lcol = lane & 15;
  const int quad = lane >> 4;

  f32x4 accq[4], acck[4];
#pragma unroll
  for (int i = 0; i < 4; ++i) {
    accq[i] = (f32x4){0.f, 0.f, 0.f, 0.f};
    acck[i] = (f32x4){0.f, 0.f, 0.f, 0.f};
  }

  for (int k0 = 0; k0 < kD; k0 += 32) {
    {
      int r = tid >> 2;
      int kc = (tid & 3) ^ ((r >> 1) & 3);
      GLOBAL_LOAD_LDS16(&A[(size_t)(row0 + r) * kD + k0 + kc * 8], &As[tid * 8]);
    }
#pragma unroll
    for (int p = 0; p < 2; ++p) {
      int idx = p * 256 + tid;
      int r = idx >> 2;
      int kc = (idx & 3) ^ ((r >> 1) & 3);
      const bf16* src = (r < 64) ? &Wq[(size_t)r * kD + k0 + kc * 8]
                                 : &Wk[(size_t)(r - 64) * kD + k0 + kc * 8];
      GLOBAL_LOAD_LDS16(src, &Bs[idx * 8]);
    }
    __syncthreads();
    bf16x8 af[4], bq_f, bk_f;
#pragma unroll
    for (int i = 0; i < 4; ++i) {
      int rr = i * 16 + lcol;
      af[i] = *(const bf16x8*)&As[(rr * 4 + (quad ^ ((rr >> 1) & 3))) * 8];
    }
    {
      int rr = wave * 16 + lcol;
      bq_f = *(const bf16x8*)&Bs[(rr * 4 + (quad ^ ((rr >> 1) & 3))) * 8];
      int rr2 = 64 + wave * 16 + lcol;
      bk_f = *(const bf16x8*)&Bs[(rr2 * 4 + (quad ^ ((rr2 >> 1) & 3))) * 8];
    }
#pragma unroll
    for (int i = 0; i < 4; ++i) {
      accq[i] = __builtin_amdgcn_mfma_f32_16x16x32_bf16(af[i], bq_f, accq[i], 0, 0, 0);
      acck[i] = __builtin_amdgcn_mfma_f32_16x16x32_bf16(af[i], bk_f, acck[i], 0, 0, 0);
    }
    __syncthreads();
  }

#pragma unroll
  for (int i = 0; i < 4; ++i) {
#pragma unroll
    for (int r = 0; r < 4; ++r) {
      int grow = row0 + i * 16 + quad * 4 + r;
      int gcol = wave * 16 + lcol;
      float vq = accq[i][r] + bq[gcol];
      vq = (vq > 0.f) ? (vq + 1.f) : expf(vq);
      pq[(size_t)grow * kM + gcol] = vq;
      float vk = acck[i][r] + bk[gcol];
      vk = (vk > 0.f) ? (vk + 1.f) : expf(vk);
      pk[(size_t)grow * kM + gcol] = vk;
    }
  }
}

// ---------------------------------------------------------------------------
__global__ __launch_bounds__(256) void kvh_split_kernel(const float* __restrict__ pk,
    const bf16* __restrict__ hb, float* __restrict__ part) {
  __shared__ float pkS[16][64];
  __shared__ float vS[16][256];
  const int d0 = blockIdx.x * 256, b = blockIdx.y, split = blockIdx.z;
  const int s_beg = split * 128;
  const float* pkb = pk + (size_t)b * kS * kM;
  const bf16* hbb  = hb + (size_t)b * kS * kD;
  const int tid = threadIdx.x;
  const int tx = tid & 15, ty = tid >> 4;
  float4 acc[4][4];
#pragma unroll
  for (int i = 0; i < 4; ++i)
#pragma unroll
    for (int j = 0; j < 4; ++j) acc[i][j] = make_float4(0.f, 0.f, 0.f, 0.f);

  for (int s0 = s_beg; s0 < s_beg + 128; s0 += 16) {
    {
      int e = tid * 4;
      int sr = e >> 6, mc = e & 63;
      *(float4*)&pkS[sr][mc] = *(const float4*)&pkb[(size_t)(s0 + sr) * kM + mc];
    }
#pragma unroll
    for (int p = 0; p < 2; ++p) {
      int idx = p * 256 + tid;
      int sr = idx >> 5, dc8 = idx & 31;
      uint4 raw = *(const uint4*)&hbb[(size_t)(s0 + sr) * kD + d0 + dc8 * 8];
      float4 f0, f1;
      f0.x = __uint_as_float(raw.x << 16);
      f0.y = __uint_as_float(raw.x & 0xffff0000u);
      f0.z = __uint_as_float(raw.y << 16);
      f0.w = __uint_as_float(raw.y & 0xffff0000u);
      f1.x = __uint_as_float(raw.z << 16);
      f1.y = __uint_as_float(raw.z & 0xffff0000u);
      f1.z = __uint_as_float(raw.w << 16);
      f1.w = __uint_as_float(raw.w & 0xffff0000u);
      *(float4*)&vS[sr][dc8 * 8]     = f0;
      *(float4*)&vS[sr][dc8 * 8 + 4] = f1;
    }
    __syncthreads();
#pragma unroll
    for (int sr = 0; sr < 16; ++sr) {
      float a[4];
#pragma unroll
      for (int i = 0; i < 4; ++i) a[i] = pkS[sr][ty * 4 + i];
      float4 bv4[4];
#pragma unroll
      for (int j = 0; j < 4; ++j) bv4[j] = *(const float4*)&vS[sr][tx * 16 + j * 4];
#pragma unroll
      for (int i = 0; i < 4; ++i)
#pragma unroll
        for (int j = 0; j < 4; ++j) {
          acc[i][j].x += a[i] * bv4[j].x;
          acc[i][j].y += a[i] * bv4[j].y;
          acc[i][j].z += a[i] * bv4[j].z;
          acc[i][j].w += a[i] * bv4[j].w;
        }
    }
    __syncthreads();
  }
  float* pp = part + (((size_t)split * kB + b) * kM) * kD;
#pragma unroll
  for (int i = 0; i < 4; ++i)
#pragma unroll
    for (int j = 0; j < 4; ++j)
      *(float4*)&pp[(size_t)(ty * 4 + i) * kD + d0 + tx * 16 + j * 4] = acc[i][j];
}

__global__ __launch_bounds__(256) void kvh_reduce_kernel(const float* __restrict__ part,
                                                         bf16* __restrict__ kvhb) {
  int gid = blockIdx.x * 256 + threadIdx.x;
  float4 s = make_float4(0.f, 0.f, 0.f, 0.f);
#pragma unroll
  for (int sp = 0; sp < 16; ++sp) {
    float4 p = ((const float4*)part)[(size_t)sp * (kB * kM * kD / 4) + gid];
    s.x += p.x; s.y += p.y; s.z += p.z; s.w += p.w;
  }
  ushort4 u;
  u.x = f2bf_u16(s.x); u.y = f2bf_u16(s.y);
  u.z = f2bf_u16(s.z); u.w = f2bf_u16(s.w);
  ((ushort4*)kvhb)[gid] = u;
}

// ---------------------------------------------------------------------------
__global__ __launch_bounds__(256) void zero_pks_kernel(float* __restrict__ p) {
  ((float4*)p)[threadIdx.x] = make_float4(0.f, 0.f, 0.f, 0.f);
}

__global__ __launch_bounds__(256) void pksum_kernel(const float* __restrict__ pk,
                                                    float* __restrict__ pksum) {
  __shared__ float part[4][64];
  int b = blockIdx.x >> 4;
  int split = blockIdx.x & 15;
  int lane = threadIdx.x & 63, w = threadIdx.x >> 6;
  float s = 0.f;
  int base = split * 128 + w * 32;
  for (int i = 0; i < 32; ++i)
    s += pk[((size_t)b * kS + base + i) * kM + lane];
  part[w][lane] = s;
  __syncthreads();
  if (w == 0)
    atomicAdd(&pksum[b * kM + lane],
              part[0][lane] + part[1][lane] + part[2][lane] + part[3][lane]);
}

// ---------------------------------------------------------------------------
__global__ __launch_bounds__(256) void z_kernel(const float* __restrict__ pq,
    const float* __restrict__ pksum, float* __restrict__ z) {
  int row = blockIdx.x * 4 + (threadIdx.x >> 6);
  int lane = threadIdx.x & 63;
  int b = row >> 11;
  float v = pq[(size_t)row * kM + lane] * pksum[b * kM + lane];
#pragma unroll
  for (int off = 32; off; off >>= 1) v += __shfl_down(v, off);
  if (lane == 0) z[row] = v + 1e-6f;
}

// ---------------------------------------------------------------------------
__global__ __launch_bounds__(256) void att_kernel(const float* __restrict__ pq,
    const float* __restrict__ kvo, const float* __restrict__ z,
    const float* __restrict__ bo, float* __restrict__ outf) {
  __shared__ float pqS[64][68];
  __shared__ float kvS[64][68];
  const int d0 = blockIdx.x * 64, s0 = blockIdx.y * 64, b = blockIdx.z;
  const int tid = threadIdx.x;
  const int tx = tid & 15, ty = tid >> 4;
  for (int i = 0; i < 4; ++i) {
    int f = tid + i * 256;
    int r = f >> 4, c = (f & 15) * 4;
    *(float4*)&pqS[r][c] = *(const float4*)&pq[((size_t)(b * kS + s0 + r)) * kM + c];
    *(float4*)&kvS[r][c] = *(const float4*)&kvo[((size_t)b * kM + r) * kD + d0 + c];
  }
  __syncthreads();
  float acc[4][4] = {};
#pragma unroll
  for (int m = 0; m < kM; ++m) {
    float a[4];
#pragma unroll
    for (int i = 0; i < 4; ++i) a[i] = pqS[ty * 4 + i][m];
    float4 b4 = *(const float4*)&kvS[m][tx * 4];
    float bb[4] = {b4.x, b4.y, b4.z, b4.w};
#pragma unroll
    for (int i = 0; i < 4; ++i)
#pragma unroll
      for (int j = 0; j < 4; ++j) acc[i][j] += a[i] * bb[j];
  }
  float4 bo4 = *(const float4*)&bo[d0 + tx * 4];
#pragma unroll
  for (int i = 0; i < 4; ++i) {
    int srow = s0 + ty * 4 + i;
    float zi = 1.0f / z[b * kS + srow];
    float4 o;
    o.x = acc[i][0] * zi + bo4.x;
    o.y = acc[i][1] * zi + bo4.y;
    o.z = acc[i][2] * zi + bo4.z;
    o.w = acc[i][3] * zi + bo4.w;
    *(float4*)&outf[((size_t)(b * kS + srow)) * kD + d0 + tx * 4] = o;
  }
}

// ---------------------------------------------------------------------------
__global__ __launch_bounds__(256) void ln_kernel(const float* __restrict__ in,
    const float* __restrict__ g, const float* __restrict__ b,
    bf16* __restrict__ out) {
  __shared__ float ws1[4], ws2[4];
  int row = blockIdx.x, tid = threadIdx.x;
  float2 v = ((const float2*)(in + (size_t)row * kD))[tid];
  float s = v.x + v.y;
#pragma unroll
  for (int off = 32; off; off >>= 1) s += __shfl_down(s, off);
  if ((tid & 63) == 0) ws1[tid >> 6] = s;
  __syncthreads();
  float mean = (ws1[0] + ws1[1] + ws1[2] + ws1[3]) * (1.0f / kD);
  float dx = v.x - mean, dy = v.y - mean;
  float s2 = dx * dx + dy * dy;
#pragma unroll
  for (int off = 32; off; off >>= 1) s2 += __shfl_down(s2, off);
  if ((tid & 63) == 0) ws2[tid >> 6] = s2;
  __syncthreads();
  float var = (ws2[0] + ws2[1] + ws2[2] + ws2[3]) * (1.0f / kD);
  float rstd = rsqrtf(var + 1e-5f);
  float2 gg = ((const float2*)g)[tid];
  float2 bb = ((const float2*)b)[tid];
  ushort2 u;
  u.x = f2bf_u16(dx * rstd * gg.x + bb.x);
  u.y = f2bf_u16(dy * rstd * gg.y + bb.y);
  ((ushort2*)(out + (size_t)row * kD))[tid] = u;
}

// ---------------------------------------------------------------------------
__global__ __launch_bounds__(256) void cls_kernel(const float* __restrict__ h,
    const float* __restrict__ Wc1, const float* __restrict__ bc1,
    const float* __restrict__ Wc2, const float* __restrict__ bc2,
    float* __restrict__ out) {
  __shared__ float r0[4], r1[4];
  int b = blockIdx.x;
  int j = threadIdx.x;
  const float* p = h + (size_t)b * kS * kD;
  float acc = bc1[j];
  for (int i = 0; i < kD; ++i) acc += p[i] * Wc1[i * (kD / 2) + j];
  acc = fmaxf(acc, 0.f);
  float p0 = acc * Wc2[j * kC + 0];
  float p1 = acc * Wc2[j * kC + 1];
#pragma unroll
  for (int off = 32; off; off >>= 1) {
    p0 += __shfl_down(p0, off);
    p1 += __shfl_down(p1, off);
  }
  if ((j & 63) == 0) { r0[j >> 6] = p0; r1[j >> 6] = p1; }
  __syncthreads();
  if (j == 0) {
    out[b * kC + 0] = r0[0] + r0[1] + r0[2] + r0[3] + bc2[0];
    out[b * kC + 1] = r1[0] + r1[1] + r1[2] + r1[3] + bc2[1];
  }
}

// ---------------------------------------------------------------------------
extern "C" void kernel_launch(void* const* d_in, const int* in_sizes, int n_in,
                              void* d_out, int out_size, void* d_ws, size_t ws_size,
                              hipStream_t stream) {
  const int*   x    = (const int*)  d_in[0];
  const float* emb  = (const float*)d_in[1];
  const float* pos  = (const float*)d_in[2];
  const float* Wq   = (const float*)d_in[3];
  const float* bq   = (const float*)d_in[4];
  const float* Wk   = (const float*)d_in[5];
  const float* bk   = (const float*)d_in[6];
  const float* Wv   = (const float*)d_in[7];
  const float* bv   = (const float*)d_in[8];
  const float* P    = (const float*)d_in[9];
  const float* Wo   = (const float*)d_in[10];
  const float* bo   = (const float*)d_in[11];
  const float* ln_g = (const float*)d_in[12];
  const float* ln_b = (const float*)d_in[13];
  const float* W1   = (const float*)d_in[14];
  const float* b1   = (const float*)d_in[15];
  const float* W2   = (const float*)d_in[16];
  const float* b2   = (const float*)d_in[17];
  const float* Wc1  = (const float*)d_in[18];
  const float* bc1  = (const float*)d_in[19];
  const float* Wc2  = (const float*)d_in[20];
  const float* bc2  = (const float*)d_in[21];
  float* out = (float*)d_out;

  // fp32 region
  float* h    = (float*)d_ws;                    // 64 MB
  float* t0   = h    + (size_t)kBS * kD;         // 64 MB (atth f32; F aliases)
  float* pq   = t0   + (size_t)kBS * kD;         // 8 MB
  float* pk   = pq   + (size_t)kBS * kM;         // 8 MB
  float* kvo  = pk   + (size_t)kBS * kM;         // 2 MB
  float* pks  = kvo  + (size_t)kB * kM * kD;
  float* zb   = pks  + (size_t)kB * kM;
  float* bqp  = zb   + kBS;
  float* bkp  = bqp  + kM;
  float* bvWo = bkp  + kM;
  float* zeros= bvWo + kD;
  // bf16 region
  bf16* hb    = (bf16*)(zeros + kD);             // 32 MB
  bf16* ab    = hb + (size_t)kBS * kD;           // 32 MB (kvh partials alias; hn)
  bf16* Wqpt  = ab  + (size_t)kBS * kD;
  bf16* Wkpt  = Wqpt + (size_t)kM * kD;
  bf16* Wot   = Wkpt + (size_t)kM * kD;
  bf16* Wvc   = Wot + (size_t)kD * kD;
  bf16* WvWot = Wvc + (size_t)kD * kD;
  bf16* W1t   = WvWot + (size_t)kD * kD;
  bf16* W2t   = W1t + (size_t)kD * kH;
  bf16* kvhb  = W2t + (size_t)kD * kH;
  bf16* F     = (bf16*)t0;
  float* kvpart = (float*)ab;

  zero512_kernel<<<1, 256, 0, stream>>>(zeros);
  embed_kernel<<<kBS * (kD / 4) / 256, 256, 0, stream>>>(x, emb, pos, h, hb);

  for (int l = 0; l < kL; ++l) {
    const float* Pl = P + (size_t)l * kD * kM;

    // ---- per-layer weight prep ----
    wfold_kernel<<<128, 256, 0, stream>>>(Wq + (size_t)l * kD * kD, Pl, Wqpt);
    wfold_kernel<<<128, 256, 0, stream>>>(Wk + (size_t)l * kD * kD, Pl, Wkpt);
    bfold_kernel<<<1, 128, 0, stream>>>(bq + l * kD, bk + l * kD, Pl, bqp, bkp);
    transpose_cast_kernel<<<dim3(kD / 32, kD / 32), 256, 0, stream>>>(
        Wo + (size_t)l * kD * kD, Wot, kD, kD);
    cast_bf16_kernel<<<kD * kD / 1024, 256, 0, stream>>>(Wv + (size_t)l * kD * kD, Wvc);
    mfma_gemm<32, 64, 0, false, false, false, true><<<dim3(8, 4), 256, 0, stream>>>(
        Wot, Wvc, zeros, nullptr, nullptr, nullptr, nullptr, WvWot, kD, kD);
    bvwo_kernel<<<2, 256, 0, stream>>>(bv + l * kD, Wo + (size_t)l * kD * kD, bvWo);
    transpose_cast_kernel<<<dim3(kD / 32, kH / 32), 256, 0, stream>>>(
        W1 + (size_t)l * kD * kH, W1t, kD, kH);
    transpose_cast_kernel<<<dim3(kH / 32, kD / 32), 256, 0, stream>>>(
        W2 + (size_t)l * kH * kD, W2t, kH, kD);

    // ---- attention (folded) ----
    skinny_dual_gemm<<<kBS / 64, 256, 0, stream>>>(hb, Wqpt, Wkpt, bqp, bkp, pq, pk);
    kvh_split_kernel<<<dim3(kD / 256, kB, 16), 256, 0, stream>>>(pk, hb, kvpart);
    kvh_reduce_kernel<<<kB * kM * kD / 1024, 256, 0, stream>>>(kvpart, kvhb);
    zero_pks_kernel<<<1, 256, 0, stream>>>(pks);
    pksum_kernel<<<kB * 16, 256, 0, stream>>>(pk, pks);
    z_kernel<<<kBS / 4, 256, 0, stream>>>(pq, pks, zb);
    mfma_gemm<32, 64, 0, false, true, true, false><<<dim3(8, 8), 256, 0, stream>>>(
        kvhb, WvWot, nullptr, pks, bvWo, nullptr, kvo, nullptr, kD, kD);
    att_kernel<<<dim3(kD / 64, kS / 64, kB), 256, 0, stream>>>(pq, kvo, zb, bo + l * kD, t0);
    ln_kernel<<<kBS, 256, 0, stream>>>(t0, ln_g + l * kD, ln_b + l * kD, ab);
    // ---- FFN in 2 row-chunks of 16384, BK=64 ----
    for (int c = 0; c < 2; ++c) {
      size_t ro = (size_t)c * 16384;
      mfma_gemm<64, 128, 2, false, false, false, true><<<dim3(kH / 128, 16384 / 128), 256, 0, stream>>>(
          ab + ro * kD, W1t, b1 + l * kH, nullptr, nullptr, nullptr, nullptr, F, kD, kH);
      mfma_gemm<64, 64, 0, true, false, true, true><<<dim3(kD / 64, 16384 / 128), 256, 0, stream>>>(
          F, W2t, b2 + l * kD, nullptr, nullptr, h + ro * kD, h + ro * kD, hb + ro * kD, kH, kD);
    }
  }

  cls_kernel<<<kB, 256, 0, stream>>>(h, Wc1, bc1, Wc2, bc2, out);
}